// Round 2
// baseline (301.647 us; speedup 1.0000x reference)
//
#include <hip/hip_runtime.h>
#include <hip/hip_bf16.h>
#include <cstdint>

// ---------------------------------------------------------------------------
// MultiHeadAttention: B=2, T=2048, D=1024, H=16, hd=64, causal.
// Inputs (fp32): x[B,T,D], W_qkv[3D,D], b_qkv[3D], W_out[D,D], b_out[D]
// out (fp32): [B,T,D]
// ws big path (48MB): Q@0, K@8M, Vt@16M, rawV/O@24M, xb@32M, Wqkvb@40M, Woutb@46M
// GEMMs: one-shot fp32->bf16 cvt, then m97-style global_load_lds staging.
// Softmax: no-max flash (p = exp2(s) directly), row-sum via MFMA B=ones.
// Attn v3: 512-thr blocks = 2 rowgroups(32 rows) x 4 K-slices; block covers
// 64 q-rows, handles complementary qt pair (15-p, p) -> every wave ~9 K-tile
// iterations (v1 worst path was 32). Body is v1's register-light one (K
// double-buffered in regs, V loaded inside body) -- v2's V-prefetch blew
// VGPRs (100->120) and doubled per-iter latency. 4-way K partials summed via
// LDS (exact: no-max flash accs are pure sums). Grid 512 -> 4 waves/SIMD.
// ---------------------------------------------------------------------------

using short8  = __attribute__((ext_vector_type(8))) short;
using floatx4 = __attribute__((ext_vector_type(4))) float;

#define LDS_STRIDE 40  // legacy gemm tiles: 32+8 pad

__device__ __forceinline__ float bf16_to_f32(unsigned short u) {
    union { unsigned int i; float f; } v; v.i = ((unsigned int)u) << 16; return v.f;
}
__device__ __forceinline__ unsigned short f32_to_bf16(float f) {
    union { float f; unsigned int i; } v; v.f = f;
    unsigned int x = v.i;
    unsigned int r = x + 0x7FFFu + ((x >> 16) & 1u);  // RNE
    return (unsigned short)(r >> 16);
}
__device__ __forceinline__ unsigned short f32_to_bf16_fast(float f) {
    union { float f; unsigned int i; } v; v.f = f;
    return (unsigned short)((v.i + 0x8000u) >> 16);
}
__device__ __forceinline__ short8 cvt8(const float* __restrict__ p) {
    const float4 f0 = *(const float4*)p;
    const float4 f1 = *(const float4*)(p + 4);
    short8 r;
    r[0] = (short)f32_to_bf16(f0.x); r[1] = (short)f32_to_bf16(f0.y);
    r[2] = (short)f32_to_bf16(f0.z); r[3] = (short)f32_to_bf16(f0.w);
    r[4] = (short)f32_to_bf16(f1.x); r[5] = (short)f32_to_bf16(f1.y);
    r[6] = (short)f32_to_bf16(f1.z); r[7] = (short)f32_to_bf16(f1.w);
    return r;
}

// 1/sqrt(64) * log2(e)
#define Q_PRESCALE 0.1803368801111204f

#if __has_builtin(__builtin_amdgcn_global_load_lds)
#define ASYNC_STAGE 1
typedef const __attribute__((address_space(1))) void* gas1_t;
typedef __attribute__((address_space(3))) void* las3_t;
__device__ __forceinline__ void gload_lds16(const ushort* g, ushort* l) {
    __builtin_amdgcn_global_load_lds((gas1_t)g, (las3_t)l, 16, 0, 0);
}
#else
#define ASYNC_STAGE 0
#endif

// fp32 -> bf16 elementwise, 8 elems/thread
__global__ __launch_bounds__(256, 8) void cvt_bf16(
    const float* __restrict__ in, ushort* __restrict__ out, int n8)
{
    const int i = blockIdx.x * 256 + threadIdx.x;
    if (i < n8) *(short8*)(out + (size_t)i * 8) = cvt8(in + (size_t)i * 8);
}

// ===== m97-style bf16 GEMM: C[M,N] = A[M,K] @ W[N,K]^T + bias[N] =====
// MODE 0: scatter Q (scaled), K, V [bh][t][64] bf16. MODE 1: fp32 Cout.
template <int MODE>
__global__ __launch_bounds__(256, 3) void gemm_bf16(
    const ushort* __restrict__ A, const ushort* __restrict__ W,
    const float* __restrict__ bias,
    ushort* __restrict__ Cq, ushort* __restrict__ Ck, ushort* __restrict__ Cv,
    float* __restrict__ Cout, int M, int N, int K)
{
    // NO padding: stride 32 (global_load_lds dest = uniform base + lane*16B)
    __shared__ __align__(16) ushort As[128 * 32];
    __shared__ __align__(16) ushort Bs[128 * 32];

    const int tid  = threadIdx.x;
    const int lane = tid & 63;
    const int wave = tid >> 6;
    const int wm = (wave >> 1) * 64;
    const int wn = (wave & 1) * 64;
    const int m0 = blockIdx.x * 128;
    const int n0 = blockIdx.y * 128;
    const int quad = lane >> 4;
    const int l16  = lane & 15;

    floatx4 acc[4][4];
#pragma unroll
    for (int i = 0; i < 4; i++)
#pragma unroll
        for (int j = 0; j < 4; j++) acc[i][j] = (floatx4)0.0f;

    // staging map: wave slab = 16 rows; lane -> row (lane>>2), col (lane&3)*8
    const int srow = wave * 16 + (lane >> 2);
    const int scol = (lane & 3) * 8;
    ushort* ldsA0 = &As[wave * 512];
    ushort* ldsA1 = &As[2048 + wave * 512];
    ushort* ldsB0 = &Bs[wave * 512];
    ushort* ldsB1 = &Bs[2048 + wave * 512];
    const ushort* pA0 = A + (size_t)(m0 + srow) * K + scol;
    const ushort* pA1 = pA0 + (size_t)64 * K;
    const ushort* pB0 = W + (size_t)(n0 + srow) * K + scol;
    const ushort* pB1 = pB0 + (size_t)64 * K;

    for (int k0 = 0; k0 < K; k0 += 32) {
#if ASYNC_STAGE
        __syncthreads();  // prev iter's fragment reads done
        gload_lds16(pA0 + k0, ldsA0);
        gload_lds16(pA1 + k0, ldsA1);
        gload_lds16(pB0 + k0, ldsB0);
        gload_lds16(pB1 + k0, ldsB1);
        __syncthreads();  // compiler drains vmcnt before barrier
#else
        const short8 a0 = *(const short8*)(pA0 + k0);
        const short8 a1 = *(const short8*)(pA1 + k0);
        const short8 b0 = *(const short8*)(pB0 + k0);
        const short8 b1 = *(const short8*)(pB1 + k0);
        __syncthreads();
        *(short8*)&As[srow * 32 + scol] = a0;
        *(short8*)&As[(srow + 64) * 32 + scol] = a1;
        *(short8*)&Bs[srow * 32 + scol] = b0;
        *(short8*)&Bs[(srow + 64) * 32 + scol] = b1;
        __syncthreads();
#endif

        short8 af[4], bf[4];
#pragma unroll
        for (int i = 0; i < 4; i++)
            af[i] = *(const short8*)&As[(wm + i * 16 + l16) * 32 + quad * 8];
#pragma unroll
        for (int j = 0; j < 4; j++)
            bf[j] = *(const short8*)&Bs[(wn + j * 16 + l16) * 32 + quad * 8];
#pragma unroll
        for (int i = 0; i < 4; i++)
#pragma unroll
            for (int j = 0; j < 4; j++)
                acc[i][j] = __builtin_amdgcn_mfma_f32_16x16x32_bf16(af[i], bf[j], acc[i][j], 0, 0, 0);
    }

#pragma unroll
    for (int i = 0; i < 4; i++) {
#pragma unroll
        for (int j = 0; j < 4; j++) {
#pragma unroll
            for (int r = 0; r < 4; r++) {
                const int row = m0 + wm + i * 16 + quad * 4 + r;
                const int col = n0 + wn + j * 16 + l16;
                float v = acc[i][j][r] + bias[col];
                if (MODE == 0) {
                    const int h  = col / 192;
                    const int rr = col - h * 192;
                    const int sel = rr >> 6;
                    const int d   = rr & 63;
                    const int b = row >> 11;
                    const int t = row & 2047;
                    const size_t idx = (((size_t)(b * 16 + h)) * 2048 + t) * 64 + d;
                    if (sel == 0)      Cq[idx] = f32_to_bf16(v * Q_PRESCALE);
                    else if (sel == 1) Ck[idx] = f32_to_bf16(v);
                    else               Cv[idx] = f32_to_bf16(v);
                } else {
                    Cout[(size_t)row * N + col] = v;
                }
            }
        }
    }
}

// ===== legacy fused-cvt GEMM (fallback when ws < 48MB) =====
template <int MODE, int AFP32>
__global__ __launch_bounds__(256, 2) void gemm_bt(
    const void* __restrict__ Av, const float* __restrict__ W,
    const float* __restrict__ bias,
    ushort* __restrict__ Cq, ushort* __restrict__ Ck, ushort* __restrict__ Cv,
    float* __restrict__ Cout, int M, int N, int K)
{
    __shared__ __align__(16) ushort As[128 * LDS_STRIDE];
    __shared__ __align__(16) ushort Bs[128 * LDS_STRIDE];

    const int tid  = threadIdx.x;
    const int lane = tid & 63;
    const int wave = tid >> 6;
    const int wm = (wave >> 1) * 64;
    const int wn = (wave & 1) * 64;
    const int m0 = blockIdx.x * 128;
    const int n0 = blockIdx.y * 128;
    const int quad = lane >> 4;
    const int l16  = lane & 15;

    floatx4 acc[4][4];
#pragma unroll
    for (int i = 0; i < 4; i++)
#pragma unroll
        for (int j = 0; j < 4; j++) acc[i][j] = (floatx4)0.0f;

    const int srow = tid >> 2;
    const int scol = (tid & 3) * 8;

    for (int k0 = 0; k0 < K; k0 += 32) {
        short8 a0, a1;
        if (AFP32) {
            const float* A = (const float*)Av;
            a0 = cvt8(A + (size_t)(m0 + srow) * K + k0 + scol);
            a1 = cvt8(A + (size_t)(m0 + srow + 64) * K + k0 + scol);
        } else {
            const ushort* A = (const ushort*)Av;
            a0 = *(const short8*)(A + (size_t)(m0 + srow) * K + k0 + scol);
            a1 = *(const short8*)(A + (size_t)(m0 + srow + 64) * K + k0 + scol);
        }
        const short8 b0 = cvt8(W + (size_t)(n0 + srow) * K + k0 + scol);
        const short8 b1 = cvt8(W + (size_t)(n0 + srow + 64) * K + k0 + scol);
        __syncthreads();
        *(short8*)&As[srow * LDS_STRIDE + scol] = a0;
        *(short8*)&As[(srow + 64) * LDS_STRIDE + scol] = a1;
        *(short8*)&Bs[srow * LDS_STRIDE + scol] = b0;
        *(short8*)&Bs[(srow + 64) * LDS_STRIDE + scol] = b1;
        __syncthreads();

        short8 af[4], bf[4];
#pragma unroll
        for (int i = 0; i < 4; i++)
            af[i] = *(const short8*)&As[(wm + i * 16 + l16) * LDS_STRIDE + quad * 8];
#pragma unroll
        for (int j = 0; j < 4; j++)
            bf[j] = *(const short8*)&Bs[(wn + j * 16 + l16) * LDS_STRIDE + quad * 8];
#pragma unroll
        for (int i = 0; i < 4; i++)
#pragma unroll
            for (int j = 0; j < 4; j++)
                acc[i][j] = __builtin_amdgcn_mfma_f32_16x16x32_bf16(af[i], bf[j], acc[i][j], 0, 0, 0);
    }

#pragma unroll
    for (int i = 0; i < 4; i++) {
#pragma unroll
        for (int j = 0; j < 4; j++) {
#pragma unroll
            for (int r = 0; r < 4; r++) {
                const int row = m0 + wm + i * 16 + quad * 4 + r;
                const int col = n0 + wn + j * 16 + l16;
                float v = acc[i][j][r] + bias[col];
                if (MODE == 0) {
                    const int h  = col / 192;
                    const int rr = col - h * 192;
                    const int sel = rr >> 6;
                    const int d   = rr & 63;
                    const int b = row >> 11;
                    const int t = row & 2047;
                    const size_t idx = (((size_t)(b * 16 + h)) * 2048 + t) * 64 + d;
                    if (sel == 0)      Cq[idx] = f32_to_bf16(v * Q_PRESCALE);
                    else if (sel == 1) Ck[idx] = f32_to_bf16(v);
                    else               Cv[idx] = f32_to_bf16(v);
                } else {
                    Cout[(size_t)row * N + col] = v;
                }
            }
        }
    }
}

// V[bh][t][d] -> Vt[bh][d][t]
__global__ __launch_bounds__(256, 4) void transpose_v(
    const ushort* __restrict__ V, ushort* __restrict__ Vt)
{
    const int bh = blockIdx.x & 31;
    const int tt = blockIdx.x >> 5;
    const int t0 = tt * 64;
    const int tid = threadIdx.x;
    __shared__ __align__(16) ushort tile[64 * 72];

    const int r = tid >> 2, c = (tid & 3) * 16;
    const ushort* src = V + ((size_t)bh * 2048 + t0 + r) * 64 + c;
    *(short8*)&tile[r * 72 + c]     = *(const short8*)src;
    *(short8*)&tile[r * 72 + c + 8] = *(const short8*)(src + 8);
    __syncthreads();

    const int w = tid >> 6, lane = tid & 63;
    const int d  = w * 16 + (lane >> 2);
    const int tc = (lane & 3) * 16;
    __attribute__((aligned(16))) ushort out[16];
#pragma unroll
    for (int i = 0; i < 16; i++) out[i] = tile[(tc + i) * 72 + d];
    ushort* dst = Vt + ((size_t)bh * 64 + d) * 2048 + t0 + tc;
    *(short8*)dst       = *(const short8*)&out[0];
    *(short8*)(dst + 8) = *(const short8*)&out[8];
}

// ===========================================================================
// MFMA causal flash attention, v3.
// Block = 512 threads = 8 waves: rowg = wave&1 (32 q-rows each), ks = wave>>1
// (4-way K-range slice). Block covers 64 q-rows. Grid = 32 bh * 8 pairs *
// 2 row-halves = 512 blocks (2/CU, 4 waves/SIMD). Block handles qt = 15-pr
// then qt = pr; per qt, tiles [0, nt) split 4 ways -> every wave ~9 K-tile
// iterations total. Body = v1's register-light body (K dbuf in regs, V loaded
// inside body). Partials (pure sums in no-max flash) combined through LDS.
// ===========================================================================
#define P_STRIDE 76
__global__ __launch_bounds__(512, 4) void attn_mfma(
    const ushort* __restrict__ Q, const ushort* __restrict__ K,
    const ushort* __restrict__ Vt, ushort* __restrict__ O)
{
    const int bid  = blockIdx.x;
    const int bh   = bid & 31;          // low bits: same-bh blocks share an XCD
    const int rt   = (bid >> 5) & 1;    // which 64-row half of the 128-row tile
    const int pr   = bid >> 6;          // 0..7 : qt pair (15-pr, pr)
    const int tid  = threadIdx.x;
    const int wave = tid >> 6;          // 0..7
    const int lane = tid & 63;
    const int quad = lane >> 4;
    const int l16  = lane & 15;
    const int rowg = wave & 1;          // 32-row group within the 64-row half
    const int ks   = wave >> 1;         // 0..3 K-slice

    // Union LDS: P buffers (8 waves * 2 frags * 16*P_STRIDE ushort = 38912 B)
    // overlaid with combine buffer (3 ks * 128 slots * 41 f32 = 62976 B).
    // Usage is barrier-separated. 62976 B -> 2 blocks/CU.
    __shared__ __align__(16) char smem[62976];
    ushort* Pbase = (ushort*)smem + wave * 2 * (16 * P_STRIDE);
    float*  cbase = (float*)smem;

    const size_t kbase  = (size_t)bh * 2048 * 64;
    const size_t vtbase = (size_t)bh * 64 * 2048 + (size_t)l16 * 2048;

    short8 ones;
#pragma unroll
    for (int i = 0; i < 8; i++) ones[i] = (short)0x3F80;

    const int b = bh >> 4, h = bh & 15;

    for (int phase = 0; phase < 2; ++phase) {
        const int qt = phase ? pr : 15 - pr;
        const int qb = qt * 128 + rt * 64 + rowg * 32;
        // tiles needed by this 64-row half: rows up to qt*128+rt*64+63
        const int nt = 2 * qt + rt + 1;
        // split [0, nt) into 4 contiguous chunks
        const int base = nt >> 2, rem = nt & 3;
        const int ts = ks * base + (ks < rem ? ks : rem);
        const int te = ts + base + (ks < rem ? 1 : 0);

        short8 qf0[2], qf1[2];
#pragma unroll
        for (int f = 0; f < 2; f++) {
            const ushort* qp = Q + kbase + (size_t)(qb + f * 16 + l16) * 64 + quad * 8;
            qf0[f] = *(const short8*)qp;
            qf1[f] = *(const short8*)(qp + 32);
        }

        floatx4 accO[2][4];
#pragma unroll
        for (int f = 0; f < 2; f++)
#pragma unroll
            for (int d = 0; d < 4; d++) accO[f][d] = (floatx4)0.0f;
        floatx4 accL[2];
        accL[0] = (floatx4)0.0f; accL[1] = (floatx4)0.0f;

        auto loadK = [&](int t64, short8 (&kf)[4][2]) {
            const ushort* kp = K + kbase + (size_t)(t64 * 64 + l16) * 64 + quad * 8;
#pragma unroll
            for (int j = 0; j < 4; j++) {
                kf[j][0] = *(const short8*)(kp + j * 1024);
                kf[j][1] = *(const short8*)(kp + j * 1024 + 32);
            }
        };

        auto body = [&](int t64, short8 (&kf)[4][2]) {
            short8 vf[4][2];
            const ushort* vp = Vt + vtbase + t64 * 64 + quad * 8;
#pragma unroll
            for (int d = 0; d < 4; d++) {
                vf[d][0] = *(const short8*)(vp + d * 16 * 2048);
                vf[d][1] = *(const short8*)(vp + d * 16 * 2048 + 32);
            }
#pragma unroll
            for (int f = 0; f < 2; f++) {
                const int qlo = qb + f * 16;
                if (t64 * 64 > qlo + 15) continue;  // fully masked fragment
                floatx4 s[4];
                __builtin_amdgcn_s_setprio(1);
#pragma unroll
                for (int j = 0; j < 4; j++) {
                    floatx4 t = (floatx4)0.0f;
                    t = __builtin_amdgcn_mfma_f32_16x16x32_bf16(qf0[f], kf[j][0], t, 0, 0, 0);
                    t = __builtin_amdgcn_mfma_f32_16x16x32_bf16(qf1[f], kf[j][1], t, 0, 0, 0);
                    s[j] = t;
                }
                __builtin_amdgcn_s_setprio(0);
                if (t64 * 64 + 63 > qlo) {
#pragma unroll
                    for (int j = 0; j < 4; j++) {
                        const int key = t64 * 64 + j * 16 + l16;
#pragma unroll
                        for (int r = 0; r < 4; r++)
                            if (key > qlo + quad * 4 + r) s[j][r] = -1e30f;
                    }
                }
                ushort* Pw = Pbase + f * (16 * P_STRIDE);
#pragma unroll
                for (int j = 0; j < 4; j++)
#pragma unroll
                    for (int r = 0; r < 4; r++)
                        Pw[(quad * 4 + r) * P_STRIDE + j * 16 + l16] =
                            f32_to_bf16_fast(__builtin_amdgcn_exp2f(s[j][r]));

                const short8 pf0 = *(const short8*)&Pw[l16 * P_STRIDE + quad * 8];
                const short8 pf1 = *(const short8*)&Pw[l16 * P_STRIDE + 32 + quad * 8];
                __builtin_amdgcn_s_setprio(1);
#pragma unroll
                for (int d = 0; d < 4; d++) {
                    accO[f][d] = __builtin_amdgcn_mfma_f32_16x16x32_bf16(pf0, vf[d][0], accO[f][d], 0, 0, 0);
                    accO[f][d] = __builtin_amdgcn_mfma_f32_16x16x32_bf16(pf1, vf[d][1], accO[f][d], 0, 0, 0);
                }
                accL[f] = __builtin_amdgcn_mfma_f32_16x16x32_bf16(pf0, ones, accL[f], 0, 0, 0);
                accL[f] = __builtin_amdgcn_mfma_f32_16x16x32_bf16(pf1, ones, accL[f], 0, 0, 0);
                __builtin_amdgcn_s_setprio(0);
            }
        };

        short8 kfA[4][2], kfB[4][2];
        int t = ts;
        if (t < te) {
            loadK(t, kfA);
            while (true) {
                if (t + 1 < te) loadK(t + 1, kfB);
                body(t, kfA);
                if (++t >= te) break;
                if (t + 1 < te) loadK(t + 1, kfA);
                body(t, kfB);
                if (++t >= te) break;
            }
        }

        // ---- combine 4-way K partials (exact: accumulators are pure sums) ----
        __syncthreads();  // all P-buffer use done; region becomes combine buf
        if (ks) {
            float* cb = cbase + (size_t)((ks - 1) * 128 + rowg * 64 + lane) * 41;
            int idx = 0;
#pragma unroll
            for (int f = 0; f < 2; f++)
#pragma unroll
                for (int d = 0; d < 4; d++)
#pragma unroll
                    for (int r = 0; r < 4; r++) cb[idx++] = accO[f][d][r];
#pragma unroll
            for (int f = 0; f < 2; f++)
#pragma unroll
                for (int r = 0; r < 4; r++) cb[idx++] = accL[f][r];
        }
        __syncthreads();
        if (ks == 0) {
#pragma unroll
            for (int c = 0; c < 3; c++) {
                const float* cb = cbase + (size_t)(c * 128 + rowg * 64 + lane) * 41;
                int idx = 0;
#pragma unroll
                for (int f = 0; f < 2; f++)
#pragma unroll
                    for (int d = 0; d < 4; d++)
#pragma unroll
                        for (int r = 0; r < 4; r++) accO[f][d][r] += cb[idx++];
#pragma unroll
                for (int f = 0; f < 2; f++)
#pragma unroll
                    for (int r = 0; r < 4; r++) accL[f][r] += cb[idx++];
            }
#pragma unroll
            for (int f = 0; f < 2; f++) {
                float inv[4];
#pragma unroll
                for (int r = 0; r < 4; r++) inv[r] = 1.0f / accL[f][r];
#pragma unroll
                for (int d = 0; d < 4; d++)
#pragma unroll
                    for (int r = 0; r < 4; r++)
                        O[(size_t)(b * 2048 + qb + f * 16 + quad * 4 + r) * 1024 + h * 64 + d * 16 + l16] =
                            f32_to_bf16(accO[f][d][r] * inv[r]);
            }
        }
        __syncthreads();  // protect combine region before next phase's P use
    }
}

extern "C" void kernel_launch(void* const* d_in, const int* in_sizes, int n_in,
                              void* d_out, int out_size, void* d_ws, size_t ws_size,
                              hipStream_t stream) {
    const float* x    = (const float*)d_in[0];
    const float* Wqkv = (const float*)d_in[1];
    const float* bqkv = (const float*)d_in[2];
    const float* Wout = (const float*)d_in[3];
    const float* bout = (const float*)d_in[4];
    float* out = (float*)d_out;

    char* ws = (char*)d_ws;
    const size_t MB = 1024 * 1024;
    ushort* Q    = (ushort*)(ws + 0 * MB);
    ushort* Kk   = (ushort*)(ws + 8 * MB);
    ushort* Vt   = (ushort*)(ws + 16 * MB);
    ushort* rawV = (ushort*)(ws + 24 * MB);
    ushort* O    = (ushort*)(ws + 24 * MB);  // overwrites rawV after transpose

    const dim3 blk(256);
    if (ws_size >= 48 * MB) {
        ushort* xb    = (ushort*)(ws + 32 * MB);
        ushort* Wqkvb = (ushort*)(ws + 40 * MB);
        ushort* Woutb = (ushort*)(ws + 46 * MB);
        cvt_bf16<<<dim3(2048), blk, 0, stream>>>(x, xb, 524288);
        cvt_bf16<<<dim3(1536), blk, 0, stream>>>(Wqkv, Wqkvb, 393216);
        cvt_bf16<<<dim3(512),  blk, 0, stream>>>(Wout, Woutb, 131072);
        gemm_bf16<0><<<dim3(32, 24), blk, 0, stream>>>(xb, Wqkvb, bqkv, Q, Kk, rawV,
                                                       nullptr, 4096, 3072, 1024);
        transpose_v<<<dim3(1024), blk, 0, stream>>>(rawV, Vt);
        attn_mfma<<<dim3(512), dim3(512), 0, stream>>>(Q, Kk, Vt, O);
        gemm_bf16<1><<<dim3(32, 8), blk, 0, stream>>>(O, Woutb, bout, nullptr, nullptr,
                                                      nullptr, out, 4096, 1024, 1024);
    } else {
        gemm_bt<0, 1><<<dim3(32, 24), blk, 0, stream>>>(x, Wqkv, bqkv, Q, Kk, rawV,
                                                        nullptr, 4096, 3072, 1024);
        transpose_v<<<dim3(1024), blk, 0, stream>>>(rawV, Vt);
        attn_mfma<<<dim3(512), dim3(512), 0, stream>>>(Q, Kk, Vt, O);
        gemm_bt<1, 0><<<dim3(32, 8), blk, 0, stream>>>(O, Wout, bout, nullptr, nullptr,
                                                       nullptr, out, 4096, 1024, 1024);
    }
}

// Round 3
// 226.795 us; speedup vs baseline: 1.3300x; 1.3300x over previous
//
#include <hip/hip_runtime.h>
#include <hip/hip_bf16.h>
#include <cstdint>

// ---------------------------------------------------------------------------
// MultiHeadAttention: B=2, T=2048, D=1024, H=16, hd=64, causal.
// Inputs (fp32): x[B,T,D], W_qkv[3D,D], b_qkv[3D], W_out[D,D], b_out[D]
// out (fp32): [B,T,D]
// ws big path (48MB): Q@0, K@8M, Vt@16M, rawV/O@24M, xb@32M, Wqkvb@40M, Woutb@46M
// GEMMs: one-shot fp32->bf16 cvt, then m97-style global_load_lds staging.
// Softmax: no-max flash (p = exp2(s) directly), row-sum via MFMA B=ones.
// Attn v4: v3 structure (2 rowgroups x 4 K-slices, ~9 iters/wave, LDS
// combine) with corrected __launch_bounds__(512, 2).
// LESSON (v3): launch_bounds 2nd arg behaves as MIN BLOCKS PER CU here:
// (512,4) -> 4 blk * 8 waves = 32 waves/CU = 8 waves/SIMD -> 64-VGPR cap ->
// total spill (FETCH 270MB, WRITE 298MB, 160us). LDS=62976B already caps at
// 2 blocks/CU = 4 waves/SIMD, which needs only the 128-VGPR cap of (512,2).
// ---------------------------------------------------------------------------

using short8  = __attribute__((ext_vector_type(8))) short;
using floatx4 = __attribute__((ext_vector_type(4))) float;

#define LDS_STRIDE 40  // legacy gemm tiles: 32+8 pad

__device__ __forceinline__ float bf16_to_f32(unsigned short u) {
    union { unsigned int i; float f; } v; v.i = ((unsigned int)u) << 16; return v.f;
}
__device__ __forceinline__ unsigned short f32_to_bf16(float f) {
    union { float f; unsigned int i; } v; v.f = f;
    unsigned int x = v.i;
    unsigned int r = x + 0x7FFFu + ((x >> 16) & 1u);  // RNE
    return (unsigned short)(r >> 16);
}
__device__ __forceinline__ unsigned short f32_to_bf16_fast(float f) {
    union { float f; unsigned int i; } v; v.f = f;
    return (unsigned short)((v.i + 0x8000u) >> 16);
}
__device__ __forceinline__ short8 cvt8(const float* __restrict__ p) {
    const float4 f0 = *(const float4*)p;
    const float4 f1 = *(const float4*)(p + 4);
    short8 r;
    r[0] = (short)f32_to_bf16(f0.x); r[1] = (short)f32_to_bf16(f0.y);
    r[2] = (short)f32_to_bf16(f0.z); r[3] = (short)f32_to_bf16(f0.w);
    r[4] = (short)f32_to_bf16(f1.x); r[5] = (short)f32_to_bf16(f1.y);
    r[6] = (short)f32_to_bf16(f1.z); r[7] = (short)f32_to_bf16(f1.w);
    return r;
}

// 1/sqrt(64) * log2(e)
#define Q_PRESCALE 0.1803368801111204f

#if __has_builtin(__builtin_amdgcn_global_load_lds)
#define ASYNC_STAGE 1
typedef const __attribute__((address_space(1))) void* gas1_t;
typedef __attribute__((address_space(3))) void* las3_t;
__device__ __forceinline__ void gload_lds16(const ushort* g, ushort* l) {
    __builtin_amdgcn_global_load_lds((gas1_t)g, (las3_t)l, 16, 0, 0);
}
#else
#define ASYNC_STAGE 0
#endif

// fp32 -> bf16 elementwise, 8 elems/thread
__global__ __launch_bounds__(256, 8) void cvt_bf16(
    const float* __restrict__ in, ushort* __restrict__ out, int n8)
{
    const int i = blockIdx.x * 256 + threadIdx.x;
    if (i < n8) *(short8*)(out + (size_t)i * 8) = cvt8(in + (size_t)i * 8);
}

// ===== m97-style bf16 GEMM: C[M,N] = A[M,K] @ W[N,K]^T + bias[N] =====
// MODE 0: scatter Q (scaled), K, V [bh][t][64] bf16. MODE 1: fp32 Cout.
template <int MODE>
__global__ __launch_bounds__(256, 3) void gemm_bf16(
    const ushort* __restrict__ A, const ushort* __restrict__ W,
    const float* __restrict__ bias,
    ushort* __restrict__ Cq, ushort* __restrict__ Ck, ushort* __restrict__ Cv,
    float* __restrict__ Cout, int M, int N, int K)
{
    // NO padding: stride 32 (global_load_lds dest = uniform base + lane*16B)
    __shared__ __align__(16) ushort As[128 * 32];
    __shared__ __align__(16) ushort Bs[128 * 32];

    const int tid  = threadIdx.x;
    const int lane = tid & 63;
    const int wave = tid >> 6;
    const int wm = (wave >> 1) * 64;
    const int wn = (wave & 1) * 64;
    const int m0 = blockIdx.x * 128;
    const int n0 = blockIdx.y * 128;
    const int quad = lane >> 4;
    const int l16  = lane & 15;

    floatx4 acc[4][4];
#pragma unroll
    for (int i = 0; i < 4; i++)
#pragma unroll
        for (int j = 0; j < 4; j++) acc[i][j] = (floatx4)0.0f;

    // staging map: wave slab = 16 rows; lane -> row (lane>>2), col (lane&3)*8
    const int srow = wave * 16 + (lane >> 2);
    const int scol = (lane & 3) * 8;
    ushort* ldsA0 = &As[wave * 512];
    ushort* ldsA1 = &As[2048 + wave * 512];
    ushort* ldsB0 = &Bs[wave * 512];
    ushort* ldsB1 = &Bs[2048 + wave * 512];
    const ushort* pA0 = A + (size_t)(m0 + srow) * K + scol;
    const ushort* pA1 = pA0 + (size_t)64 * K;
    const ushort* pB0 = W + (size_t)(n0 + srow) * K + scol;
    const ushort* pB1 = pB0 + (size_t)64 * K;

    for (int k0 = 0; k0 < K; k0 += 32) {
#if ASYNC_STAGE
        __syncthreads();  // prev iter's fragment reads done
        gload_lds16(pA0 + k0, ldsA0);
        gload_lds16(pA1 + k0, ldsA1);
        gload_lds16(pB0 + k0, ldsB0);
        gload_lds16(pB1 + k0, ldsB1);
        __syncthreads();  // compiler drains vmcnt before barrier
#else
        const short8 a0 = *(const short8*)(pA0 + k0);
        const short8 a1 = *(const short8*)(pA1 + k0);
        const short8 b0 = *(const short8*)(pB0 + k0);
        const short8 b1 = *(const short8*)(pB1 + k0);
        __syncthreads();
        *(short8*)&As[srow * 32 + scol] = a0;
        *(short8*)&As[(srow + 64) * 32 + scol] = a1;
        *(short8*)&Bs[srow * 32 + scol] = b0;
        *(short8*)&Bs[(srow + 64) * 32 + scol] = b1;
        __syncthreads();
#endif

        short8 af[4], bf[4];
#pragma unroll
        for (int i = 0; i < 4; i++)
            af[i] = *(const short8*)&As[(wm + i * 16 + l16) * 32 + quad * 8];
#pragma unroll
        for (int j = 0; j < 4; j++)
            bf[j] = *(const short8*)&Bs[(wn + j * 16 + l16) * 32 + quad * 8];
#pragma unroll
        for (int i = 0; i < 4; i++)
#pragma unroll
            for (int j = 0; j < 4; j++)
                acc[i][j] = __builtin_amdgcn_mfma_f32_16x16x32_bf16(af[i], bf[j], acc[i][j], 0, 0, 0);
    }

#pragma unroll
    for (int i = 0; i < 4; i++) {
#pragma unroll
        for (int j = 0; j < 4; j++) {
#pragma unroll
            for (int r = 0; r < 4; r++) {
                const int row = m0 + wm + i * 16 + quad * 4 + r;
                const int col = n0 + wn + j * 16 + l16;
                float v = acc[i][j][r] + bias[col];
                if (MODE == 0) {
                    const int h  = col / 192;
                    const int rr = col - h * 192;
                    const int sel = rr >> 6;
                    const int d   = rr & 63;
                    const int b = row >> 11;
                    const int t = row & 2047;
                    const size_t idx = (((size_t)(b * 16 + h)) * 2048 + t) * 64 + d;
                    if (sel == 0)      Cq[idx] = f32_to_bf16(v * Q_PRESCALE);
                    else if (sel == 1) Ck[idx] = f32_to_bf16(v);
                    else               Cv[idx] = f32_to_bf16(v);
                } else {
                    Cout[(size_t)row * N + col] = v;
                }
            }
        }
    }
}

// ===== legacy fused-cvt GEMM (fallback when ws < 48MB) =====
template <int MODE, int AFP32>
__global__ __launch_bounds__(256, 2) void gemm_bt(
    const void* __restrict__ Av, const float* __restrict__ W,
    const float* __restrict__ bias,
    ushort* __restrict__ Cq, ushort* __restrict__ Ck, ushort* __restrict__ Cv,
    float* __restrict__ Cout, int M, int N, int K)
{
    __shared__ __align__(16) ushort As[128 * LDS_STRIDE];
    __shared__ __align__(16) ushort Bs[128 * LDS_STRIDE];

    const int tid  = threadIdx.x;
    const int lane = tid & 63;
    const int wave = tid >> 6;
    const int wm = (wave >> 1) * 64;
    const int wn = (wave & 1) * 64;
    const int m0 = blockIdx.x * 128;
    const int n0 = blockIdx.y * 128;
    const int quad = lane >> 4;
    const int l16  = lane & 15;

    floatx4 acc[4][4];
#pragma unroll
    for (int i = 0; i < 4; i++)
#pragma unroll
        for (int j = 0; j < 4; j++) acc[i][j] = (floatx4)0.0f;

    const int srow = tid >> 2;
    const int scol = (tid & 3) * 8;

    for (int k0 = 0; k0 < K; k0 += 32) {
        short8 a0, a1;
        if (AFP32) {
            const float* A = (const float*)Av;
            a0 = cvt8(A + (size_t)(m0 + srow) * K + k0 + scol);
            a1 = cvt8(A + (size_t)(m0 + srow + 64) * K + k0 + scol);
        } else {
            const ushort* A = (const ushort*)Av;
            a0 = *(const short8*)(A + (size_t)(m0 + srow) * K + k0 + scol);
            a1 = *(const short8*)(A + (size_t)(m0 + srow + 64) * K + k0 + scol);
        }
        const short8 b0 = cvt8(W + (size_t)(n0 + srow) * K + k0 + scol);
        const short8 b1 = cvt8(W + (size_t)(n0 + srow + 64) * K + k0 + scol);
        __syncthreads();
        *(short8*)&As[srow * LDS_STRIDE + scol] = a0;
        *(short8*)&As[(srow + 64) * LDS_STRIDE + scol] = a1;
        *(short8*)&Bs[srow * LDS_STRIDE + scol] = b0;
        *(short8*)&Bs[(srow + 64) * LDS_STRIDE + scol] = b1;
        __syncthreads();

        short8 af[4], bf[4];
#pragma unroll
        for (int i = 0; i < 4; i++)
            af[i] = *(const short8*)&As[(wm + i * 16 + l16) * LDS_STRIDE + quad * 8];
#pragma unroll
        for (int j = 0; j < 4; j++)
            bf[j] = *(const short8*)&Bs[(wn + j * 16 + l16) * LDS_STRIDE + quad * 8];
#pragma unroll
        for (int i = 0; i < 4; i++)
#pragma unroll
            for (int j = 0; j < 4; j++)
                acc[i][j] = __builtin_amdgcn_mfma_f32_16x16x32_bf16(af[i], bf[j], acc[i][j], 0, 0, 0);
    }

#pragma unroll
    for (int i = 0; i < 4; i++) {
#pragma unroll
        for (int j = 0; j < 4; j++) {
#pragma unroll
            for (int r = 0; r < 4; r++) {
                const int row = m0 + wm + i * 16 + quad * 4 + r;
                const int col = n0 + wn + j * 16 + l16;
                float v = acc[i][j][r] + bias[col];
                if (MODE == 0) {
                    const int h  = col / 192;
                    const int rr = col - h * 192;
                    const int sel = rr >> 6;
                    const int d   = rr & 63;
                    const int b = row >> 11;
                    const int t = row & 2047;
                    const size_t idx = (((size_t)(b * 16 + h)) * 2048 + t) * 64 + d;
                    if (sel == 0)      Cq[idx] = f32_to_bf16(v * Q_PRESCALE);
                    else if (sel == 1) Ck[idx] = f32_to_bf16(v);
                    else               Cv[idx] = f32_to_bf16(v);
                } else {
                    Cout[(size_t)row * N + col] = v;
                }
            }
        }
    }
}

// V[bh][t][d] -> Vt[bh][d][t]
__global__ __launch_bounds__(256, 4) void transpose_v(
    const ushort* __restrict__ V, ushort* __restrict__ Vt)
{
    const int bh = blockIdx.x & 31;
    const int tt = blockIdx.x >> 5;
    const int t0 = tt * 64;
    const int tid = threadIdx.x;
    __shared__ __align__(16) ushort tile[64 * 72];

    const int r = tid >> 2, c = (tid & 3) * 16;
    const ushort* src = V + ((size_t)bh * 2048 + t0 + r) * 64 + c;
    *(short8*)&tile[r * 72 + c]     = *(const short8*)src;
    *(short8*)&tile[r * 72 + c + 8] = *(const short8*)(src + 8);
    __syncthreads();

    const int w = tid >> 6, lane = tid & 63;
    const int d  = w * 16 + (lane >> 2);
    const int tc = (lane & 3) * 16;
    __attribute__((aligned(16))) ushort out[16];
#pragma unroll
    for (int i = 0; i < 16; i++) out[i] = tile[(tc + i) * 72 + d];
    ushort* dst = Vt + ((size_t)bh * 64 + d) * 2048 + t0 + tc;
    *(short8*)dst       = *(const short8*)&out[0];
    *(short8*)(dst + 8) = *(const short8*)&out[8];
}

// ===========================================================================
// MFMA causal flash attention, v4 (= v3 structure, corrected launch bounds).
// Block = 512 threads = 8 waves: rowg = wave&1 (32 q-rows each), ks = wave>>1
// (4-way K-range slice). Block covers 64 q-rows. Grid = 32 bh * 8 pairs *
// 2 row-halves = 512 blocks (2/CU by LDS, 4 waves/SIMD). Block handles
// qt = 15-pr then qt = pr; per qt, tiles [0, nt) split 4 ways -> every wave
// ~9 K-tile iterations. Body = v1's register-light body (K dbuf in regs, V
// loaded inside body). Partials (pure sums) combined through LDS.
// __launch_bounds__(512, 2): 2 blocks/CU -> 128-VGPR cap (v1 body = ~100).
// ===========================================================================
#define P_STRIDE 76
__global__ __launch_bounds__(512, 2) void attn_mfma(
    const ushort* __restrict__ Q, const ushort* __restrict__ K,
    const ushort* __restrict__ Vt, ushort* __restrict__ O)
{
    const int bid  = blockIdx.x;
    const int bh   = bid & 31;          // low bits: same-bh blocks share an XCD
    const int rt   = (bid >> 5) & 1;    // which 64-row half of the 128-row tile
    const int pr   = bid >> 6;          // 0..7 : qt pair (15-pr, pr)
    const int tid  = threadIdx.x;
    const int wave = tid >> 6;          // 0..7
    const int lane = tid & 63;
    const int quad = lane >> 4;
    const int l16  = lane & 15;
    const int rowg = wave & 1;          // 32-row group within the 64-row half
    const int ks   = wave >> 1;         // 0..3 K-slice

    // Union LDS: P buffers (8 waves * 2 frags * 16*P_STRIDE ushort = 38912 B)
    // overlaid with combine buffer (3 ks * 128 slots * 41 f32 = 62976 B).
    // Usage is barrier-separated. 62976 B -> 2 blocks/CU.
    __shared__ __align__(16) char smem[62976];
    ushort* Pbase = (ushort*)smem + wave * 2 * (16 * P_STRIDE);
    float*  cbase = (float*)smem;

    const size_t kbase  = (size_t)bh * 2048 * 64;
    const size_t vtbase = (size_t)bh * 64 * 2048 + (size_t)l16 * 2048;

    short8 ones;
#pragma unroll
    for (int i = 0; i < 8; i++) ones[i] = (short)0x3F80;

    const int b = bh >> 4, h = bh & 15;

    for (int phase = 0; phase < 2; ++phase) {
        const int qt = phase ? pr : 15 - pr;
        const int qb = qt * 128 + rt * 64 + rowg * 32;
        // tiles needed by this 64-row half: rows up to qt*128+rt*64+63
        const int nt = 2 * qt + rt + 1;
        // split [0, nt) into 4 contiguous chunks
        const int base = nt >> 2, rem = nt & 3;
        const int ts = ks * base + (ks < rem ? ks : rem);
        const int te = ts + base + (ks < rem ? 1 : 0);

        short8 qf0[2], qf1[2];
#pragma unroll
        for (int f = 0; f < 2; f++) {
            const ushort* qp = Q + kbase + (size_t)(qb + f * 16 + l16) * 64 + quad * 8;
            qf0[f] = *(const short8*)qp;
            qf1[f] = *(const short8*)(qp + 32);
        }

        floatx4 accO[2][4];
#pragma unroll
        for (int f = 0; f < 2; f++)
#pragma unroll
            for (int d = 0; d < 4; d++) accO[f][d] = (floatx4)0.0f;
        floatx4 accL[2];
        accL[0] = (floatx4)0.0f; accL[1] = (floatx4)0.0f;

        auto loadK = [&](int t64, short8 (&kf)[4][2]) {
            const ushort* kp = K + kbase + (size_t)(t64 * 64 + l16) * 64 + quad * 8;
#pragma unroll
            for (int j = 0; j < 4; j++) {
                kf[j][0] = *(const short8*)(kp + j * 1024);
                kf[j][1] = *(const short8*)(kp + j * 1024 + 32);
            }
        };

        auto body = [&](int t64, short8 (&kf)[4][2]) {
            short8 vf[4][2];
            const ushort* vp = Vt + vtbase + t64 * 64 + quad * 8;
#pragma unroll
            for (int d = 0; d < 4; d++) {
                vf[d][0] = *(const short8*)(vp + d * 16 * 2048);
                vf[d][1] = *(const short8*)(vp + d * 16 * 2048 + 32);
            }
#pragma unroll
            for (int f = 0; f < 2; f++) {
                const int qlo = qb + f * 16;
                if (t64 * 64 > qlo + 15) continue;  // fully masked fragment
                floatx4 s[4];
                __builtin_amdgcn_s_setprio(1);
#pragma unroll
                for (int j = 0; j < 4; j++) {
                    floatx4 t = (floatx4)0.0f;
                    t = __builtin_amdgcn_mfma_f32_16x16x32_bf16(qf0[f], kf[j][0], t, 0, 0, 0);
                    t = __builtin_amdgcn_mfma_f32_16x16x32_bf16(qf1[f], kf[j][1], t, 0, 0, 0);
                    s[j] = t;
                }
                __builtin_amdgcn_s_setprio(0);
                if (t64 * 64 + 63 > qlo) {
#pragma unroll
                    for (int j = 0; j < 4; j++) {
                        const int key = t64 * 64 + j * 16 + l16;
#pragma unroll
                        for (int r = 0; r < 4; r++)
                            if (key > qlo + quad * 4 + r) s[j][r] = -1e30f;
                    }
                }
                ushort* Pw = Pbase + f * (16 * P_STRIDE);
#pragma unroll
                for (int j = 0; j < 4; j++)
#pragma unroll
                    for (int r = 0; r < 4; r++)
                        Pw[(quad * 4 + r) * P_STRIDE + j * 16 + l16] =
                            f32_to_bf16_fast(__builtin_amdgcn_exp2f(s[j][r]));

                const short8 pf0 = *(const short8*)&Pw[l16 * P_STRIDE + quad * 8];
                const short8 pf1 = *(const short8*)&Pw[l16 * P_STRIDE + 32 + quad * 8];
                __builtin_amdgcn_s_setprio(1);
#pragma unroll
                for (int d = 0; d < 4; d++) {
                    accO[f][d] = __builtin_amdgcn_mfma_f32_16x16x32_bf16(pf0, vf[d][0], accO[f][d], 0, 0, 0);
                    accO[f][d] = __builtin_amdgcn_mfma_f32_16x16x32_bf16(pf1, vf[d][1], accO[f][d], 0, 0, 0);
                }
                accL[f] = __builtin_amdgcn_mfma_f32_16x16x32_bf16(pf0, ones, accL[f], 0, 0, 0);
                accL[f] = __builtin_amdgcn_mfma_f32_16x16x32_bf16(pf1, ones, accL[f], 0, 0, 0);
                __builtin_amdgcn_s_setprio(0);
            }
        };

        short8 kfA[4][2], kfB[4][2];
        int t = ts;
        if (t < te) {
            loadK(t, kfA);
            while (true) {
                if (t + 1 < te) loadK(t + 1, kfB);
                body(t, kfA);
                if (++t >= te) break;
                if (t + 1 < te) loadK(t + 1, kfA);
                body(t, kfB);
                if (++t >= te) break;
            }
        }

        // ---- combine 4-way K partials (exact: accumulators are pure sums) ----
        __syncthreads();  // all P-buffer use done; region becomes combine buf
        if (ks) {
            float* cb = cbase + (size_t)((ks - 1) * 128 + rowg * 64 + lane) * 41;
            int idx = 0;
#pragma unroll
            for (int f = 0; f < 2; f++)
#pragma unroll
                for (int d = 0; d < 4; d++)
#pragma unroll
                    for (int r = 0; r < 4; r++) cb[idx++] = accO[f][d][r];
#pragma unroll
            for (int f = 0; f < 2; f++)
#pragma unroll
                for (int r = 0; r < 4; r++) cb[idx++] = accL[f][r];
        }
        __syncthreads();
        if (ks == 0) {
#pragma unroll
            for (int c = 0; c < 3; c++) {
                const float* cb = cbase + (size_t)(c * 128 + rowg * 64 + lane) * 41;
                int idx = 0;
#pragma unroll
                for (int f = 0; f < 2; f++)
#pragma unroll
                    for (int d = 0; d < 4; d++)
#pragma unroll
                        for (int r = 0; r < 4; r++) accO[f][d][r] += cb[idx++];
#pragma unroll
                for (int f = 0; f < 2; f++)
#pragma unroll
                    for (int r = 0; r < 4; r++) accL[f][r] += cb[idx++];
            }
#pragma unroll
            for (int f = 0; f < 2; f++) {
                float inv[4];
#pragma unroll
                for (int r = 0; r < 4; r++) inv[r] = 1.0f / accL[f][r];
#pragma unroll
                for (int d = 0; d < 4; d++)
#pragma unroll
                    for (int r = 0; r < 4; r++)
                        O[(size_t)(b * 2048 + qb + f * 16 + quad * 4 + r) * 1024 + h * 64 + d * 16 + l16] =
                            f32_to_bf16(accO[f][d][r] * inv[r]);
            }
        }
        __syncthreads();  // protect combine region before next phase's P use
    }
}

extern "C" void kernel_launch(void* const* d_in, const int* in_sizes, int n_in,
                              void* d_out, int out_size, void* d_ws, size_t ws_size,
                              hipStream_t stream) {
    const float* x    = (const float*)d_in[0];
    const float* Wqkv = (const float*)d_in[1];
    const float* bqkv = (const float*)d_in[2];
    const float* Wout = (const float*)d_in[3];
    const float* bout = (const float*)d_in[4];
    float* out = (float*)d_out;

    char* ws = (char*)d_ws;
    const size_t MB = 1024 * 1024;
    ushort* Q    = (ushort*)(ws + 0 * MB);
    ushort* Kk   = (ushort*)(ws + 8 * MB);
    ushort* Vt   = (ushort*)(ws + 16 * MB);
    ushort* rawV = (ushort*)(ws + 24 * MB);
    ushort* O    = (ushort*)(ws + 24 * MB);  // overwrites rawV after transpose

    const dim3 blk(256);
    if (ws_size >= 48 * MB) {
        ushort* xb    = (ushort*)(ws + 32 * MB);
        ushort* Wqkvb = (ushort*)(ws + 40 * MB);
        ushort* Woutb = (ushort*)(ws + 46 * MB);
        cvt_bf16<<<dim3(2048), blk, 0, stream>>>(x, xb, 524288);
        cvt_bf16<<<dim3(1536), blk, 0, stream>>>(Wqkv, Wqkvb, 393216);
        cvt_bf16<<<dim3(512),  blk, 0, stream>>>(Wout, Woutb, 131072);
        gemm_bf16<0><<<dim3(32, 24), blk, 0, stream>>>(xb, Wqkvb, bqkv, Q, Kk, rawV,
                                                       nullptr, 4096, 3072, 1024);
        transpose_v<<<dim3(1024), blk, 0, stream>>>(rawV, Vt);
        attn_mfma<<<dim3(512), dim3(512), 0, stream>>>(Q, Kk, Vt, O);
        gemm_bf16<1><<<dim3(32, 8), blk, 0, stream>>>(O, Woutb, bout, nullptr, nullptr,
                                                      nullptr, out, 4096, 1024, 1024);
    } else {
        gemm_bt<0, 1><<<dim3(32, 24), blk, 0, stream>>>(x, Wqkv, bqkv, Q, Kk, rawV,
                                                        nullptr, 4096, 3072, 1024);
        transpose_v<<<dim3(1024), blk, 0, stream>>>(rawV, Vt);
        attn_mfma<<<dim3(512), dim3(512), 0, stream>>>(Q, Kk, Vt, O);
        gemm_bt<1, 0><<<dim3(32, 8), blk, 0, stream>>>(O, Wout, bout, nullptr, nullptr,
                                                       nullptr, out, 4096, 1024, 1024);
    }
}

// Round 4
// 214.869 us; speedup vs baseline: 1.4039x; 1.0555x over previous
//
#include <hip/hip_runtime.h>
#include <hip/hip_bf16.h>
#include <cstdint>

// ---------------------------------------------------------------------------
// MultiHeadAttention: B=2, T=2048, D=1024, H=16, hd=64, causal.
// Inputs (fp32): x[B,T,D], W_qkv[3D,D], b_qkv[3D], W_out[D,D], b_out[D]
// out (fp32): [B,T,D]
// ws big path (48MB): Q@0, K@8M, Vt@16M, rawV/O@24M, xb@32M, Wqkvb@40M, Woutb@46M
// GEMMs: one-shot fp32->bf16 cvt, then m97-style global_load_lds staging.
// Softmax: no-max flash (p = exp2(s) directly), in-lane f32 row-sum.
// Attn v5: swapped QK^T (mfma(K,Q)) puts each q-row's P in one lane ->
// P feeds PV's A-fragment DIRECTLY from registers (cvt_pk pack). The key
// k-slot permutation is baked into Vt's layout at transpose time (MFMA's
// k-dim is permutation-invariant when P-cols and V-rows permute together).
// Zero LDS / zero cross-lane in the K-loop; accL MFMAs replaced by in-lane
// adds + 6 shuffles at epilogue. Skeleton = v1 (best measured): 256-thr
// blocks, 4 indep waves, grid 512, big-first qt remap, K-only double-buffer.
// LESSONS: v2/v4 proved wave-count & balance give ZERO overlap gain here;
// the wall is the per-iteration serial chain. v3: launch_bounds 2nd arg
// acts as min-BLOCKS/CU -> (512,4) = 64-VGPR cap = spill catastrophe.
// ---------------------------------------------------------------------------

using short8  = __attribute__((ext_vector_type(8))) short;
using floatx4 = __attribute__((ext_vector_type(4))) float;

#define LDS_STRIDE 40  // legacy gemm tiles: 32+8 pad

__device__ __forceinline__ float bf16_to_f32(unsigned short u) {
    union { unsigned int i; float f; } v; v.i = ((unsigned int)u) << 16; return v.f;
}
__device__ __forceinline__ unsigned short f32_to_bf16(float f) {
    union { float f; unsigned int i; } v; v.f = f;
    unsigned int x = v.i;
    unsigned int r = x + 0x7FFFu + ((x >> 16) & 1u);  // RNE
    return (unsigned short)(r >> 16);
}
__device__ __forceinline__ unsigned short f32_to_bf16_fast(float f) {
    union { float f; unsigned int i; } v; v.f = f;
    return (unsigned short)((v.i + 0x8000u) >> 16);
}
__device__ __forceinline__ short8 cvt8(const float* __restrict__ p) {
    const float4 f0 = *(const float4*)p;
    const float4 f1 = *(const float4*)(p + 4);
    short8 r;
    r[0] = (short)f32_to_bf16(f0.x); r[1] = (short)f32_to_bf16(f0.y);
    r[2] = (short)f32_to_bf16(f0.z); r[3] = (short)f32_to_bf16(f0.w);
    r[4] = (short)f32_to_bf16(f1.x); r[5] = (short)f32_to_bf16(f1.y);
    r[6] = (short)f32_to_bf16(f1.z); r[7] = (short)f32_to_bf16(f1.w);
    return r;
}
// pack two f32 -> one dword of 2 bf16 (RNE); no builtin on gfx950, pure-VALU asm
__device__ __forceinline__ unsigned int cvtpk(float a, float b) {
    unsigned int r;
    asm("v_cvt_pk_bf16_f32 %0, %1, %2" : "=v"(r) : "v"(a), "v"(b));
    return r;
}

// 1/sqrt(64) * log2(e)
#define Q_PRESCALE 0.1803368801111204f

#if __has_builtin(__builtin_amdgcn_global_load_lds)
#define ASYNC_STAGE 1
typedef const __attribute__((address_space(1))) void* gas1_t;
typedef __attribute__((address_space(3))) void* las3_t;
__device__ __forceinline__ void gload_lds16(const ushort* g, ushort* l) {
    __builtin_amdgcn_global_load_lds((gas1_t)g, (las3_t)l, 16, 0, 0);
}
#else
#define ASYNC_STAGE 0
#endif

// fp32 -> bf16 elementwise, 8 elems/thread
__global__ __launch_bounds__(256, 8) void cvt_bf16(
    const float* __restrict__ in, ushort* __restrict__ out, int n8)
{
    const int i = blockIdx.x * 256 + threadIdx.x;
    if (i < n8) *(short8*)(out + (size_t)i * 8) = cvt8(in + (size_t)i * 8);
}

// ===== m97-style bf16 GEMM: C[M,N] = A[M,K] @ W[N,K]^T + bias[N] =====
// MODE 0: scatter Q (scaled), K, V [bh][t][64] bf16. MODE 1: fp32 Cout.
template <int MODE>
__global__ __launch_bounds__(256, 3) void gemm_bf16(
    const ushort* __restrict__ A, const ushort* __restrict__ W,
    const float* __restrict__ bias,
    ushort* __restrict__ Cq, ushort* __restrict__ Ck, ushort* __restrict__ Cv,
    float* __restrict__ Cout, int M, int N, int K)
{
    // NO padding: stride 32 (global_load_lds dest = uniform base + lane*16B)
    __shared__ __align__(16) ushort As[128 * 32];
    __shared__ __align__(16) ushort Bs[128 * 32];

    const int tid  = threadIdx.x;
    const int lane = tid & 63;
    const int wave = tid >> 6;
    const int wm = (wave >> 1) * 64;
    const int wn = (wave & 1) * 64;
    const int m0 = blockIdx.x * 128;
    const int n0 = blockIdx.y * 128;
    const int quad = lane >> 4;
    const int l16  = lane & 15;

    floatx4 acc[4][4];
#pragma unroll
    for (int i = 0; i < 4; i++)
#pragma unroll
        for (int j = 0; j < 4; j++) acc[i][j] = (floatx4)0.0f;

    // staging map: wave slab = 16 rows; lane -> row (lane>>2), col (lane&3)*8
    const int srow = wave * 16 + (lane >> 2);
    const int scol = (lane & 3) * 8;
    ushort* ldsA0 = &As[wave * 512];
    ushort* ldsA1 = &As[2048 + wave * 512];
    ushort* ldsB0 = &Bs[wave * 512];
    ushort* ldsB1 = &Bs[2048 + wave * 512];
    const ushort* pA0 = A + (size_t)(m0 + srow) * K + scol;
    const ushort* pA1 = pA0 + (size_t)64 * K;
    const ushort* pB0 = W + (size_t)(n0 + srow) * K + scol;
    const ushort* pB1 = pB0 + (size_t)64 * K;

    for (int k0 = 0; k0 < K; k0 += 32) {
#if ASYNC_STAGE
        __syncthreads();  // prev iter's fragment reads done
        gload_lds16(pA0 + k0, ldsA0);
        gload_lds16(pA1 + k0, ldsA1);
        gload_lds16(pB0 + k0, ldsB0);
        gload_lds16(pB1 + k0, ldsB1);
        __syncthreads();  // compiler drains vmcnt before barrier
#else
        const short8 a0 = *(const short8*)(pA0 + k0);
        const short8 a1 = *(const short8*)(pA1 + k0);
        const short8 b0 = *(const short8*)(pB0 + k0);
        const short8 b1 = *(const short8*)(pB1 + k0);
        __syncthreads();
        *(short8*)&As[srow * 32 + scol] = a0;
        *(short8*)&As[(srow + 64) * 32 + scol] = a1;
        *(short8*)&Bs[srow * 32 + scol] = b0;
        *(short8*)&Bs[(srow + 64) * 32 + scol] = b1;
        __syncthreads();
#endif

        short8 af[4], bf[4];
#pragma unroll
        for (int i = 0; i < 4; i++)
            af[i] = *(const short8*)&As[(wm + i * 16 + l16) * 32 + quad * 8];
#pragma unroll
        for (int j = 0; j < 4; j++)
            bf[j] = *(const short8*)&Bs[(wn + j * 16 + l16) * 32 + quad * 8];
#pragma unroll
        for (int i = 0; i < 4; i++)
#pragma unroll
            for (int j = 0; j < 4; j++)
                acc[i][j] = __builtin_amdgcn_mfma_f32_16x16x32_bf16(af[i], bf[j], acc[i][j], 0, 0, 0);
    }

#pragma unroll
    for (int i = 0; i < 4; i++) {
#pragma unroll
        for (int j = 0; j < 4; j++) {
#pragma unroll
            for (int r = 0; r < 4; r++) {
                const int row = m0 + wm + i * 16 + quad * 4 + r;
                const int col = n0 + wn + j * 16 + l16;
                float v = acc[i][j][r] + bias[col];
                if (MODE == 0) {
                    const int h  = col / 192;
                    const int rr = col - h * 192;
                    const int sel = rr >> 6;
                    const int d   = rr & 63;
                    const int b = row >> 11;
                    const int t = row & 2047;
                    const size_t idx = (((size_t)(b * 16 + h)) * 2048 + t) * 64 + d;
                    if (sel == 0)      Cq[idx] = f32_to_bf16(v * Q_PRESCALE);
                    else if (sel == 1) Ck[idx] = f32_to_bf16(v);
                    else               Cv[idx] = f32_to_bf16(v);
                } else {
                    Cout[(size_t)row * N + col] = v;
                }
            }
        }
    }
}

// ===== legacy fused-cvt GEMM (fallback when ws < 48MB) =====
template <int MODE, int AFP32>
__global__ __launch_bounds__(256, 2) void gemm_bt(
    const void* __restrict__ Av, const float* __restrict__ W,
    const float* __restrict__ bias,
    ushort* __restrict__ Cq, ushort* __restrict__ Ck, ushort* __restrict__ Cv,
    float* __restrict__ Cout, int M, int N, int K)
{
    __shared__ __align__(16) ushort As[128 * LDS_STRIDE];
    __shared__ __align__(16) ushort Bs[128 * LDS_STRIDE];

    const int tid  = threadIdx.x;
    const int lane = tid & 63;
    const int wave = tid >> 6;
    const int wm = (wave >> 1) * 64;
    const int wn = (wave & 1) * 64;
    const int m0 = blockIdx.x * 128;
    const int n0 = blockIdx.y * 128;
    const int quad = lane >> 4;
    const int l16  = lane & 15;

    floatx4 acc[4][4];
#pragma unroll
    for (int i = 0; i < 4; i++)
#pragma unroll
        for (int j = 0; j < 4; j++) acc[i][j] = (floatx4)0.0f;

    const int srow = tid >> 2;
    const int scol = (tid & 3) * 8;

    for (int k0 = 0; k0 < K; k0 += 32) {
        short8 a0, a1;
        if (AFP32) {
            const float* A = (const float*)Av;
            a0 = cvt8(A + (size_t)(m0 + srow) * K + k0 + scol);
            a1 = cvt8(A + (size_t)(m0 + srow + 64) * K + k0 + scol);
        } else {
            const ushort* A = (const ushort*)Av;
            a0 = *(const short8*)(A + (size_t)(m0 + srow) * K + k0 + scol);
            a1 = *(const short8*)(A + (size_t)(m0 + srow + 64) * K + k0 + scol);
        }
        const short8 b0 = cvt8(W + (size_t)(n0 + srow) * K + k0 + scol);
        const short8 b1 = cvt8(W + (size_t)(n0 + srow + 64) * K + k0 + scol);
        __syncthreads();
        *(short8*)&As[srow * LDS_STRIDE + scol] = a0;
        *(short8*)&As[(srow + 64) * LDS_STRIDE + scol] = a1;
        *(short8*)&Bs[srow * LDS_STRIDE + scol] = b0;
        *(short8*)&Bs[(srow + 64) * LDS_STRIDE + scol] = b1;
        __syncthreads();

        short8 af[4], bf[4];
#pragma unroll
        for (int i = 0; i < 4; i++)
            af[i] = *(const short8*)&As[(wm + i * 16 + l16) * LDS_STRIDE + quad * 8];
#pragma unroll
        for (int j = 0; j < 4; j++)
            bf[j] = *(const short8*)&Bs[(wn + j * 16 + l16) * LDS_STRIDE + quad * 8];
#pragma unroll
        for (int i = 0; i < 4; i++)
#pragma unroll
            for (int j = 0; j < 4; j++)
                acc[i][j] = __builtin_amdgcn_mfma_f32_16x16x32_bf16(af[i], bf[j], acc[i][j], 0, 0, 0);
    }

#pragma unroll
    for (int i = 0; i < 4; i++) {
#pragma unroll
        for (int j = 0; j < 4; j++) {
#pragma unroll
            for (int r = 0; r < 4; r++) {
                const int row = m0 + wm + i * 16 + quad * 4 + r;
                const int col = n0 + wn + j * 16 + l16;
                float v = acc[i][j][r] + bias[col];
                if (MODE == 0) {
                    const int h  = col / 192;
                    const int rr = col - h * 192;
                    const int sel = rr >> 6;
                    const int d   = rr & 63;
                    const int b = row >> 11;
                    const int t = row & 2047;
                    const size_t idx = (((size_t)(b * 16 + h)) * 2048 + t) * 64 + d;
                    if (sel == 0)      Cq[idx] = f32_to_bf16(v * Q_PRESCALE);
                    else if (sel == 1) Ck[idx] = f32_to_bf16(v);
                    else               Cv[idx] = f32_to_bf16(v);
                } else {
                    Cout[(size_t)row * N + col] = v;
                }
            }
        }
    }
}

// V[bh][t][d] -> Vtp[bh][d][t'] where t' permutes keys within each 32-chunk
// into PV A-fragment slot order: slot s (0..31) holds key
// ((s>>2)&1)*16 + ((s>>3)&3)*4 + (s&3). This bakes the swapped-QK^T lane->key
// mapping into V so attn's PV consumes P directly from registers.
__global__ __launch_bounds__(256, 4) void transpose_v(
    const ushort* __restrict__ V, ushort* __restrict__ Vt)
{
    const int bh = blockIdx.x & 31;
    const int tt = blockIdx.x >> 5;
    const int t0 = tt * 64;
    const int tid = threadIdx.x;
    __shared__ __align__(16) ushort tile[64 * 72];

    const int r = tid >> 2, c = (tid & 3) * 16;
    const ushort* src = V + ((size_t)bh * 2048 + t0 + r) * 64 + c;
    *(short8*)&tile[r * 72 + c]     = *(const short8*)src;
    *(short8*)&tile[r * 72 + c + 8] = *(const short8*)(src + 8);
    __syncthreads();

    const int w = tid >> 6, lane = tid & 63;
    const int d  = w * 16 + (lane >> 2);
    const int tc = (lane & 3) * 16;
    __attribute__((aligned(16))) ushort out[16];
#pragma unroll
    for (int i = 0; i < 16; i++) {
        const int slot = (tc & 31) + i;
        const int key  = ((slot >> 2) & 1) * 16 + ((slot >> 3) & 3) * 4 + (slot & 3);
        out[i] = tile[((tc & 32) + key) * 72 + d];
    }
    ushort* dst = Vt + ((size_t)bh * 64 + d) * 2048 + t0 + tc;
    *(short8*)dst       = *(const short8*)&out[0];
    *(short8*)(dst + 8) = *(const short8*)&out[8];
}

// ===========================================================================
// MFMA causal flash attention, v5 (register-resident P, zero LDS).
// Swapped QK^T: s = mfma(K, Q) -> lane(quad,l16) holds S[key=j*16+quad*4+r]
// [q=l16]. exp2 in-place, cvt_pk to bf16 pairs -> pf0/pf1 are the PV
// A-fragments directly (k-slot permutation matched by Vtp layout).
// L row-sum: in-lane f32 adds; cross-quad reduce + redistribute at epilogue.
// Skeleton = v1: 256-thr blocks (4 indep waves), grid 512 = 32 bh x 16 qt,
// big-first qt remap, K double-buffered in regs, V loaded inside body.
// ===========================================================================
__global__ __launch_bounds__(256, 2) void attn_mfma(
    const ushort* __restrict__ Q, const ushort* __restrict__ K,
    const ushort* __restrict__ Vt, ushort* __restrict__ O)
{
    const int bid   = blockIdx.x;
    const int bh    = bid & 31;
    const int qtIdx = bid >> 5;
    const int qt    = (qtIdx < 8) ? (15 - qtIdx) : (qtIdx - 8);
    const int tid  = threadIdx.x;
    const int wave = tid >> 6;
    const int lane = tid & 63;
    const int quad = lane >> 4;
    const int l16  = lane & 15;
    const int qb   = qt * 128 + wave * 32;

    const size_t kbase  = (size_t)bh * 2048 * 64;
    const size_t vtbase = (size_t)bh * 64 * 2048 + (size_t)l16 * 2048;

    short8 qf0[2], qf1[2];
#pragma unroll
    for (int f = 0; f < 2; f++) {
        const ushort* qp = Q + kbase + (size_t)(qb + f * 16 + l16) * 64 + quad * 8;
        qf0[f] = *(const short8*)qp;
        qf1[f] = *(const short8*)(qp + 32);
    }

    floatx4 accO[2][4];
#pragma unroll
    for (int f = 0; f < 2; f++)
#pragma unroll
        for (int d = 0; d < 4; d++) accO[f][d] = (floatx4)0.0f;
    float accLs[2] = {0.0f, 0.0f};

    auto loadK = [&](int t64, short8 (&kf)[4][2]) {
        const ushort* kp = K + kbase + (size_t)(t64 * 64 + l16) * 64 + quad * 8;
#pragma unroll
        for (int j = 0; j < 4; j++) {
            kf[j][0] = *(const short8*)(kp + j * 1024);
            kf[j][1] = *(const short8*)(kp + j * 1024 + 32);
        }
    };

    union PB { unsigned int u[4]; short8 s8; };

    auto body = [&](int t64, short8 (&kf)[4][2]) {
        short8 vf[4][2];
        const ushort* vp = Vt + vtbase + t64 * 64 + quad * 8;
#pragma unroll
        for (int d = 0; d < 4; d++) {
            vf[d][0] = *(const short8*)(vp + d * 16 * 2048);
            vf[d][1] = *(const short8*)(vp + d * 16 * 2048 + 32);
        }
#pragma unroll
        for (int f = 0; f < 2; f++) {
            const int qlo = qb + f * 16;
            if (t64 * 64 > qlo + 15) continue;  // fully masked fragment
            floatx4 s[4];
#pragma unroll
            for (int j = 0; j < 4; j++) {
                floatx4 t = (floatx4)0.0f;
                t = __builtin_amdgcn_mfma_f32_16x16x32_bf16(kf[j][0], qf0[f], t, 0, 0, 0);
                t = __builtin_amdgcn_mfma_f32_16x16x32_bf16(kf[j][1], qf1[f], t, 0, 0, 0);
                s[j] = t;
            }
            if (t64 * 64 + 63 > qlo) {  // diagonal tile: causal mask
                const int qcol = qlo + l16;
#pragma unroll
                for (int j = 0; j < 4; j++) {
                    const int keyb = t64 * 64 + j * 16 + quad * 4;
#pragma unroll
                    for (int r = 0; r < 4; r++)
                        if (keyb + r > qcol) s[j][r] = -1e30f;
                }
            }
#pragma unroll
            for (int j = 0; j < 4; j++)
#pragma unroll
                for (int r = 0; r < 4; r++)
                    s[j][r] = __builtin_amdgcn_exp2f(s[j][r]);
            const floatx4 ssum = s[0] + s[1] + s[2] + s[3];
            accLs[f] += (ssum[0] + ssum[1]) + (ssum[2] + ssum[3]);
            PB p0, p1;
#pragma unroll
            for (int j = 0; j < 2; j++) {
                p0.u[j * 2 + 0] = cvtpk(s[j][0], s[j][1]);
                p0.u[j * 2 + 1] = cvtpk(s[j][2], s[j][3]);
                p1.u[j * 2 + 0] = cvtpk(s[j + 2][0], s[j + 2][1]);
                p1.u[j * 2 + 1] = cvtpk(s[j + 2][2], s[j + 2][3]);
            }
#pragma unroll
            for (int d = 0; d < 4; d++) {
                accO[f][d] = __builtin_amdgcn_mfma_f32_16x16x32_bf16(p0.s8, vf[d][0], accO[f][d], 0, 0, 0);
                accO[f][d] = __builtin_amdgcn_mfma_f32_16x16x32_bf16(p1.s8, vf[d][1], accO[f][d], 0, 0, 0);
            }
        }
    };

    const int nt = 2 * qt + 2;
    short8 kfA[4][2], kfB[4][2];
    loadK(0, kfA);
    int t = 0;
    while (true) {
        if (t + 1 < nt) loadK(t + 1, kfB);
        body(t, kfA);
        if (++t >= nt) break;
        if (t + 1 < nt) loadK(t + 1, kfA);
        body(t, kfB);
        if (++t >= nt) break;
    }

    const int b = bh >> 4, h = bh & 15;
#pragma unroll
    for (int f = 0; f < 2; f++) {
        // accLs[f] = partial row-sum for q = qb+f*16+l16 over this lane's keys.
        float L = accLs[f];
        L += __shfl_xor(L, 16);
        L += __shfl_xor(L, 32);  // now L(q=l16) in all quads
        float inv[4];
#pragma unroll
        for (int r = 0; r < 4; r++) inv[r] = 1.0f / __shfl(L, quad * 4 + r);
#pragma unroll
        for (int d = 0; d < 4; d++)
#pragma unroll
            for (int r = 0; r < 4; r++)
                O[(size_t)(b * 2048 + qb + f * 16 + quad * 4 + r) * 1024 + h * 64 + d * 16 + l16] =
                    f32_to_bf16(accO[f][d][r] * inv[r]);
    }
}

extern "C" void kernel_launch(void* const* d_in, const int* in_sizes, int n_in,
                              void* d_out, int out_size, void* d_ws, size_t ws_size,
                              hipStream_t stream) {
    const float* x    = (const float*)d_in[0];
    const float* Wqkv = (const float*)d_in[1];
    const float* bqkv = (const float*)d_in[2];
    const float* Wout = (const float*)d_in[3];
    const float* bout = (const float*)d_in[4];
    float* out = (float*)d_out;

    char* ws = (char*)d_ws;
    const size_t MB = 1024 * 1024;
    ushort* Q    = (ushort*)(ws + 0 * MB);
    ushort* Kk   = (ushort*)(ws + 8 * MB);
    ushort* Vt   = (ushort*)(ws + 16 * MB);
    ushort* rawV = (ushort*)(ws + 24 * MB);
    ushort* O    = (ushort*)(ws + 24 * MB);  // overwrites rawV after transpose

    const dim3 blk(256);
    if (ws_size >= 48 * MB) {
        ushort* xb    = (ushort*)(ws + 32 * MB);
        ushort* Wqkvb = (ushort*)(ws + 40 * MB);
        ushort* Woutb = (ushort*)(ws + 46 * MB);
        cvt_bf16<<<dim3(2048), blk, 0, stream>>>(x, xb, 524288);
        cvt_bf16<<<dim3(1536), blk, 0, stream>>>(Wqkv, Wqkvb, 393216);
        cvt_bf16<<<dim3(512),  blk, 0, stream>>>(Wout, Woutb, 131072);
        gemm_bf16<0><<<dim3(32, 24), blk, 0, stream>>>(xb, Wqkvb, bqkv, Q, Kk, rawV,
                                                       nullptr, 4096, 3072, 1024);
        transpose_v<<<dim3(1024), blk, 0, stream>>>(rawV, Vt);
        attn_mfma<<<dim3(512), blk, 0, stream>>>(Q, Kk, Vt, O);
        gemm_bf16<1><<<dim3(32, 8), blk, 0, stream>>>(O, Woutb, bout, nullptr, nullptr,
                                                      nullptr, out, 4096, 1024, 1024);
    } else {
        gemm_bt<0, 1><<<dim3(32, 24), blk, 0, stream>>>(x, Wqkv, bqkv, Q, Kk, rawV,
                                                        nullptr, 4096, 3072, 1024);
        transpose_v<<<dim3(1024), blk, 0, stream>>>(rawV, Vt);
        attn_mfma<<<dim3(512), blk, 0, stream>>>(Q, Kk, Vt, O);
        gemm_bt<1, 0><<<dim3(32, 8), blk, 0, stream>>>(O, Wout, bout, nullptr, nullptr,
                                                       nullptr, out, 4096, 1024, 1024);
    }
}

// Round 6
// 184.291 us; speedup vs baseline: 1.6368x; 1.1659x over previous
//
#include <hip/hip_runtime.h>
#include <hip/hip_bf16.h>
#include <cstdint>

// ---------------------------------------------------------------------------
// MultiHeadAttention: B=2, T=2048, D=1024, H=16, hd=64, causal.
// Inputs (fp32): x[B,T,D], W_qkv[3D,D], b_qkv[3D], W_out[D,D], b_out[D]
// out (fp32): [B,T,D]
// ws big path (48MB): Q@0, K@8M, Vt@16M, rawV/O@24M, xb@32M, Wqkvb@40M, Woutb@46M
// GEMMs: one-shot fp32->bf16 cvt, then m97-style global_load_lds staging.
// Softmax: no-max flash (p = exp2(s) directly), in-lane f32 row-sum.
// Attn v6: v5's register-P body + LDS-staged K/V tiles.
//  - v5 proved the P-LDS roundtrip was NOT the bottleneck (69.2 -> 68.3us).
//  - Diagnosis: K/V fragment loads = 16 scattered 64B txns per dwordx4 inst,
//    and all 4 waves of a block loaded the SAME tiles (4x redundant) ->
//    ~1024 txns/block-iter; vmcnt stall ~75% of time. v4 (more waves,
//    distinct K-slices) made it worse -> txn/L1-thrash bound.
//  - Fix: tile-blocked Vtb[bh][t][d][slot] (contig 8KB tiles), stage K+V via
//    global_load_lds (coalesced, once per block), ds_read_b128 fragments with
//    XOR chunk-swizzle baked into the GLOBAL source (linear LDS dest, rule:
//    swizzle both-sides-or-neither) -> 2-way bank aliasing = free.
//  - R5 lesson: hipcc's HOST pass lacks the builtin -> gload_lds16 must be
//    defined unconditionally with the #if inside the body, not at call sites.
// LESSONS: launch_bounds 2nd arg acts as min-BLOCKS/CU ((512,4) = 64-VGPR
// cap = spill catastrophe); wave-count/balance give zero overlap gain here.
// ---------------------------------------------------------------------------

using short8  = __attribute__((ext_vector_type(8))) short;
using floatx4 = __attribute__((ext_vector_type(4))) float;

#define LDS_STRIDE 40  // legacy gemm tiles: 32+8 pad

__device__ __forceinline__ float bf16_to_f32(unsigned short u) {
    union { unsigned int i; float f; } v; v.i = ((unsigned int)u) << 16; return v.f;
}
__device__ __forceinline__ unsigned short f32_to_bf16(float f) {
    union { float f; unsigned int i; } v; v.f = f;
    unsigned int x = v.i;
    unsigned int r = x + 0x7FFFu + ((x >> 16) & 1u);  // RNE
    return (unsigned short)(r >> 16);
}
__device__ __forceinline__ unsigned short f32_to_bf16_fast(float f) {
    union { float f; unsigned int i; } v; v.f = f;
    return (unsigned short)((v.i + 0x8000u) >> 16);
}
__device__ __forceinline__ short8 cvt8(const float* __restrict__ p) {
    const float4 f0 = *(const float4*)p;
    const float4 f1 = *(const float4*)(p + 4);
    short8 r;
    r[0] = (short)f32_to_bf16(f0.x); r[1] = (short)f32_to_bf16(f0.y);
    r[2] = (short)f32_to_bf16(f0.z); r[3] = (short)f32_to_bf16(f0.w);
    r[4] = (short)f32_to_bf16(f1.x); r[5] = (short)f32_to_bf16(f1.y);
    r[6] = (short)f32_to_bf16(f1.z); r[7] = (short)f32_to_bf16(f1.w);
    return r;
}
// pack two f32 -> one dword of 2 bf16 (RNE); no builtin on gfx950, pure-VALU asm
__device__ __forceinline__ unsigned int cvtpk(float a, float b) {
    unsigned int r;
    asm("v_cvt_pk_bf16_f32 %0, %1, %2" : "=v"(r) : "v"(a), "v"(b));
    return r;
}

// 1/sqrt(64) * log2(e)
#define Q_PRESCALE 0.1803368801111204f

#if __has_builtin(__builtin_amdgcn_global_load_lds)
#define ASYNC_STAGE 1
typedef const __attribute__((address_space(1))) void* gas1_t;
typedef __attribute__((address_space(3))) void* las3_t;
#else
#define ASYNC_STAGE 0
#endif

// Defined unconditionally: hipcc's host pass lacks the builtin, so the #if
// must live INSIDE the body (placeholder branch never executes on device).
__device__ __forceinline__ void gload_lds16(const ushort* g, ushort* l) {
#if ASYNC_STAGE
    __builtin_amdgcn_global_load_lds((gas1_t)g, (las3_t)l, 16, 0, 0);
#else
    *(short8*)l = *(const short8*)g;  // host-pass placeholder
#endif
}

// fp32 -> bf16 elementwise, 8 elems/thread
__global__ __launch_bounds__(256, 8) void cvt_bf16(
    const float* __restrict__ in, ushort* __restrict__ out, int n8)
{
    const int i = blockIdx.x * 256 + threadIdx.x;
    if (i < n8) *(short8*)(out + (size_t)i * 8) = cvt8(in + (size_t)i * 8);
}

// ===== m97-style bf16 GEMM: C[M,N] = A[M,K] @ W[N,K]^T + bias[N] =====
// MODE 0: scatter Q (scaled), K, V [bh][t][64] bf16. MODE 1: fp32 Cout.
template <int MODE>
__global__ __launch_bounds__(256, 3) void gemm_bf16(
    const ushort* __restrict__ A, const ushort* __restrict__ W,
    const float* __restrict__ bias,
    ushort* __restrict__ Cq, ushort* __restrict__ Ck, ushort* __restrict__ Cv,
    float* __restrict__ Cout, int M, int N, int K)
{
    // NO padding: stride 32 (global_load_lds dest = uniform base + lane*16B)
    __shared__ __align__(16) ushort As[128 * 32];
    __shared__ __align__(16) ushort Bs[128 * 32];

    const int tid  = threadIdx.x;
    const int lane = tid & 63;
    const int wave = tid >> 6;
    const int wm = (wave >> 1) * 64;
    const int wn = (wave & 1) * 64;
    const int m0 = blockIdx.x * 128;
    const int n0 = blockIdx.y * 128;
    const int quad = lane >> 4;
    const int l16  = lane & 15;

    floatx4 acc[4][4];
#pragma unroll
    for (int i = 0; i < 4; i++)
#pragma unroll
        for (int j = 0; j < 4; j++) acc[i][j] = (floatx4)0.0f;

    // staging map: wave slab = 16 rows; lane -> row (lane>>2), col (lane&3)*8
    const int srow = wave * 16 + (lane >> 2);
    const int scol = (lane & 3) * 8;
    ushort* ldsA0 = &As[wave * 512];
    ushort* ldsA1 = &As[2048 + wave * 512];
    ushort* ldsB0 = &Bs[wave * 512];
    ushort* ldsB1 = &Bs[2048 + wave * 512];
    const ushort* pA0 = A + (size_t)(m0 + srow) * K + scol;
    const ushort* pA1 = pA0 + (size_t)64 * K;
    const ushort* pB0 = W + (size_t)(n0 + srow) * K + scol;
    const ushort* pB1 = pB0 + (size_t)64 * K;

    for (int k0 = 0; k0 < K; k0 += 32) {
#if ASYNC_STAGE
        __syncthreads();  // prev iter's fragment reads done
        gload_lds16(pA0 + k0, ldsA0);
        gload_lds16(pA1 + k0, ldsA1);
        gload_lds16(pB0 + k0, ldsB0);
        gload_lds16(pB1 + k0, ldsB1);
        __syncthreads();  // compiler drains vmcnt before barrier
#else
        const short8 a0 = *(const short8*)(pA0 + k0);
        const short8 a1 = *(const short8*)(pA1 + k0);
        const short8 b0 = *(const short8*)(pB0 + k0);
        const short8 b1 = *(const short8*)(pB1 + k0);
        __syncthreads();
        *(short8*)&As[srow * 32 + scol] = a0;
        *(short8*)&As[(srow + 64) * 32 + scol] = a1;
        *(short8*)&Bs[srow * 32 + scol] = b0;
        *(short8*)&Bs[(srow + 64) * 32 + scol] = b1;
        __syncthreads();
#endif

        short8 af[4], bf[4];
#pragma unroll
        for (int i = 0; i < 4; i++)
            af[i] = *(const short8*)&As[(wm + i * 16 + l16) * 32 + quad * 8];
#pragma unroll
        for (int j = 0; j < 4; j++)
            bf[j] = *(const short8*)&Bs[(wn + j * 16 + l16) * 32 + quad * 8];
#pragma unroll
        for (int i = 0; i < 4; i++)
#pragma unroll
            for (int j = 0; j < 4; j++)
                acc[i][j] = __builtin_amdgcn_mfma_f32_16x16x32_bf16(af[i], bf[j], acc[i][j], 0, 0, 0);
    }

#pragma unroll
    for (int i = 0; i < 4; i++) {
#pragma unroll
        for (int j = 0; j < 4; j++) {
#pragma unroll
            for (int r = 0; r < 4; r++) {
                const int row = m0 + wm + i * 16 + quad * 4 + r;
                const int col = n0 + wn + j * 16 + l16;
                float v = acc[i][j][r] + bias[col];
                if (MODE == 0) {
                    const int h  = col / 192;
                    const int rr = col - h * 192;
                    const int sel = rr >> 6;
                    const int d   = rr & 63;
                    const int b = row >> 11;
                    const int t = row & 2047;
                    const size_t idx = (((size_t)(b * 16 + h)) * 2048 + t) * 64 + d;
                    if (sel == 0)      Cq[idx] = f32_to_bf16(v * Q_PRESCALE);
                    else if (sel == 1) Ck[idx] = f32_to_bf16(v);
                    else               Cv[idx] = f32_to_bf16(v);
                } else {
                    Cout[(size_t)row * N + col] = v;
                }
            }
        }
    }
}

// ===== legacy fused-cvt GEMM (fallback when ws < 48MB) =====
template <int MODE, int AFP32>
__global__ __launch_bounds__(256, 2) void gemm_bt(
    const void* __restrict__ Av, const float* __restrict__ W,
    const float* __restrict__ bias,
    ushort* __restrict__ Cq, ushort* __restrict__ Ck, ushort* __restrict__ Cv,
    float* __restrict__ Cout, int M, int N, int K)
{
    __shared__ __align__(16) ushort As[128 * LDS_STRIDE];
    __shared__ __align__(16) ushort Bs[128 * LDS_STRIDE];

    const int tid  = threadIdx.x;
    const int lane = tid & 63;
    const int wave = tid >> 6;
    const int wm = (wave >> 1) * 64;
    const int wn = (wave & 1) * 64;
    const int m0 = blockIdx.x * 128;
    const int n0 = blockIdx.y * 128;
    const int quad = lane >> 4;
    const int l16  = lane & 15;

    floatx4 acc[4][4];
#pragma unroll
    for (int i = 0; i < 4; i++)
#pragma unroll
        for (int j = 0; j < 4; j++) acc[i][j] = (floatx4)0.0f;

    const int srow = tid >> 2;
    const int scol = (tid & 3) * 8;

    for (int k0 = 0; k0 < K; k0 += 32) {
        short8 a0, a1;
        if (AFP32) {
            const float* A = (const float*)Av;
            a0 = cvt8(A + (size_t)(m0 + srow) * K + k0 + scol);
            a1 = cvt8(A + (size_t)(m0 + srow + 64) * K + k0 + scol);
        } else {
            const ushort* A = (const ushort*)Av;
            a0 = *(const short8*)(A + (size_t)(m0 + srow) * K + k0 + scol);
            a1 = *(const short8*)(A + (size_t)(m0 + srow + 64) * K + k0 + scol);
        }
        const short8 b0 = cvt8(W + (size_t)(n0 + srow) * K + k0 + scol);
        const short8 b1 = cvt8(W + (size_t)(n0 + srow + 64) * K + k0 + scol);
        __syncthreads();
        *(short8*)&As[srow * LDS_STRIDE + scol] = a0;
        *(short8*)&As[(srow + 64) * LDS_STRIDE + scol] = a1;
        *(short8*)&Bs[srow * LDS_STRIDE + scol] = b0;
        *(short8*)&Bs[(srow + 64) * LDS_STRIDE + scol] = b1;
        __syncthreads();

        short8 af[4], bf[4];
#pragma unroll
        for (int i = 0; i < 4; i++)
            af[i] = *(const short8*)&As[(wm + i * 16 + l16) * LDS_STRIDE + quad * 8];
#pragma unroll
        for (int j = 0; j < 4; j++)
            bf[j] = *(const short8*)&Bs[(wn + j * 16 + l16) * LDS_STRIDE + quad * 8];
#pragma unroll
        for (int i = 0; i < 4; i++)
#pragma unroll
            for (int j = 0; j < 4; j++)
                acc[i][j] = __builtin_amdgcn_mfma_f32_16x16x32_bf16(af[i], bf[j], acc[i][j], 0, 0, 0);
    }

#pragma unroll
    for (int i = 0; i < 4; i++) {
#pragma unroll
        for (int j = 0; j < 4; j++) {
#pragma unroll
            for (int r = 0; r < 4; r++) {
                const int row = m0 + wm + i * 16 + quad * 4 + r;
                const int col = n0 + wn + j * 16 + l16;
                float v = acc[i][j][r] + bias[col];
                if (MODE == 0) {
                    const int h  = col / 192;
                    const int rr = col - h * 192;
                    const int sel = rr >> 6;
                    const int d   = rr & 63;
                    const int b = row >> 11;
                    const int t = row & 2047;
                    const size_t idx = (((size_t)(b * 16 + h)) * 2048 + t) * 64 + d;
                    if (sel == 0)      Cq[idx] = f32_to_bf16(v * Q_PRESCALE);
                    else if (sel == 1) Ck[idx] = f32_to_bf16(v);
                    else               Cv[idx] = f32_to_bf16(v);
                } else {
                    Cout[(size_t)row * N + col] = v;
                }
            }
        }
    }
}

// V[bh][t][d] -> tile-blocked Vtb[bh][t64][d][slot'] where within each tile
// slot' permutes keys into PV A-fragment k-slot order: slot s (0..31 per
// 32-half) holds key ((s>>2)&1)*16 + ((s>>3)&3)*4 + (s&3). Each 64-key tile
// is a contiguous 8KB block (coalesced staging in attn).
__global__ __launch_bounds__(256, 4) void transpose_v(
    const ushort* __restrict__ V, ushort* __restrict__ Vt)
{
    const int bh = blockIdx.x & 31;
    const int tt = blockIdx.x >> 5;
    const int t0 = tt * 64;
    const int tid = threadIdx.x;
    __shared__ __align__(16) ushort tile[64 * 72];

    const int r = tid >> 2, c = (tid & 3) * 16;
    const ushort* src = V + ((size_t)bh * 2048 + t0 + r) * 64 + c;
    *(short8*)&tile[r * 72 + c]     = *(const short8*)src;
    *(short8*)&tile[r * 72 + c + 8] = *(const short8*)(src + 8);
    __syncthreads();

    const int w = tid >> 6, lane = tid & 63;
    const int d  = w * 16 + (lane >> 2);
    const int tc = (lane & 3) * 16;
    __attribute__((aligned(16))) ushort out[16];
#pragma unroll
    for (int i = 0; i < 16; i++) {
        const int slot = (tc & 31) + i;
        const int key  = ((slot >> 2) & 1) * 16 + ((slot >> 3) & 3) * 4 + (slot & 3);
        out[i] = tile[((tc & 32) + key) * 72 + d];
    }
    // tile-blocked dst: Vtb[((bh*32 + tt)*64 + d)*64 + tc]
    ushort* dst = Vt + ((size_t)(bh * 32 + tt) * 64 + d) * 64 + tc;
    *(short8*)dst       = *(const short8*)&out[0];
    *(short8*)(dst + 8) = *(const short8*)&out[8];
}

// ===========================================================================
// MFMA causal flash attention, v6 (register-P + LDS-staged K/V tiles).
// Per block-iteration: 256 threads stage the 8KB K-tile + 8KB V-tile once
// (global_load_lds, fully coalesced, XOR-chunk-swizzled source so swizzled
// ds_read_b128 fragment reads are bank-conflict-free), then 4 waves consume
// from LDS. Replaces 4x-redundant 16-segment-scattered register loads that
// left the kernel ~75% vmcnt-stalled (v1/v5 ~4.8k SIMD-cyc/iter).
// Body math = v5: swapped QK^T (mfma(K,Q)) -> lane-resident P -> cvt_pk ->
// PV directly from registers; in-lane L sum, shuffle-redistribute epilogue.
// Grid 512 = 32 bh x 16 qt (big-first), 256 thr, 2 barriers/iter.
// ===========================================================================
__global__ __launch_bounds__(256, 2) void attn_mfma(
    const ushort* __restrict__ Q, const ushort* __restrict__ K,
    const ushort* __restrict__ Vtb, ushort* __restrict__ O)
{
    const int bid   = blockIdx.x;
    const int bh    = bid & 31;
    const int qtIdx = bid >> 5;
    const int qt    = (qtIdx < 8) ? (15 - qtIdx) : (qtIdx - 8);
    const int tid  = threadIdx.x;
    const int wave = tid >> 6;
    const int lane = tid & 63;
    const int quad = lane >> 4;
    const int l16  = lane & 15;
    const int qb   = qt * 128 + wave * 32;

    __shared__ __align__(16) ushort Ks[4096];  // 64 rows x 64 ush (swizzled)
    __shared__ __align__(16) ushort Vs[4096];

    const size_t kbase = (size_t)bh * 2048 * 64;

    // ---- staging maps (loop-invariant). Thread covers LDS bytes
    // [tid*16,+16) and [tid*16+4096,+16); LDS dest is linear (gload_lds
    // scatters lane*16 from a wave-uniform base). Source is chunk-swizzled:
    // physical (row r, chunk c) holds logical (r, c ^ (r&7)).
    const int ob0 = tid * 16, ob1 = ob0 + 4096;
    const int r0 = ob0 >> 7, c0 = (ob0 >> 4) & 7;
    const int r1 = ob1 >> 7, c1 = (ob1 >> 4) & 7;
    const int e0 = r0 * 64 + ((c0 ^ (r0 & 7)) << 3);  // ushort idx in tile
    const int e1 = r1 * 64 + ((c1 ^ (r1 & 7)) << 3);
    ushort* dK0 = &Ks[wave * 512];
    ushort* dK1 = &Ks[2048 + wave * 512];
    ushort* dV0 = &Vs[wave * 512];
    ushort* dV1 = &Vs[2048 + wave * 512];
    const ushort* Kb = K + kbase;                         // + t*4096 + e
    const ushort* Vb = Vtb + (size_t)bh * 32 * 4096;      // + t*4096 + e

    // ---- swizzled fragment read offsets: logical (row, chunk C) is at
    // ushort idx row*64 + ((C ^ (row&7))<<3); row = <grp>*16 + l16.
    const int sw0 = ((quad ^ (l16 & 7)) << 3);        // half 0: C = quad
    const int sw1 = (((4 + quad) ^ (l16 & 7)) << 3);  // half 1: C = 4+quad
    const int rbase = l16 * 64;

    short8 qf0[2], qf1[2];
#pragma unroll
    for (int f = 0; f < 2; f++) {
        const ushort* qp = Q + kbase + (size_t)(qb + f * 16 + l16) * 64 + quad * 8;
        qf0[f] = *(const short8*)qp;
        qf1[f] = *(const short8*)(qp + 32);
    }

    floatx4 accO[2][4];
#pragma unroll
    for (int f = 0; f < 2; f++)
#pragma unroll
        for (int d = 0; d < 4; d++) accO[f][d] = (floatx4)0.0f;
    float accLs[2] = {0.0f, 0.0f};

    union PB { unsigned int u[4]; short8 s8; };

    const int nt = 2 * qt + 2;
    for (int t = 0; t < nt; ++t) {
        __syncthreads();  // prev iter's ds_reads done
        const ushort* Ktile = Kb + t * 4096;
        const ushort* Vtile = Vb + t * 4096;
        gload_lds16(Ktile + e0, dK0);
        gload_lds16(Ktile + e1, dK1);
        gload_lds16(Vtile + e0, dV0);
        gload_lds16(Vtile + e1, dV1);
        __syncthreads();  // compiler drains vmcnt before barrier

        short8 kf[4][2], vf[4][2];
#pragma unroll
        for (int j = 0; j < 4; j++) {
            kf[j][0] = *(const short8*)&Ks[j * 1024 + rbase + sw0];
            kf[j][1] = *(const short8*)&Ks[j * 1024 + rbase + sw1];
        }
#pragma unroll
        for (int d = 0; d < 4; d++) {
            vf[d][0] = *(const short8*)&Vs[d * 1024 + rbase + sw0];
            vf[d][1] = *(const short8*)&Vs[d * 1024 + rbase + sw1];
        }

#pragma unroll
        for (int f = 0; f < 2; f++) {
            const int qlo = qb + f * 16;
            if (t * 64 > qlo + 15) continue;  // fully masked fragment
            floatx4 s[4];
#pragma unroll
            for (int j = 0; j < 4; j++) {
                floatx4 acc = (floatx4)0.0f;
                acc = __builtin_amdgcn_mfma_f32_16x16x32_bf16(kf[j][0], qf0[f], acc, 0, 0, 0);
                acc = __builtin_amdgcn_mfma_f32_16x16x32_bf16(kf[j][1], qf1[f], acc, 0, 0, 0);
                s[j] = acc;
            }
            if (t * 64 + 63 > qlo) {  // diagonal tile: causal mask
                const int qcol = qlo + l16;
#pragma unroll
                for (int j = 0; j < 4; j++) {
                    const int keyb = t * 64 + j * 16 + quad * 4;
#pragma unroll
                    for (int r = 0; r < 4; r++)
                        if (keyb + r > qcol) s[j][r] = -1e30f;
                }
            }
#pragma unroll
            for (int j = 0; j < 4; j++)
#pragma unroll
                for (int r = 0; r < 4; r++)
                    s[j][r] = __builtin_amdgcn_exp2f(s[j][r]);
            const floatx4 ssum = s[0] + s[1] + s[2] + s[3];
            accLs[f] += (ssum[0] + ssum[1]) + (ssum[2] + ssum[3]);
            PB p0, p1;
#pragma unroll
            for (int j = 0; j < 2; j++) {
                p0.u[j * 2 + 0] = cvtpk(s[j][0], s[j][1]);
                p0.u[j * 2 + 1] = cvtpk(s[j][2], s[j][3]);
                p1.u[j * 2 + 0] = cvtpk(s[j + 2][0], s[j + 2][1]);
                p1.u[j * 2 + 1] = cvtpk(s[j + 2][2], s[j + 2][3]);
            }
#pragma unroll
            for (int d = 0; d < 4; d++) {
                accO[f][d] = __builtin_amdgcn_mfma_f32_16x16x32_bf16(p0.s8, vf[d][0], accO[f][d], 0, 0, 0);
                accO[f][d] = __builtin_amdgcn_mfma_f32_16x16x32_bf16(p1.s8, vf[d][1], accO[f][d], 0, 0, 0);
            }
        }
    }

    const int b = bh >> 4, h = bh & 15;
#pragma unroll
    for (int f = 0; f < 2; f++) {
        // accLs[f] = partial row-sum for q = qb+f*16+l16 over this lane's keys.
        float L = accLs[f];
        L += __shfl_xor(L, 16);
        L += __shfl_xor(L, 32);  // now L(q=l16) in all quads
        float inv[4];
#pragma unroll
        for (int r = 0; r < 4; r++) inv[r] = 1.0f / __shfl(L, quad * 4 + r);
#pragma unroll
        for (int d = 0; d < 4; d++)
#pragma unroll
            for (int r = 0; r < 4; r++)
                O[(size_t)(b * 2048 + qb + f * 16 + quad * 4 + r) * 1024 + h * 64 + d * 16 + l16] =
                    f32_to_bf16(accO[f][d][r] * inv[r]);
    }
}

extern "C" void kernel_launch(void* const* d_in, const int* in_sizes, int n_in,
                              void* d_out, int out_size, void* d_ws, size_t ws_size,
                              hipStream_t stream) {
    const float* x    = (const float*)d_in[0];
    const float* Wqkv = (const float*)d_in[1];
    const float* bqkv = (const float*)d_in[2];
    const float* Wout = (const float*)d_in[3];
    const float* bout = (const float*)d_in[4];
    float* out = (float*)d_out;

    char* ws = (char*)d_ws;
    const size_t MB = 1024 * 1024;
    ushort* Q    = (ushort*)(ws + 0 * MB);
    ushort* Kk   = (ushort*)(ws + 8 * MB);
    ushort* Vt   = (ushort*)(ws + 16 * MB);
    ushort* rawV = (ushort*)(ws + 24 * MB);
    ushort* O    = (ushort*)(ws + 24 * MB);  // overwrites rawV after transpose

    const dim3 blk(256);
    if (ws_size >= 48 * MB) {
        ushort* xb    = (ushort*)(ws + 32 * MB);
        ushort* Wqkvb = (ushort*)(ws + 40 * MB);
        ushort* Woutb = (ushort*)(ws + 46 * MB);
        cvt_bf16<<<dim3(2048), blk, 0, stream>>>(x, xb, 524288);
        cvt_bf16<<<dim3(1536), blk, 0, stream>>>(Wqkv, Wqkvb, 393216);
        cvt_bf16<<<dim3(512),  blk, 0, stream>>>(Wout, Woutb, 131072);
        gemm_bf16<0><<<dim3(32, 24), blk, 0, stream>>>(xb, Wqkvb, bqkv, Q, Kk, rawV,
                                                       nullptr, 4096, 3072, 1024);
        transpose_v<<<dim3(1024), blk, 0, stream>>>(rawV, Vt);
        attn_mfma<<<dim3(512), blk, 0, stream>>>(Q, Kk, Vt, O);
        gemm_bf16<1><<<dim3(32, 8), blk, 0, stream>>>(O, Woutb, bout, nullptr, nullptr,
                                                      nullptr, out, 4096, 1024, 1024);
    } else {
        gemm_bt<0, 1><<<dim3(32, 24), blk, 0, stream>>>(x, Wqkv, bqkv, Q, Kk, rawV,
                                                        nullptr, 4096, 3072, 1024);
        transpose_v<<<dim3(1024), blk, 0, stream>>>(rawV, Vt);
        attn_mfma<<<dim3(512), blk, 0, stream>>>(Q, Kk, Vt, O);
        gemm_bt<1, 0><<<dim3(32, 8), blk, 0, stream>>>(O, Wout, bout, nullptr, nullptr,
                                                       nullptr, out, 4096, 1024, 1024);
    }
}

// Round 7
// 177.522 us; speedup vs baseline: 1.6992x; 1.0381x over previous
//
#include <hip/hip_runtime.h>
#include <hip/hip_bf16.h>
#include <cstdint>

// ---------------------------------------------------------------------------
// MultiHeadAttention: B=2, T=2048, D=1024, H=16, hd=64, causal.
// Inputs (fp32): x[B,T,D], W_qkv[3D,D], b_qkv[3D], W_out[D,D], b_out[D]
// out (fp32): [B,T,D]
// ws big path (48MB): Q@0, K@8M, Vt@16M, rawV/O@24M, xb@32M, Wqkvb@40M, Woutb@46M
// GEMMs: one-shot fp32->bf16 cvt (single fused kernel), m97-style staging.
// Softmax: no-max flash (p = exp2(s) directly), in-lane f32 row-sum.
// Attn v7 = v6 + double-buffered K/V LDS staging (T3 minimum 2-phase):
//  prefetch tile t+1 issued BEFORE compute(t) -> HBM/L2 latency hides under
//  MFMA/VALU; one __syncthreads per iter (auto-drain then ~free) vs two.
//  v6 (coalesced once-per-block staging) took attn 68.3 -> ~38us, total 184.
// LESSONS: launch_bounds 2nd arg acts as min-BLOCKS/CU ((512,4) = 64-VGPR cap
// = spill catastrophe); wave-count/balance give zero overlap gain (v2/v4);
// P-LDS roundtrip was not the wall (v5); K/V txn pattern was (v6); hipcc host
// pass lacks gfx950 builtins -> #if must be inside function bodies (R5).
// ---------------------------------------------------------------------------

using short8  = __attribute__((ext_vector_type(8))) short;
using floatx4 = __attribute__((ext_vector_type(4))) float;

#define LDS_STRIDE 40  // legacy gemm tiles: 32+8 pad

__device__ __forceinline__ float bf16_to_f32(unsigned short u) {
    union { unsigned int i; float f; } v; v.i = ((unsigned int)u) << 16; return v.f;
}
__device__ __forceinline__ unsigned short f32_to_bf16(float f) {
    union { float f; unsigned int i; } v; v.f = f;
    unsigned int x = v.i;
    unsigned int r = x + 0x7FFFu + ((x >> 16) & 1u);  // RNE
    return (unsigned short)(r >> 16);
}
__device__ __forceinline__ unsigned short f32_to_bf16_fast(float f) {
    union { float f; unsigned int i; } v; v.f = f;
    return (unsigned short)((v.i + 0x8000u) >> 16);
}
__device__ __forceinline__ short8 cvt8(const float* __restrict__ p) {
    const float4 f0 = *(const float4*)p;
    const float4 f1 = *(const float4*)(p + 4);
    short8 r;
    r[0] = (short)f32_to_bf16(f0.x); r[1] = (short)f32_to_bf16(f0.y);
    r[2] = (short)f32_to_bf16(f0.z); r[3] = (short)f32_to_bf16(f0.w);
    r[4] = (short)f32_to_bf16(f1.x); r[5] = (short)f32_to_bf16(f1.y);
    r[6] = (short)f32_to_bf16(f1.z); r[7] = (short)f32_to_bf16(f1.w);
    return r;
}
// pack two f32 -> one dword of 2 bf16 (RNE); no builtin on gfx950, pure-VALU asm
__device__ __forceinline__ unsigned int cvtpk(float a, float b) {
    unsigned int r;
    asm("v_cvt_pk_bf16_f32 %0, %1, %2" : "=v"(r) : "v"(a), "v"(b));
    return r;
}

// 1/sqrt(64) * log2(e)
#define Q_PRESCALE 0.1803368801111204f

#if __has_builtin(__builtin_amdgcn_global_load_lds)
#define ASYNC_STAGE 1
typedef const __attribute__((address_space(1))) void* gas1_t;
typedef __attribute__((address_space(3))) void* las3_t;
#else
#define ASYNC_STAGE 0
#endif

// Defined unconditionally: hipcc's host pass lacks the builtin, so the #if
// must live INSIDE the body (placeholder branch never executes on device).
__device__ __forceinline__ void gload_lds16(const ushort* g, ushort* l) {
#if ASYNC_STAGE
    __builtin_amdgcn_global_load_lds((gas1_t)g, (las3_t)l, 16, 0, 0);
#else
    *(short8*)l = *(const short8*)g;  // host-pass placeholder
#endif
}

// fused fp32 -> bf16 for x / W_qkv / W_out, 8 elems/thread, one launch.
// Range boundaries are block-aligned: 524288 = 2048*256, 917504 = 3584*256.
__global__ __launch_bounds__(256, 8) void cvt_bf16_3(
    const float* __restrict__ x,  const float* __restrict__ wq,
    const float* __restrict__ wo, ushort* __restrict__ xb,
    ushort* __restrict__ wqb, ushort* __restrict__ wob)
{
    const int i = blockIdx.x * 256 + threadIdx.x;  // 0..1048575
    const float* src; ushort* dst; int off;
    if (i < 524288)      { src = x;  dst = xb;  off = i; }
    else if (i < 917504) { src = wq; dst = wqb; off = i - 524288; }
    else                 { src = wo; dst = wob; off = i - 917504; }
    *(short8*)(dst + (size_t)off * 8) = cvt8(src + (size_t)off * 8);
}

// ===== m97-style bf16 GEMM: C[M,N] = A[M,K] @ W[N,K]^T + bias[N] =====
// MODE 0: scatter Q (scaled), K, V [bh][t][64] bf16. MODE 1: fp32 Cout.
template <int MODE>
__global__ __launch_bounds__(256, 3) void gemm_bf16(
    const ushort* __restrict__ A, const ushort* __restrict__ W,
    const float* __restrict__ bias,
    ushort* __restrict__ Cq, ushort* __restrict__ Ck, ushort* __restrict__ Cv,
    float* __restrict__ Cout, int M, int N, int K)
{
    // NO padding: stride 32 (global_load_lds dest = uniform base + lane*16B)
    __shared__ __align__(16) ushort As[128 * 32];
    __shared__ __align__(16) ushort Bs[128 * 32];

    const int tid  = threadIdx.x;
    const int lane = tid & 63;
    const int wave = tid >> 6;
    const int wm = (wave >> 1) * 64;
    const int wn = (wave & 1) * 64;
    const int m0 = blockIdx.x * 128;
    const int n0 = blockIdx.y * 128;
    const int quad = lane >> 4;
    const int l16  = lane & 15;

    floatx4 acc[4][4];
#pragma unroll
    for (int i = 0; i < 4; i++)
#pragma unroll
        for (int j = 0; j < 4; j++) acc[i][j] = (floatx4)0.0f;

    // staging map: wave slab = 16 rows; lane -> row (lane>>2), col (lane&3)*8
    const int srow = wave * 16 + (lane >> 2);
    const int scol = (lane & 3) * 8;
    ushort* ldsA0 = &As[wave * 512];
    ushort* ldsA1 = &As[2048 + wave * 512];
    ushort* ldsB0 = &Bs[wave * 512];
    ushort* ldsB1 = &Bs[2048 + wave * 512];
    const ushort* pA0 = A + (size_t)(m0 + srow) * K + scol;
    const ushort* pA1 = pA0 + (size_t)64 * K;
    const ushort* pB0 = W + (size_t)(n0 + srow) * K + scol;
    const ushort* pB1 = pB0 + (size_t)64 * K;

    for (int k0 = 0; k0 < K; k0 += 32) {
#if ASYNC_STAGE
        __syncthreads();  // prev iter's fragment reads done
        gload_lds16(pA0 + k0, ldsA0);
        gload_lds16(pA1 + k0, ldsA1);
        gload_lds16(pB0 + k0, ldsB0);
        gload_lds16(pB1 + k0, ldsB1);
        __syncthreads();  // compiler drains vmcnt before barrier
#else
        const short8 a0 = *(const short8*)(pA0 + k0);
        const short8 a1 = *(const short8*)(pA1 + k0);
        const short8 b0 = *(const short8*)(pB0 + k0);
        const short8 b1 = *(const short8*)(pB1 + k0);
        __syncthreads();
        *(short8*)&As[srow * 32 + scol] = a0;
        *(short8*)&As[(srow + 64) * 32 + scol] = a1;
        *(short8*)&Bs[srow * 32 + scol] = b0;
        *(short8*)&Bs[(srow + 64) * 32 + scol] = b1;
        __syncthreads();
#endif

        short8 af[4], bf[4];
#pragma unroll
        for (int i = 0; i < 4; i++)
            af[i] = *(const short8*)&As[(wm + i * 16 + l16) * 32 + quad * 8];
#pragma unroll
        for (int j = 0; j < 4; j++)
            bf[j] = *(const short8*)&Bs[(wn + j * 16 + l16) * 32 + quad * 8];
#pragma unroll
        for (int i = 0; i < 4; i++)
#pragma unroll
            for (int j = 0; j < 4; j++)
                acc[i][j] = __builtin_amdgcn_mfma_f32_16x16x32_bf16(af[i], bf[j], acc[i][j], 0, 0, 0);
    }

#pragma unroll
    for (int i = 0; i < 4; i++) {
#pragma unroll
        for (int j = 0; j < 4; j++) {
#pragma unroll
            for (int r = 0; r < 4; r++) {
                const int row = m0 + wm + i * 16 + quad * 4 + r;
                const int col = n0 + wn + j * 16 + l16;
                float v = acc[i][j][r] + bias[col];
                if (MODE == 0) {
                    const int h  = col / 192;
                    const int rr = col - h * 192;
                    const int sel = rr >> 6;
                    const int d   = rr & 63;
                    const int b = row >> 11;
                    const int t = row & 2047;
                    const size_t idx = (((size_t)(b * 16 + h)) * 2048 + t) * 64 + d;
                    if (sel == 0)      Cq[idx] = f32_to_bf16(v * Q_PRESCALE);
                    else if (sel == 1) Ck[idx] = f32_to_bf16(v);
                    else               Cv[idx] = f32_to_bf16(v);
                } else {
                    Cout[(size_t)row * N + col] = v;
                }
            }
        }
    }
}

// ===== legacy fused-cvt GEMM (fallback when ws < 48MB) =====
template <int MODE, int AFP32>
__global__ __launch_bounds__(256, 2) void gemm_bt(
    const void* __restrict__ Av, const float* __restrict__ W,
    const float* __restrict__ bias,
    ushort* __restrict__ Cq, ushort* __restrict__ Ck, ushort* __restrict__ Cv,
    float* __restrict__ Cout, int M, int N, int K)
{
    __shared__ __align__(16) ushort As[128 * LDS_STRIDE];
    __shared__ __align__(16) ushort Bs[128 * LDS_STRIDE];

    const int tid  = threadIdx.x;
    const int lane = tid & 63;
    const int wave = tid >> 6;
    const int wm = (wave >> 1) * 64;
    const int wn = (wave & 1) * 64;
    const int m0 = blockIdx.x * 128;
    const int n0 = blockIdx.y * 128;
    const int quad = lane >> 4;
    const int l16  = lane & 15;

    floatx4 acc[4][4];
#pragma unroll
    for (int i = 0; i < 4; i++)
#pragma unroll
        for (int j = 0; j < 4; j++) acc[i][j] = (floatx4)0.0f;

    const int srow = tid >> 2;
    const int scol = (tid & 3) * 8;

    for (int k0 = 0; k0 < K; k0 += 32) {
        short8 a0, a1;
        if (AFP32) {
            const float* A = (const float*)Av;
            a0 = cvt8(A + (size_t)(m0 + srow) * K + k0 + scol);
            a1 = cvt8(A + (size_t)(m0 + srow + 64) * K + k0 + scol);
        } else {
            const ushort* A = (const ushort*)Av;
            a0 = *(const short8*)(A + (size_t)(m0 + srow) * K + k0 + scol);
            a1 = *(const short8*)(A + (size_t)(m0 + srow + 64) * K + k0 + scol);
        }
        const short8 b0 = cvt8(W + (size_t)(n0 + srow) * K + k0 + scol);
        const short8 b1 = cvt8(W + (size_t)(n0 + srow + 64) * K + k0 + scol);
        __syncthreads();
        *(short8*)&As[srow * LDS_STRIDE + scol] = a0;
        *(short8*)&As[(srow + 64) * LDS_STRIDE + scol] = a1;
        *(short8*)&Bs[srow * LDS_STRIDE + scol] = b0;
        *(short8*)&Bs[(srow + 64) * LDS_STRIDE + scol] = b1;
        __syncthreads();

        short8 af[4], bf[4];
#pragma unroll
        for (int i = 0; i < 4; i++)
            af[i] = *(const short8*)&As[(wm + i * 16 + l16) * LDS_STRIDE + quad * 8];
#pragma unroll
        for (int j = 0; j < 4; j++)
            bf[j] = *(const short8*)&Bs[(wn + j * 16 + l16) * LDS_STRIDE + quad * 8];
#pragma unroll
        for (int i = 0; i < 4; i++)
#pragma unroll
            for (int j = 0; j < 4; j++)
                acc[i][j] = __builtin_amdgcn_mfma_f32_16x16x32_bf16(af[i], bf[j], acc[i][j], 0, 0, 0);
    }

#pragma unroll
    for (int i = 0; i < 4; i++) {
#pragma unroll
        for (int j = 0; j < 4; j++) {
#pragma unroll
            for (int r = 0; r < 4; r++) {
                const int row = m0 + wm + i * 16 + quad * 4 + r;
                const int col = n0 + wn + j * 16 + l16;
                float v = acc[i][j][r] + bias[col];
                if (MODE == 0) {
                    const int h  = col / 192;
                    const int rr = col - h * 192;
                    const int sel = rr >> 6;
                    const int d   = rr & 63;
                    const int b = row >> 11;
                    const int t = row & 2047;
                    const size_t idx = (((size_t)(b * 16 + h)) * 2048 + t) * 64 + d;
                    if (sel == 0)      Cq[idx] = f32_to_bf16(v * Q_PRESCALE);
                    else if (sel == 1) Ck[idx] = f32_to_bf16(v);
                    else               Cv[idx] = f32_to_bf16(v);
                } else {
                    Cout[(size_t)row * N + col] = v;
                }
            }
        }
    }
}

// V[bh][t][d] -> tile-blocked Vtb[bh][t64][d][slot'] where within each tile
// slot' permutes keys into PV A-fragment k-slot order: slot s (0..31 per
// 32-half) holds key ((s>>2)&1)*16 + ((s>>3)&3)*4 + (s&3). Each 64-key tile
// is a contiguous 8KB block (coalesced staging in attn).
__global__ __launch_bounds__(256, 4) void transpose_v(
    const ushort* __restrict__ V, ushort* __restrict__ Vt)
{
    const int bh = blockIdx.x & 31;
    const int tt = blockIdx.x >> 5;
    const int t0 = tt * 64;
    const int tid = threadIdx.x;
    __shared__ __align__(16) ushort tile[64 * 72];

    const int r = tid >> 2, c = (tid & 3) * 16;
    const ushort* src = V + ((size_t)bh * 2048 + t0 + r) * 64 + c;
    *(short8*)&tile[r * 72 + c]     = *(const short8*)src;
    *(short8*)&tile[r * 72 + c + 8] = *(const short8*)(src + 8);
    __syncthreads();

    const int w = tid >> 6, lane = tid & 63;
    const int d  = w * 16 + (lane >> 2);
    const int tc = (lane & 3) * 16;
    __attribute__((aligned(16))) ushort out[16];
#pragma unroll
    for (int i = 0; i < 16; i++) {
        const int slot = (tc & 31) + i;
        const int key  = ((slot >> 2) & 1) * 16 + ((slot >> 3) & 3) * 4 + (slot & 3);
        out[i] = tile[((tc & 32) + key) * 72 + d];
    }
    // tile-blocked dst: Vtb[((bh*32 + tt)*64 + d)*64 + tc]
    ushort* dst = Vt + ((size_t)(bh * 32 + tt) * 64 + d) * 64 + tc;
    *(short8*)dst       = *(const short8*)&out[0];
    *(short8*)(dst + 8) = *(const short8*)&out[8];
}

// ===========================================================================
// MFMA causal flash attention, v7 (v6 + double-buffered LDS staging).
// Per iter: issue prefetch(t+1) into alt buffer -> ds_read+compute(t) ->
// one __syncthreads (drain ~free: loads had the whole compute to land).
// Staging coalesced once-per-block via global_load_lds; XOR-chunk-swizzled
// source so swizzled ds_read_b128 fragment reads are conflict-free.
// Body: swapped QK^T (mfma(K,Q)) -> lane-resident P -> cvt_pk -> PV directly
// from registers; in-lane L sum, shuffle-redistribute epilogue.
// Grid 512 = 32 bh x 16 qt (big-first), 256 thr, LDS 32KB.
// ===========================================================================
__global__ __launch_bounds__(256, 2) void attn_mfma(
    const ushort* __restrict__ Q, const ushort* __restrict__ K,
    const ushort* __restrict__ Vtb, ushort* __restrict__ O)
{
    const int bid   = blockIdx.x;
    const int bh    = bid & 31;
    const int qtIdx = bid >> 5;
    const int qt    = (qtIdx < 8) ? (15 - qtIdx) : (qtIdx - 8);
    const int tid  = threadIdx.x;
    const int wave = tid >> 6;
    const int lane = tid & 63;
    const int quad = lane >> 4;
    const int l16  = lane & 15;
    const int qb   = qt * 128 + wave * 32;

    __shared__ __align__(16) ushort Ks[2][4096];  // 64 rows x 64 ush (swizzled)
    __shared__ __align__(16) ushort Vs[2][4096];

    const size_t kbase = (size_t)bh * 2048 * 64;

    // ---- staging maps (loop-invariant). Thread covers LDS bytes
    // [tid*16,+16) and [tid*16+4096,+16) of each tile; LDS dest is linear
    // (gload_lds scatters lane*16 from a wave-uniform base). Source is
    // chunk-swizzled: physical (row r, chunk c) holds logical (r, c^(r&7)).
    const int ob0 = tid * 16, ob1 = ob0 + 4096;
    const int r0 = ob0 >> 7, c0 = (ob0 >> 4) & 7;
    const int r1 = ob1 >> 7, c1 = (ob1 >> 4) & 7;
    const int e0 = r0 * 64 + ((c0 ^ (r0 & 7)) << 3);  // ushort idx in tile
    const int e1 = r1 * 64 + ((c1 ^ (r1 & 7)) << 3);
    const ushort* Kb = K + kbase;                         // + t*4096 + e
    const ushort* Vb = Vtb + (size_t)bh * 32 * 4096;      // + t*4096 + e

    auto stage = [&](int t, ushort* KsB, ushort* VsB) {
        const ushort* Ktile = Kb + t * 4096;
        const ushort* Vtile = Vb + t * 4096;
        gload_lds16(Ktile + e0, KsB + wave * 512);
        gload_lds16(Ktile + e1, KsB + 2048 + wave * 512);
        gload_lds16(Vtile + e0, VsB + wave * 512);
        gload_lds16(Vtile + e1, VsB + 2048 + wave * 512);
    };

    // ---- swizzled fragment read offsets: logical (row, chunk C) is at
    // ushort idx row*64 + ((C ^ (row&7))<<3); row = <grp>*16 + l16.
    const int sw0 = ((quad ^ (l16 & 7)) << 3);        // half 0: C = quad
    const int sw1 = (((4 + quad) ^ (l16 & 7)) << 3);  // half 1: C = 4+quad
    const int rbase = l16 * 64;

    short8 qf0[2], qf1[2];
#pragma unroll
    for (int f = 0; f < 2; f++) {
        const ushort* qp = Q + kbase + (size_t)(qb + f * 16 + l16) * 64 + quad * 8;
        qf0[f] = *(const short8*)qp;
        qf1[f] = *(const short8*)(qp + 32);
    }

    floatx4 accO[2][4];
#pragma unroll
    for (int f = 0; f < 2; f++)
#pragma unroll
        for (int d = 0; d < 4; d++) accO[f][d] = (floatx4)0.0f;
    float accLs[2] = {0.0f, 0.0f};

    union PB { unsigned int u[4]; short8 s8; };

    auto compute = [&](int t, const ushort* KsB, const ushort* VsB) {
        short8 kf[4][2], vf[4][2];
#pragma unroll
        for (int j = 0; j < 4; j++) {
            kf[j][0] = *(const short8*)&KsB[j * 1024 + rbase + sw0];
            kf[j][1] = *(const short8*)&KsB[j * 1024 + rbase + sw1];
        }
#pragma unroll
        for (int d = 0; d < 4; d++) {
            vf[d][0] = *(const short8*)&VsB[d * 1024 + rbase + sw0];
            vf[d][1] = *(const short8*)&VsB[d * 1024 + rbase + sw1];
        }

#pragma unroll
        for (int f = 0; f < 2; f++) {
            const int qlo = qb + f * 16;
            if (t * 64 > qlo + 15) continue;  // fully masked fragment
            floatx4 s[4];
#pragma unroll
            for (int j = 0; j < 4; j++) {
                floatx4 acc = (floatx4)0.0f;
                acc = __builtin_amdgcn_mfma_f32_16x16x32_bf16(kf[j][0], qf0[f], acc, 0, 0, 0);
                acc = __builtin_amdgcn_mfma_f32_16x16x32_bf16(kf[j][1], qf1[f], acc, 0, 0, 0);
                s[j] = acc;
            }
            if (t * 64 + 63 > qlo) {  // diagonal tile: causal mask
                const int qcol = qlo + l16;
#pragma unroll
                for (int j = 0; j < 4; j++) {
                    const int keyb = t * 64 + j * 16 + quad * 4;
#pragma unroll
                    for (int r = 0; r < 4; r++)
                        if (keyb + r > qcol) s[j][r] = -1e30f;
                }
            }
#pragma unroll
            for (int j = 0; j < 4; j++)
#pragma unroll
                for (int r = 0; r < 4; r++)
                    s[j][r] = __builtin_amdgcn_exp2f(s[j][r]);
            const floatx4 ssum = s[0] + s[1] + s[2] + s[3];
            accLs[f] += (ssum[0] + ssum[1]) + (ssum[2] + ssum[3]);
            PB p0, p1;
#pragma unroll
            for (int j = 0; j < 2; j++) {
                p0.u[j * 2 + 0] = cvtpk(s[j][0], s[j][1]);
                p0.u[j * 2 + 1] = cvtpk(s[j][2], s[j][3]);
                p1.u[j * 2 + 0] = cvtpk(s[j + 2][0], s[j + 2][1]);
                p1.u[j * 2 + 1] = cvtpk(s[j + 2][2], s[j + 2][3]);
            }
#pragma unroll
            for (int d = 0; d < 4; d++) {
                accO[f][d] = __builtin_amdgcn_mfma_f32_16x16x32_bf16(p0.s8, vf[d][0], accO[f][d], 0, 0, 0);
                accO[f][d] = __builtin_amdgcn_mfma_f32_16x16x32_bf16(p1.s8, vf[d][1], accO[f][d], 0, 0, 0);
            }
        }
    };

    const int nt = 2 * qt + 2;  // >= 2 always
    stage(0, Ks[0], Vs[0]);
    __syncthreads();            // buf0 staged
    int t = 0;
    while (true) {
        if (t + 1 < nt) stage(t + 1, Ks[1], Vs[1]);  // prefetch under compute
        compute(t, Ks[0], Vs[0]);
        __syncthreads();        // prefetch landed + all waves done with buf0
        if (++t >= nt) break;
        if (t + 1 < nt) stage(t + 1, Ks[0], Vs[0]);
        compute(t, Ks[1], Vs[1]);
        __syncthreads();
        if (++t >= nt) break;
    }

    const int b = bh >> 4, h = bh & 15;
#pragma unroll
    for (int f = 0; f < 2; f++) {
        // accLs[f] = partial row-sum for q = qb+f*16+l16 over this lane's keys.
        float L = accLs[f];
        L += __shfl_xor(L, 16);
        L += __shfl_xor(L, 32);  // now L(q=l16) in all quads
        float inv[4];
#pragma unroll
        for (int r = 0; r < 4; r++) inv[r] = 1.0f / __shfl(L, quad * 4 + r);
#pragma unroll
        for (int d = 0; d < 4; d++)
#pragma unroll
            for (int r = 0; r < 4; r++)
                O[(size_t)(b * 2048 + qb + f * 16 + quad * 4 + r) * 1024 + h * 64 + d * 16 + l16] =
                    f32_to_bf16(accO[f][d][r] * inv[r]);
    }
}

extern "C" void kernel_launch(void* const* d_in, const int* in_sizes, int n_in,
                              void* d_out, int out_size, void* d_ws, size_t ws_size,
                              hipStream_t stream) {
    const float* x    = (const float*)d_in[0];
    const float* Wqkv = (const float*)d_in[1];
    const float* bqkv = (const float*)d_in[2];
    const float* Wout = (const float*)d_in[3];
    const float* bout = (const float*)d_in[4];
    float* out = (float*)d_out;

    char* ws = (char*)d_ws;
    const size_t MB = 1024 * 1024;
    ushort* Q    = (ushort*)(ws + 0 * MB);
    ushort* Kk   = (ushort*)(ws + 8 * MB);
    ushort* Vt   = (ushort*)(ws + 16 * MB);
    ushort* rawV = (ushort*)(ws + 24 * MB);
    ushort* O    = (ushort*)(ws + 24 * MB);  // overwrites rawV after transpose

    const dim3 blk(256);
    if (ws_size >= 48 * MB) {
        ushort* xb    = (ushort*)(ws + 32 * MB);
        ushort* Wqkvb = (ushort*)(ws + 40 * MB);
        ushort* Woutb = (ushort*)(ws + 46 * MB);
        cvt_bf16_3<<<dim3(4096), blk, 0, stream>>>(x, Wqkv, Wout, xb, Wqkvb, Woutb);
        gemm_bf16<0><<<dim3(32, 24), blk, 0, stream>>>(xb, Wqkvb, bqkv, Q, Kk, rawV,
                                                       nullptr, 4096, 3072, 1024);
        transpose_v<<<dim3(1024), blk, 0, stream>>>(rawV, Vt);
        attn_mfma<<<dim3(512), blk, 0, stream>>>(Q, Kk, Vt, O);
        gemm_bf16<1><<<dim3(32, 8), blk, 0, stream>>>(O, Woutb, bout, nullptr, nullptr,
                                                      nullptr, out, 4096, 1024, 1024);
    } else {
        gemm_bt<0, 1><<<dim3(32, 24), blk, 0, stream>>>(x, Wqkv, bqkv, Q, Kk, rawV,
                                                        nullptr, 4096, 3072, 1024);
        transpose_v<<<dim3(1024), blk, 0, stream>>>(rawV, Vt);
        attn_mfma<<<dim3(512), blk, 0, stream>>>(Q, Kk, Vt, O);
        gemm_bt<1, 0><<<dim3(32, 8), blk, 0, stream>>>(O, Wout, bout, nullptr, nullptr,
                                                       nullptr, out, 4096, 1024, 1024);
    }
}

// Round 8
// 173.072 us; speedup vs baseline: 1.7429x; 1.0257x over previous
//
#include <hip/hip_runtime.h>
#include <hip/hip_bf16.h>
#include <cstdint>

// ---------------------------------------------------------------------------
// MultiHeadAttention: B=2, T=2048, D=1024, H=16, hd=64, causal.
// Inputs (fp32): x[B,T,D], W_qkv[3D,D], b_qkv[3D], W_out[D,D], b_out[D]
// out (fp32): [B,T,D]
// ws big path (48MB): Q@0, K@8M, Vtb@16M, O@24M, xb@32M, Wqkvb@40M, Woutb@46M
// GEMMs: one-shot fp32->bf16 cvt (single fused kernel), m97-style staging.
// Softmax: no-max flash (p = exp2(s) directly), in-lane f32 row-sum.
// v8: (1) transpose_v FUSED into QKV-GEMM epilogue (inverse slot map:
//     slot(k) = (k&32) + ((k>>4)&1)*4 + ((k>>2)&3)*8 + (k&3)) -> kernel,
//     launch gap, and 16MB rawV roundtrip all gone.
//     (2) attn KVBLK=128: two 64-key sub-tiles per staged dbuf -> half the
//     barriers/drain windows; LDS 64KB, still 2 blocks/CU.
// History: v6 coalesced once-per-block LDS staging (attn 68->38us, total 184);
// v7 dbuf staging + fused cvt (total 177.5).
// LESSONS: launch_bounds 2nd arg acts as min-BLOCKS/CU ((512,4) = 64-VGPR cap
// = spill catastrophe); wave-count/balance give zero overlap gain (v2/v4);
// P-LDS roundtrip was not the wall (v5); K/V txn pattern was (v6); hipcc host
// pass lacks gfx950 builtins -> #if must be inside function bodies (R5).
// ---------------------------------------------------------------------------

using short8  = __attribute__((ext_vector_type(8))) short;
using floatx4 = __attribute__((ext_vector_type(4))) float;

#define LDS_STRIDE 40  // legacy gemm tiles: 32+8 pad

__device__ __forceinline__ float bf16_to_f32(unsigned short u) {
    union { unsigned int i; float f; } v; v.i = ((unsigned int)u) << 16; return v.f;
}
__device__ __forceinline__ unsigned short f32_to_bf16(float f) {
    union { float f; unsigned int i; } v; v.f = f;
    unsigned int x = v.i;
    unsigned int r = x + 0x7FFFu + ((x >> 16) & 1u);  // RNE
    return (unsigned short)(r >> 16);
}
__device__ __forceinline__ short8 cvt8(const float* __restrict__ p) {
    const float4 f0 = *(const float4*)p;
    const float4 f1 = *(const float4*)(p + 4);
    short8 r;
    r[0] = (short)f32_to_bf16(f0.x); r[1] = (short)f32_to_bf16(f0.y);
    r[2] = (short)f32_to_bf16(f0.z); r[3] = (short)f32_to_bf16(f0.w);
    r[4] = (short)f32_to_bf16(f1.x); r[5] = (short)f32_to_bf16(f1.y);
    r[6] = (short)f32_to_bf16(f1.z); r[7] = (short)f32_to_bf16(f1.w);
    return r;
}
// pack two f32 -> one dword of 2 bf16 (RNE); no builtin on gfx950, pure-VALU asm
__device__ __forceinline__ unsigned int cvtpk(float a, float b) {
    unsigned int r;
    asm("v_cvt_pk_bf16_f32 %0, %1, %2" : "=v"(r) : "v"(a), "v"(b));
    return r;
}

// 1/sqrt(64) * log2(e)
#define Q_PRESCALE 0.1803368801111204f

#if __has_builtin(__builtin_amdgcn_global_load_lds)
#define ASYNC_STAGE 1
typedef const __attribute__((address_space(1))) void* gas1_t;
typedef __attribute__((address_space(3))) void* las3_t;
#else
#define ASYNC_STAGE 0
#endif

// Defined unconditionally: hipcc's host pass lacks the builtin, so the #if
// must live INSIDE the body (placeholder branch never executes on device).
__device__ __forceinline__ void gload_lds16(const ushort* g, ushort* l) {
#if ASYNC_STAGE
    __builtin_amdgcn_global_load_lds((gas1_t)g, (las3_t)l, 16, 0, 0);
#else
    *(short8*)l = *(const short8*)g;  // host-pass placeholder
#endif
}

// inverse of transpose_v's slot->key map: which Vtb slot holds key k (0..63)
__device__ __forceinline__ int v_slot(int k) {
    const int k5 = k & 31;
    return (k & 32) + ((k5 >> 4) & 1) * 4 + ((k5 >> 2) & 3) * 8 + (k5 & 3);
}

// fused fp32 -> bf16 for x / W_qkv / W_out, 8 elems/thread, one launch.
// Range boundaries are block-aligned: 524288 = 2048*256, 917504 = 3584*256.
__global__ __launch_bounds__(256, 8) void cvt_bf16_3(
    const float* __restrict__ x,  const float* __restrict__ wq,
    const float* __restrict__ wo, ushort* __restrict__ xb,
    ushort* __restrict__ wqb, ushort* __restrict__ wob)
{
    const int i = blockIdx.x * 256 + threadIdx.x;  // 0..1048575
    const float* src; ushort* dst; int off;
    if (i < 524288)      { src = x;  dst = xb;  off = i; }
    else if (i < 917504) { src = wq; dst = wqb; off = i - 524288; }
    else                 { src = wo; dst = wob; off = i - 917504; }
    *(short8*)(dst + (size_t)off * 8) = cvt8(src + (size_t)off * 8);
}

// ===== m97-style bf16 GEMM: C[M,N] = A[M,K] @ W[N,K]^T + bias[N] =====
// MODE 0: scatter Q (scaled), K [bh][t][64]; V directly into tile-blocked
// permuted Vtb[bh][t64][d][slot] (transpose_v fused). MODE 1: fp32 Cout.
template <int MODE>
__global__ __launch_bounds__(256, 3) void gemm_bf16(
    const ushort* __restrict__ A, const ushort* __restrict__ W,
    const float* __restrict__ bias,
    ushort* __restrict__ Cq, ushort* __restrict__ Ck, ushort* __restrict__ Cv,
    float* __restrict__ Cout, int M, int N, int K)
{
    // NO padding: stride 32 (global_load_lds dest = uniform base + lane*16B)
    __shared__ __align__(16) ushort As[128 * 32];
    __shared__ __align__(16) ushort Bs[128 * 32];

    const int tid  = threadIdx.x;
    const int lane = tid & 63;
    const int wave = tid >> 6;
    const int wm = (wave >> 1) * 64;
    const int wn = (wave & 1) * 64;
    const int m0 = blockIdx.x * 128;
    const int n0 = blockIdx.y * 128;
    const int quad = lane >> 4;
    const int l16  = lane & 15;

    floatx4 acc[4][4];
#pragma unroll
    for (int i = 0; i < 4; i++)
#pragma unroll
        for (int j = 0; j < 4; j++) acc[i][j] = (floatx4)0.0f;

    // staging map: wave slab = 16 rows; lane -> row (lane>>2), col (lane&3)*8
    const int srow = wave * 16 + (lane >> 2);
    const int scol = (lane & 3) * 8;
    ushort* ldsA0 = &As[wave * 512];
    ushort* ldsA1 = &As[2048 + wave * 512];
    ushort* ldsB0 = &Bs[wave * 512];
    ushort* ldsB1 = &Bs[2048 + wave * 512];
    const ushort* pA0 = A + (size_t)(m0 + srow) * K + scol;
    const ushort* pA1 = pA0 + (size_t)64 * K;
    const ushort* pB0 = W + (size_t)(n0 + srow) * K + scol;
    const ushort* pB1 = pB0 + (size_t)64 * K;

    for (int k0 = 0; k0 < K; k0 += 32) {
#if ASYNC_STAGE
        __syncthreads();  // prev iter's fragment reads done
        gload_lds16(pA0 + k0, ldsA0);
        gload_lds16(pA1 + k0, ldsA1);
        gload_lds16(pB0 + k0, ldsB0);
        gload_lds16(pB1 + k0, ldsB1);
        __syncthreads();  // compiler drains vmcnt before barrier
#else
        const short8 a0 = *(const short8*)(pA0 + k0);
        const short8 a1 = *(const short8*)(pA1 + k0);
        const short8 b0 = *(const short8*)(pB0 + k0);
        const short8 b1 = *(const short8*)(pB1 + k0);
        __syncthreads();
        *(short8*)&As[srow * 32 + scol] = a0;
        *(short8*)&As[(srow + 64) * 32 + scol] = a1;
        *(short8*)&Bs[srow * 32 + scol] = b0;
        *(short8*)&Bs[(srow + 64) * 32 + scol] = b1;
        __syncthreads();
#endif

        short8 af[4], bf[4];
#pragma unroll
        for (int i = 0; i < 4; i++)
            af[i] = *(const short8*)&As[(wm + i * 16 + l16) * 32 + quad * 8];
#pragma unroll
        for (int j = 0; j < 4; j++)
            bf[j] = *(const short8*)&Bs[(wn + j * 16 + l16) * 32 + quad * 8];
#pragma unroll
        for (int i = 0; i < 4; i++)
#pragma unroll
            for (int j = 0; j < 4; j++)
                acc[i][j] = __builtin_amdgcn_mfma_f32_16x16x32_bf16(af[i], bf[j], acc[i][j], 0, 0, 0);
    }

#pragma unroll
    for (int i = 0; i < 4; i++) {
#pragma unroll
        for (int j = 0; j < 4; j++) {
#pragma unroll
            for (int r = 0; r < 4; r++) {
                const int row = m0 + wm + i * 16 + quad * 4 + r;
                const int col = n0 + wn + j * 16 + l16;
                float v = acc[i][j][r] + bias[col];
                if (MODE == 0) {
                    const int h  = col / 192;
                    const int rr = col - h * 192;
                    const int sel = rr >> 6;
                    const int d   = rr & 63;
                    const int b = row >> 11;
                    const int t = row & 2047;
                    const int bh = b * 16 + h;
                    if (sel == 0) {
                        Cq[(((size_t)bh) * 2048 + t) * 64 + d] =
                            f32_to_bf16(v * Q_PRESCALE);
                    } else if (sel == 1) {
                        Ck[(((size_t)bh) * 2048 + t) * 64 + d] = f32_to_bf16(v);
                    } else {
                        // fused transpose_v: Vtb[bh][t>>6][d][slot(t&63)]
                        Cv[(((size_t)bh * 32 + (t >> 6)) * 64 + d) * 64 + v_slot(t & 63)] =
                            f32_to_bf16(v);
                    }
                } else {
                    Cout[(size_t)row * N + col] = v;
                }
            }
        }
    }
}

// ===== legacy fused-cvt GEMM (fallback when ws < 48MB) =====
template <int MODE, int AFP32>
__global__ __launch_bounds__(256, 2) void gemm_bt(
    const void* __restrict__ Av, const float* __restrict__ W,
    const float* __restrict__ bias,
    ushort* __restrict__ Cq, ushort* __restrict__ Ck, ushort* __restrict__ Cv,
    float* __restrict__ Cout, int M, int N, int K)
{
    __shared__ __align__(16) ushort As[128 * LDS_STRIDE];
    __shared__ __align__(16) ushort Bs[128 * LDS_STRIDE];

    const int tid  = threadIdx.x;
    const int lane = tid & 63;
    const int wave = tid >> 6;
    const int wm = (wave >> 1) * 64;
    const int wn = (wave & 1) * 64;
    const int m0 = blockIdx.x * 128;
    const int n0 = blockIdx.y * 128;
    const int quad = lane >> 4;
    const int l16  = lane & 15;

    floatx4 acc[4][4];
#pragma unroll
    for (int i = 0; i < 4; i++)
#pragma unroll
        for (int j = 0; j < 4; j++) acc[i][j] = (floatx4)0.0f;

    const int srow = tid >> 2;
    const int scol = (tid & 3) * 8;

    for (int k0 = 0; k0 < K; k0 += 32) {
        short8 a0, a1;
        if (AFP32) {
            const float* A = (const float*)Av;
            a0 = cvt8(A + (size_t)(m0 + srow) * K + k0 + scol);
            a1 = cvt8(A + (size_t)(m0 + srow + 64) * K + k0 + scol);
        } else {
            const ushort* A = (const ushort*)Av;
            a0 = *(const short8*)(A + (size_t)(m0 + srow) * K + k0 + scol);
            a1 = *(const short8*)(A + (size_t)(m0 + srow + 64) * K + k0 + scol);
        }
        const short8 b0 = cvt8(W + (size_t)(n0 + srow) * K + k0 + scol);
        const short8 b1 = cvt8(W + (size_t)(n0 + srow + 64) * K + k0 + scol);
        __syncthreads();
        *(short8*)&As[srow * LDS_STRIDE + scol] = a0;
        *(short8*)&As[(srow + 64) * LDS_STRIDE + scol] = a1;
        *(short8*)&Bs[srow * LDS_STRIDE + scol] = b0;
        *(short8*)&Bs[(srow + 64) * LDS_STRIDE + scol] = b1;
        __syncthreads();

        short8 af[4], bf[4];
#pragma unroll
        for (int i = 0; i < 4; i++)
            af[i] = *(const short8*)&As[(wm + i * 16 + l16) * LDS_STRIDE + quad * 8];
#pragma unroll
        for (int j = 0; j < 4; j++)
            bf[j] = *(const short8*)&Bs[(wn + j * 16 + l16) * LDS_STRIDE + quad * 8];
#pragma unroll
        for (int i = 0; i < 4; i++)
#pragma unroll
            for (int j = 0; j < 4; j++)
                acc[i][j] = __builtin_amdgcn_mfma_f32_16x16x32_bf16(af[i], bf[j], acc[i][j], 0, 0, 0);
    }

#pragma unroll
    for (int i = 0; i < 4; i++) {
#pragma unroll
        for (int j = 0; j < 4; j++) {
#pragma unroll
            for (int r = 0; r < 4; r++) {
                const int row = m0 + wm + i * 16 + quad * 4 + r;
                const int col = n0 + wn + j * 16 + l16;
                float v = acc[i][j][r] + bias[col];
                if (MODE == 0) {
                    const int h  = col / 192;
                    const int rr = col - h * 192;
                    const int sel = rr >> 6;
                    const int d   = rr & 63;
                    const int b = row >> 11;
                    const int t = row & 2047;
                    const int bh = b * 16 + h;
                    if (sel == 0) {
                        Cq[(((size_t)bh) * 2048 + t) * 64 + d] =
                            f32_to_bf16(v * Q_PRESCALE);
                    } else if (sel == 1) {
                        Ck[(((size_t)bh) * 2048 + t) * 64 + d] = f32_to_bf16(v);
                    } else {
                        Cv[(((size_t)bh * 32 + (t >> 6)) * 64 + d) * 64 + v_slot(t & 63)] =
                            f32_to_bf16(v);
                    }
                } else {
                    Cout[(size_t)row * N + col] = v;
                }
            }
        }
    }
}

// ===========================================================================
// MFMA causal flash attention, v8 (KVBLK=128: two 64-key sub-tiles per
// staged double-buffer -> half the barriers / vmcnt-drain windows of v7).
// Staging: 16KB K + 16KB V per step, coalesced via global_load_lds with
// XOR-chunk-swizzled per-8KB-sub-tile source; swizzled ds_read_b128 reads.
// Body: swapped QK^T (mfma(K,Q)) -> lane-resident P -> cvt_pk -> PV directly
// from registers; in-lane L sum, shuffle-redistribute epilogue.
// Grid 512 = 32 bh x 16 qt (big-first), 256 thr, LDS 64KB (2 blocks/CU).
// ===========================================================================
__global__ __launch_bounds__(256, 2) void attn_mfma(
    const ushort* __restrict__ Q, const ushort* __restrict__ K,
    const ushort* __restrict__ Vtb, ushort* __restrict__ O)
{
    const int bid   = blockIdx.x;
    const int bh    = bid & 31;
    const int qtIdx = bid >> 5;
    const int qt    = (qtIdx < 8) ? (15 - qtIdx) : (qtIdx - 8);
    const int tid  = threadIdx.x;
    const int wave = tid >> 6;
    const int lane = tid & 63;
    const int quad = lane >> 4;
    const int l16  = lane & 15;
    const int qb   = qt * 128 + wave * 32;

    __shared__ __align__(16) ushort Ks[2][8192];  // 128 keys x 64 (2x 8KB swz)
    __shared__ __align__(16) ushort Vs[2][8192];

    const size_t kbase = (size_t)bh * 2048 * 64;

    // staging map: per array, thread covers 4x16B at ob = tid*16 + c*4096.
    // Each 8KB sub-tile has its own chunk swizzle: physical (row r, chunk ch)
    // holds logical (r, ch ^ (r&7)).
    int e[4];
#pragma unroll
    for (int c = 0; c < 4; c++) {
        const int ob  = tid * 16 + c * 4096;
        const int sub = ob >> 13;
        const int obs = ob & 8191;
        const int r   = obs >> 7;
        const int ch  = (obs >> 4) & 7;
        e[c] = sub * 4096 + r * 64 + ((ch ^ (r & 7)) << 3);
    }
    const ushort* Kb = K + kbase;                      // + t128*8192 + e
    const ushort* Vb = Vtb + (size_t)bh * 32 * 4096;   // + t128*8192 + e

    auto stage = [&](int t128, ushort* KsB, ushort* VsB) {
        const ushort* Ktile = Kb + t128 * 8192;
        const ushort* Vtile = Vb + t128 * 8192;
#pragma unroll
        for (int c = 0; c < 4; c++)
            gload_lds16(Ktile + e[c], KsB + c * 2048 + wave * 512);
#pragma unroll
        for (int c = 0; c < 4; c++)
            gload_lds16(Vtile + e[c], VsB + c * 2048 + wave * 512);
    };

    // swizzled fragment read offsets within an 8KB sub-tile:
    // logical (row, chunk C) at ushort idx row*64 + ((C ^ (row&7))<<3).
    const int sw0 = ((quad ^ (l16 & 7)) << 3);        // half 0: C = quad
    const int sw1 = (((4 + quad) ^ (l16 & 7)) << 3);  // half 1: C = 4+quad
    const int rbase = l16 * 64;

    short8 qf0[2], qf1[2];
#pragma unroll
    for (int f = 0; f < 2; f++) {
        const ushort* qp = Q + kbase + (size_t)(qb + f * 16 + l16) * 64 + quad * 8;
        qf0[f] = *(const short8*)qp;
        qf1[f] = *(const short8*)(qp + 32);
    }

    floatx4 accO[2][4];
#pragma unroll
    for (int f = 0; f < 2; f++)
#pragma unroll
        for (int d = 0; d < 4; d++) accO[f][d] = (floatx4)0.0f;
    float accLs[2] = {0.0f, 0.0f};

    union PB { unsigned int u[4]; short8 s8; };

    auto compute = [&](int t128, const ushort* KsB, const ushort* VsB) {
#pragma unroll
        for (int s = 0; s < 2; ++s) {
            const int t64 = 2 * t128 + s;
            if (t64 * 64 > qb + 31) continue;  // both fragments masked
            const ushort* Kt = KsB + s * 4096;
            const ushort* Vt = VsB + s * 4096;
            short8 kf[4][2], vf[4][2];
#pragma unroll
            for (int j = 0; j < 4; j++) {
                kf[j][0] = *(const short8*)&Kt[j * 1024 + rbase + sw0];
                kf[j][1] = *(const short8*)&Kt[j * 1024 + rbase + sw1];
            }
#pragma unroll
            for (int d = 0; d < 4; d++) {
                vf[d][0] = *(const short8*)&Vt[d * 1024 + rbase + sw0];
                vf[d][1] = *(const short8*)&Vt[d * 1024 + rbase + sw1];
            }

#pragma unroll
            for (int f = 0; f < 2; f++) {
                const int qlo = qb + f * 16;
                if (t64 * 64 > qlo + 15) continue;  // fully masked fragment
                floatx4 sc[4];
#pragma unroll
                for (int j = 0; j < 4; j++) {
                    floatx4 acc = (floatx4)0.0f;
                    acc = __builtin_amdgcn_mfma_f32_16x16x32_bf16(kf[j][0], qf0[f], acc, 0, 0, 0);
                    acc = __builtin_amdgcn_mfma_f32_16x16x32_bf16(kf[j][1], qf1[f], acc, 0, 0, 0);
                    sc[j] = acc;
                }
                if (t64 * 64 + 63 > qlo) {  // diagonal tile: causal mask
                    const int qcol = qlo + l16;
#pragma unroll
                    for (int j = 0; j < 4; j++) {
                        const int keyb = t64 * 64 + j * 16 + quad * 4;
#pragma unroll
                        for (int r = 0; r < 4; r++)
                            if (keyb + r > qcol) sc[j][r] = -1e30f;
                    }
                }
#pragma unroll
                for (int j = 0; j < 4; j++)
#pragma unroll
                    for (int r = 0; r < 4; r++)
                        sc[j][r] = __builtin_amdgcn_exp2f(sc[j][r]);
                const floatx4 ssum = sc[0] + sc[1] + sc[2] + sc[3];
                accLs[f] += (ssum[0] + ssum[1]) + (ssum[2] + ssum[3]);
                PB p0, p1;
#pragma unroll
                for (int j = 0; j < 2; j++) {
                    p0.u[j * 2 + 0] = cvtpk(sc[j][0], sc[j][1]);
                    p0.u[j * 2 + 1] = cvtpk(sc[j][2], sc[j][3]);
                    p1.u[j * 2 + 0] = cvtpk(sc[j + 2][0], sc[j + 2][1]);
                    p1.u[j * 2 + 1] = cvtpk(sc[j + 2][2], sc[j + 2][3]);
                }
#pragma unroll
                for (int d = 0; d < 4; d++) {
                    accO[f][d] = __builtin_amdgcn_mfma_f32_16x16x32_bf16(p0.s8, vf[d][0], accO[f][d], 0, 0, 0);
                    accO[f][d] = __builtin_amdgcn_mfma_f32_16x16x32_bf16(p1.s8, vf[d][1], accO[f][d], 0, 0, 0);
                }
            }
        }
    };

    const int nt = qt + 1;  // 128-key steps
    stage(0, Ks[0], Vs[0]);
    __syncthreads();        // buf0 staged
    int t = 0;
    while (true) {
        if (t + 1 < nt) stage(t + 1, Ks[1], Vs[1]);  // prefetch under compute
        compute(t, Ks[0], Vs[0]);
        __syncthreads();    // prefetch landed + all waves done with buf0
        if (++t >= nt) break;
        if (t + 1 < nt) stage(t + 1, Ks[0], Vs[0]);
        compute(t, Ks[1], Vs[1]);
        __syncthreads();
        if (++t >= nt) break;
    }

    const int b = bh >> 4, h = bh & 15;
#pragma unroll
    for (int f = 0; f < 2; f++) {
        // accLs[f] = partial row-sum for q = qb+f*16+l16 over this lane's keys.
        float L = accLs[f];
        L += __shfl_xor(L, 16);
        L += __shfl_xor(L, 32);  // now L(q=l16) in all quads
        float inv[4];
#pragma unroll
        for (int r = 0; r < 4; r++) inv[r] = 1.0f / __shfl(L, quad * 4 + r);
#pragma unroll
        for (int d = 0; d < 4; d++)
#pragma unroll
            for (int r = 0; r < 4; r++)
                O[(size_t)(b * 2048 + qb + f * 16 + quad * 4 + r) * 1024 + h * 64 + d * 16 + l16] =
                    f32_to_bf16(accO[f][d][r] * inv[r]);
    }
}

extern "C" void kernel_launch(void* const* d_in, const int* in_sizes, int n_in,
                              void* d_out, int out_size, void* d_ws, size_t ws_size,
                              hipStream_t stream) {
    const float* x    = (const float*)d_in[0];
    const float* Wqkv = (const float*)d_in[1];
    const float* bqkv = (const float*)d_in[2];
    const float* Wout = (const float*)d_in[3];
    const float* bout = (const float*)d_in[4];
    float* out = (float*)d_out;

    char* ws = (char*)d_ws;
    const size_t MB = 1024 * 1024;
    ushort* Q    = (ushort*)(ws + 0 * MB);
    ushort* Kk   = (ushort*)(ws + 8 * MB);
    ushort* Vtb  = (ushort*)(ws + 16 * MB);  // tile-blocked permuted V (direct)
    ushort* O    = (ushort*)(ws + 24 * MB);

    const dim3 blk(256);
    if (ws_size >= 48 * MB) {
        ushort* xb    = (ushort*)(ws + 32 * MB);
        ushort* Wqkvb = (ushort*)(ws + 40 * MB);
        ushort* Woutb = (ushort*)(ws + 46 * MB);
        cvt_bf16_3<<<dim3(4096), blk, 0, stream>>>(x, Wqkv, Wout, xb, Wqkvb, Woutb);
        gemm_bf16<0><<<dim3(32, 24), blk, 0, stream>>>(xb, Wqkvb, bqkv, Q, Kk, Vtb,
                                                       nullptr, 4096, 3072, 1024);
        attn_mfma<<<dim3(512), blk, 0, stream>>>(Q, Kk, Vtb, O);
        gemm_bf16<1><<<dim3(32, 8), blk, 0, stream>>>(O, Woutb, bout, nullptr, nullptr,
                                                      nullptr, out, 4096, 1024, 1024);
    } else {
        gemm_bt<0, 1><<<dim3(32, 24), blk, 0, stream>>>(x, Wqkv, bqkv, Q, Kk, Vtb,
                                                        nullptr, 4096, 3072, 1024);
        attn_mfma<<<dim3(512), blk, 0, stream>>>(Q, Kk, Vtb, O);
        gemm_bt<1, 0><<<dim3(32, 8), blk, 0, stream>>>(O, Wout, bout, nullptr, nullptr,
                                                       nullptr, out, 4096, 1024, 1024);
    }
}

// Round 9
// 172.900 us; speedup vs baseline: 1.7446x; 1.0010x over previous
//
#include <hip/hip_runtime.h>
#include <hip/hip_bf16.h>
#include <cstdint>

// ---------------------------------------------------------------------------
// MultiHeadAttention: B=2, T=2048, D=1024, H=16, hd=64, causal.
// Inputs (fp32): x[B,T,D], W_qkv[3D,D], b_qkv[3D], W_out[D,D], b_out[D]
// out (fp32): [B,T,D]
// ws big path (48MB): Q@0, K@8M, Vtb@16M, O@24M, xb@32M, Wqkvb@40M, Woutb@46M
// GEMMs: one-shot fp32->bf16 cvt (single fused kernel), m97-style staging.
// Softmax: no-max flash (p = exp2(s) directly), in-lane f32 row-sum.
// v9: GEMM LDS line-pair XOR swizzle. v8 profiling showed gemm_bf16 is now
//   the top kernel (44.5us) with 3.1M SQ_LDS_BANK_CONFLICT: 64B rows meant a
//   16-lane fragment group piled 8 lanes per 16B bank slot. Fix: pair rows
//   into 128B lines, slot = ((row&1)*4+chunk) ^ ((row>>1)&7) -> each 16-lane
//   group covers all 8 slots twice (2/bank = free, attn-style). Linear LDS
//   dest + inverse-swizzled global source (coalescing-preserving bijection
//   per line) + swizzled ds_read (rule: both-sides-or-neither).
// History: v6 coalesced LDS staging (attn 68->38us); v7 dbuf+fused cvt
// (177.5); v8 fused transpose_v into GEMM epilogue + attn KVBLK=128 (173.1).
// LESSONS: launch_bounds 2nd arg acts as min-BLOCKS/CU ((512,4) = 64-VGPR cap
// = spill catastrophe); wave-count/balance give zero overlap gain (v2/v4);
// P-LDS roundtrip was not the wall (v5); K/V txn pattern was (v6); hipcc host
// pass lacks gfx950 builtins -> #if must be inside function bodies (R5).
// ---------------------------------------------------------------------------

using short8  = __attribute__((ext_vector_type(8))) short;
using floatx4 = __attribute__((ext_vector_type(4))) float;

#define LDS_STRIDE 40  // legacy gemm tiles: 32+8 pad

__device__ __forceinline__ float bf16_to_f32(unsigned short u) {
    union { unsigned int i; float f; } v; v.i = ((unsigned int)u) << 16; return v.f;
}
__device__ __forceinline__ unsigned short f32_to_bf16(float f) {
    union { float f; unsigned int i; } v; v.f = f;
    unsigned int x = v.i;
    unsigned int r = x + 0x7FFFu + ((x >> 16) & 1u);  // RNE
    return (unsigned short)(r >> 16);
}
__device__ __forceinline__ short8 cvt8(const float* __restrict__ p) {
    const float4 f0 = *(const float4*)p;
    const float4 f1 = *(const float4*)(p + 4);
    short8 r;
    r[0] = (short)f32_to_bf16(f0.x); r[1] = (short)f32_to_bf16(f0.y);
    r[2] = (short)f32_to_bf16(f0.z); r[3] = (short)f32_to_bf16(f0.w);
    r[4] = (short)f32_to_bf16(f1.x); r[5] = (short)f32_to_bf16(f1.y);
    r[6] = (short)f32_to_bf16(f1.z); r[7] = (short)f32_to_bf16(f1.w);
    return r;
}
// pack two f32 -> one dword of 2 bf16 (RNE); no builtin on gfx950, pure-VALU asm
__device__ __forceinline__ unsigned int cvtpk(float a, float b) {
    unsigned int r;
    asm("v_cvt_pk_bf16_f32 %0, %1, %2" : "=v"(r) : "v"(a), "v"(b));
    return r;
}

// 1/sqrt(64) * log2(e)
#define Q_PRESCALE 0.1803368801111204f

#if __has_builtin(__builtin_amdgcn_global_load_lds)
#define ASYNC_STAGE 1
typedef const __attribute__((address_space(1))) void* gas1_t;
typedef __attribute__((address_space(3))) void* las3_t;
#else
#define ASYNC_STAGE 0
#endif

// Defined unconditionally: hipcc's host pass lacks the builtin, so the #if
// must live INSIDE the body (placeholder branch never executes on device).
__device__ __forceinline__ void gload_lds16(const ushort* g, ushort* l) {
#if ASYNC_STAGE
    __builtin_amdgcn_global_load_lds((gas1_t)g, (las3_t)l, 16, 0, 0);
#else
    *(short8*)l = *(const short8*)g;  // host-pass placeholder
#endif
}

// inverse of transpose_v's slot->key map: which Vtb slot holds key k (0..63)
__device__ __forceinline__ int v_slot(int k) {
    const int k5 = k & 31;
    return (k & 32) + ((k5 >> 4) & 1) * 4 + ((k5 >> 2) & 3) * 8 + (k5 & 3);
}

// fused fp32 -> bf16 for x / W_qkv / W_out, 8 elems/thread, one launch.
// Range boundaries are block-aligned: 524288 = 2048*256, 917504 = 3584*256.
__global__ __launch_bounds__(256, 8) void cvt_bf16_3(
    const float* __restrict__ x,  const float* __restrict__ wq,
    const float* __restrict__ wo, ushort* __restrict__ xb,
    ushort* __restrict__ wqb, ushort* __restrict__ wob)
{
    const int i = blockIdx.x * 256 + threadIdx.x;  // 0..1048575
    const float* src; ushort* dst; int off;
    if (i < 524288)      { src = x;  dst = xb;  off = i; }
    else if (i < 917504) { src = wq; dst = wqb; off = i - 524288; }
    else                 { src = wo; dst = wob; off = i - 917504; }
    *(short8*)(dst + (size_t)off * 8) = cvt8(src + (size_t)off * 8);
}

// ===== m97-style bf16 GEMM: C[M,N] = A[M,K] @ W[N,K]^T + bias[N] =====
// MODE 0: scatter Q (scaled), K [bh][t][64]; V directly into tile-blocked
// permuted Vtb[bh][t64][d][slot] (transpose_v fused). MODE 1: fp32 Cout.
// LDS tiles use the line-pair swizzle: logical (row, chunk) [128 rows x 4
// chunks of 8 ushorts] lives at physical line = row>>1 (128B), slot =
// ((row&1)*4 + chunk) ^ (line&7).
template <int MODE>
__global__ __launch_bounds__(256, 3) void gemm_bf16(
    const ushort* __restrict__ A, const ushort* __restrict__ W,
    const float* __restrict__ bias,
    ushort* __restrict__ Cq, ushort* __restrict__ Ck, ushort* __restrict__ Cv,
    float* __restrict__ Cout, int M, int N, int K)
{
    __shared__ __align__(16) ushort As[128 * 32];
    __shared__ __align__(16) ushort Bs[128 * 32];

    const int tid  = threadIdx.x;
    const int lane = tid & 63;
    const int wave = tid >> 6;
    const int wm = (wave >> 1) * 64;
    const int wn = (wave & 1) * 64;
    const int m0 = blockIdx.x * 128;
    const int n0 = blockIdx.y * 128;
    const int quad = lane >> 4;
    const int l16  = lane & 15;

    floatx4 acc[4][4];
#pragma unroll
    for (int i = 0; i < 4; i++)
#pragma unroll
        for (int j = 0; j < 4; j++) acc[i][j] = (floatx4)0.0f;

    // ---- swizzled staging source map (loop-invariant). Thread's linear LDS
    // dest bytes: ob0 = tid*16 (rows 0-63 half), ob1 = ob0+4096 (rows 64-127).
    // Decode physical -> logical: line = ob>>7, slot = (ob>>4)&7,
    // p = slot ^ (line&7), row = line*2 + (p>>2), chunk = p&3.
    const int ob0 = tid * 16, ob1 = ob0 + 4096;
    const int ln0 = ob0 >> 7, p0_ = ((ob0 >> 4) & 7) ^ (ln0 & 7);
    const int ln1 = ob1 >> 7, p1_ = ((ob1 >> 4) & 7) ^ (ln1 & 7);
    const int row0 = ln0 * 2 + (p0_ >> 2), ch0 = p0_ & 3;
    const int row1 = ln1 * 2 + (p1_ >> 2), ch1 = p1_ & 3;
    ushort* ldsA0 = &As[wave * 512];
    ushort* ldsA1 = &As[2048 + wave * 512];
    ushort* ldsB0 = &Bs[wave * 512];
    ushort* ldsB1 = &Bs[2048 + wave * 512];
    const ushort* pA0 = A + (size_t)(m0 + row0) * K + ch0 * 8;
    const ushort* pA1 = A + (size_t)(m0 + row1) * K + ch1 * 8;
    const ushort* pB0 = W + (size_t)(n0 + row0) * K + ch0 * 8;
    const ushort* pB1 = W + (size_t)(n0 + row1) * K + ch1 * 8;

    // ---- swizzled fragment read offsets. row = w? + i*16 + l16, chunk=quad.
    // Across i: line += 8 -> (line&7) unchanged, row&1 unchanged => slot
    // constant; ushort idx = line*64 + slot*8 = base + i*512.
    const int Ra = wm + l16;
    const int aoff = (Ra >> 1) * 64 + (((((Ra & 1) << 2) + quad) ^ ((Ra >> 1) & 7)) << 3);
    const int Rb = wn + l16;
    const int boff = (Rb >> 1) * 64 + (((((Rb & 1) << 2) + quad) ^ ((Rb >> 1) & 7)) << 3);

    for (int k0 = 0; k0 < K; k0 += 32) {
#if ASYNC_STAGE
        __syncthreads();  // prev iter's fragment reads done
        gload_lds16(pA0 + k0, ldsA0);
        gload_lds16(pA1 + k0, ldsA1);
        gload_lds16(pB0 + k0, ldsB0);
        gload_lds16(pB1 + k0, ldsB1);
        __syncthreads();  // compiler drains vmcnt before barrier
#else
        const short8 a0 = *(const short8*)(pA0 + k0);
        const short8 a1 = *(const short8*)(pA1 + k0);
        const short8 b0 = *(const short8*)(pB0 + k0);
        const short8 b1 = *(const short8*)(pB1 + k0);
        __syncthreads();
        *(short8*)((char*)As + ob0) = a0;
        *(short8*)((char*)As + ob1) = a1;
        *(short8*)((char*)Bs + ob0) = b0;
        *(short8*)((char*)Bs + ob1) = b1;
        __syncthreads();
#endif

        short8 af[4], bf[4];
#pragma unroll
        for (int i = 0; i < 4; i++)
            af[i] = *(const short8*)&As[aoff + i * 512];
#pragma unroll
        for (int j = 0; j < 4; j++)
            bf[j] = *(const short8*)&Bs[boff + j * 512];
#pragma unroll
        for (int i = 0; i < 4; i++)
#pragma unroll
            for (int j = 0; j < 4; j++)
                acc[i][j] = __builtin_amdgcn_mfma_f32_16x16x32_bf16(af[i], bf[j], acc[i][j], 0, 0, 0);
    }

#pragma unroll
    for (int i = 0; i < 4; i++) {
#pragma unroll
        for (int j = 0; j < 4; j++) {
#pragma unroll
            for (int r = 0; r < 4; r++) {
                const int row = m0 + wm + i * 16 + quad * 4 + r;
                const int col = n0 + wn + j * 16 + l16;
                float v = acc[i][j][r] + bias[col];
                if (MODE == 0) {
                    const int h  = col / 192;
                    const int rr = col - h * 192;
                    const int sel = rr >> 6;
                    const int d   = rr & 63;
                    const int b = row >> 11;
                    const int t = row & 2047;
                    const int bh = b * 16 + h;
                    if (sel == 0) {
                        Cq[(((size_t)bh) * 2048 + t) * 64 + d] =
                            f32_to_bf16(v * Q_PRESCALE);
                    } else if (sel == 1) {
                        Ck[(((size_t)bh) * 2048 + t) * 64 + d] = f32_to_bf16(v);
                    } else {
                        // fused transpose_v: Vtb[bh][t>>6][d][slot(t&63)]
                        Cv[(((size_t)bh * 32 + (t >> 6)) * 64 + d) * 64 + v_slot(t & 63)] =
                            f32_to_bf16(v);
                    }
                } else {
                    Cout[(size_t)row * N + col] = v;
                }
            }
        }
    }
}

// ===== legacy fused-cvt GEMM (fallback when ws < 48MB) =====
template <int MODE, int AFP32>
__global__ __launch_bounds__(256, 2) void gemm_bt(
    const void* __restrict__ Av, const float* __restrict__ W,
    const float* __restrict__ bias,
    ushort* __restrict__ Cq, ushort* __restrict__ Ck, ushort* __restrict__ Cv,
    float* __restrict__ Cout, int M, int N, int K)
{
    __shared__ __align__(16) ushort As[128 * LDS_STRIDE];
    __shared__ __align__(16) ushort Bs[128 * LDS_STRIDE];

    const int tid  = threadIdx.x;
    const int lane = tid & 63;
    const int wave = tid >> 6;
    const int wm = (wave >> 1) * 64;
    const int wn = (wave & 1) * 64;
    const int m0 = blockIdx.x * 128;
    const int n0 = blockIdx.y * 128;
    const int quad = lane >> 4;
    const int l16  = lane & 15;

    floatx4 acc[4][4];
#pragma unroll
    for (int i = 0; i < 4; i++)
#pragma unroll
        for (int j = 0; j < 4; j++) acc[i][j] = (floatx4)0.0f;

    const int srow = tid >> 2;
    const int scol = (tid & 3) * 8;

    for (int k0 = 0; k0 < K; k0 += 32) {
        short8 a0, a1;
        if (AFP32) {
            const float* A = (const float*)Av;
            a0 = cvt8(A + (size_t)(m0 + srow) * K + k0 + scol);
            a1 = cvt8(A + (size_t)(m0 + srow + 64) * K + k0 + scol);
        } else {
            const ushort* A = (const ushort*)Av;
            a0 = *(const short8*)(A + (size_t)(m0 + srow) * K + k0 + scol);
            a1 = *(const short8*)(A + (size_t)(m0 + srow + 64) * K + k0 + scol);
        }
        const short8 b0 = cvt8(W + (size_t)(n0 + srow) * K + k0 + scol);
        const short8 b1 = cvt8(W + (size_t)(n0 + srow + 64) * K + k0 + scol);
        __syncthreads();
        *(short8*)&As[srow * LDS_STRIDE + scol] = a0;
        *(short8*)&As[(srow + 64) * LDS_STRIDE + scol] = a1;
        *(short8*)&Bs[srow * LDS_STRIDE + scol] = b0;
        *(short8*)&Bs[(srow + 64) * LDS_STRIDE + scol] = b1;
        __syncthreads();

        short8 af[4], bf[4];
#pragma unroll
        for (int i = 0; i < 4; i++)
            af[i] = *(const short8*)&As[(wm + i * 16 + l16) * LDS_STRIDE + quad * 8];
#pragma unroll
        for (int j = 0; j < 4; j++)
            bf[j] = *(const short8*)&Bs[(wn + j * 16 + l16) * LDS_STRIDE + quad * 8];
#pragma unroll
        for (int i = 0; i < 4; i++)
#pragma unroll
            for (int j = 0; j < 4; j++)
                acc[i][j] = __builtin_amdgcn_mfma_f32_16x16x32_bf16(af[i], bf[j], acc[i][j], 0, 0, 0);
    }

#pragma unroll
    for (int i = 0; i < 4; i++) {
#pragma unroll
        for (int j = 0; j < 4; j++) {
#pragma unroll
            for (int r = 0; r < 4; r++) {
                const int row = m0 + wm + i * 16 + quad * 4 + r;
                const int col = n0 + wn + j * 16 + l16;
                float v = acc[i][j][r] + bias[col];
                if (MODE == 0) {
                    const int h  = col / 192;
                    const int rr = col - h * 192;
                    const int sel = rr >> 6;
                    const int d   = rr & 63;
                    const int b = row >> 11;
                    const int t = row & 2047;
                    const int bh = b * 16 + h;
                    if (sel == 0) {
                        Cq[(((size_t)bh) * 2048 + t) * 64 + d] =
                            f32_to_bf16(v * Q_PRESCALE);
                    } else if (sel == 1) {
                        Ck[(((size_t)bh) * 2048 + t) * 64 + d] = f32_to_bf16(v);
                    } else {
                        Cv[(((size_t)bh * 32 + (t >> 6)) * 64 + d) * 64 + v_slot(t & 63)] =
                            f32_to_bf16(v);
                    }
                } else {
                    Cout[(size_t)row * N + col] = v;
                }
            }
        }
    }
}

// ===========================================================================
// MFMA causal flash attention, v8 (unchanged): KVBLK=128, dbuf LDS staging,
// swizzled coalesced global_load_lds, register-P (swapped QK^T + cvt_pk),
// in-lane L sum. Grid 512 = 32 bh x 16 qt (big-first), 256 thr, LDS 64KB.
// ===========================================================================
__global__ __launch_bounds__(256, 2) void attn_mfma(
    const ushort* __restrict__ Q, const ushort* __restrict__ K,
    const ushort* __restrict__ Vtb, ushort* __restrict__ O)
{
    const int bid   = blockIdx.x;
    const int bh    = bid & 31;
    const int qtIdx = bid >> 5;
    const int qt    = (qtIdx < 8) ? (15 - qtIdx) : (qtIdx - 8);
    const int tid  = threadIdx.x;
    const int wave = tid >> 6;
    const int lane = tid & 63;
    const int quad = lane >> 4;
    const int l16  = lane & 15;
    const int qb   = qt * 128 + wave * 32;

    __shared__ __align__(16) ushort Ks[2][8192];  // 128 keys x 64 (2x 8KB swz)
    __shared__ __align__(16) ushort Vs[2][8192];

    const size_t kbase = (size_t)bh * 2048 * 64;

    // staging map: per array, thread covers 4x16B at ob = tid*16 + c*4096.
    // Each 8KB sub-tile has its own chunk swizzle: physical (row r, chunk ch)
    // holds logical (r, ch ^ (r&7)).
    int e[4];
#pragma unroll
    for (int c = 0; c < 4; c++) {
        const int ob  = tid * 16 + c * 4096;
        const int sub = ob >> 13;
        const int obs = ob & 8191;
        const int r   = obs >> 7;
        const int ch  = (obs >> 4) & 7;
        e[c] = sub * 4096 + r * 64 + ((ch ^ (r & 7)) << 3);
    }
    const ushort* Kb = K + kbase;                      // + t128*8192 + e
    const ushort* Vb = Vtb + (size_t)bh * 32 * 4096;   // + t128*8192 + e

    auto stage = [&](int t128, ushort* KsB, ushort* VsB) {
        const ushort* Ktile = Kb + t128 * 8192;
        const ushort* Vtile = Vb + t128 * 8192;
#pragma unroll
        for (int c = 0; c < 4; c++)
            gload_lds16(Ktile + e[c], KsB + c * 2048 + wave * 512);
#pragma unroll
        for (int c = 0; c < 4; c++)
            gload_lds16(Vtile + e[c], VsB + c * 2048 + wave * 512);
    };

    // swizzled fragment read offsets within an 8KB sub-tile:
    // logical (row, chunk C) at ushort idx row*64 + ((C ^ (row&7))<<3).
    const int sw0 = ((quad ^ (l16 & 7)) << 3);        // half 0: C = quad
    const int sw1 = (((4 + quad) ^ (l16 & 7)) << 3);  // half 1: C = 4+quad
    const int rbase = l16 * 64;

    short8 qf0[2], qf1[2];
#pragma unroll
    for (int f = 0; f < 2; f++) {
        const ushort* qp = Q + kbase + (size_t)(qb + f * 16 + l16) * 64 + quad * 8;
        qf0[f] = *(const short8*)qp;
        qf1[f] = *(const short8*)(qp + 32);
    }

    floatx4 accO[2][4];
#pragma unroll
    for (int f = 0; f < 2; f++)
#pragma unroll
        for (int d = 0; d < 4; d++) accO[f][d] = (floatx4)0.0f;
    float accLs[2] = {0.0f, 0.0f};

    union PB { unsigned int u[4]; short8 s8; };

    auto compute = [&](int t128, const ushort* KsB, const ushort* VsB) {
#pragma unroll
        for (int s = 0; s < 2; ++s) {
            const int t64 = 2 * t128 + s;
            if (t64 * 64 > qb + 31) continue;  // both fragments masked
            const ushort* Kt = KsB + s * 4096;
            const ushort* Vt = VsB + s * 4096;
            short8 kf[4][2], vf[4][2];
#pragma unroll
            for (int j = 0; j < 4; j++) {
                kf[j][0] = *(const short8*)&Kt[j * 1024 + rbase + sw0];
                kf[j][1] = *(const short8*)&Kt[j * 1024 + rbase + sw1];
            }
#pragma unroll
            for (int d = 0; d < 4; d++) {
                vf[d][0] = *(const short8*)&Vt[d * 1024 + rbase + sw0];
                vf[d][1] = *(const short8*)&Vt[d * 1024 + rbase + sw1];
            }

#pragma unroll
            for (int f = 0; f < 2; f++) {
                const int qlo = qb + f * 16;
                if (t64 * 64 > qlo + 15) continue;  // fully masked fragment
                floatx4 sc[4];
#pragma unroll
                for (int j = 0; j < 4; j++) {
                    floatx4 acc = (floatx4)0.0f;
                    acc = __builtin_amdgcn_mfma_f32_16x16x32_bf16(kf[j][0], qf0[f], acc, 0, 0, 0);
                    acc = __builtin_amdgcn_mfma_f32_16x16x32_bf16(kf[j][1], qf1[f], acc, 0, 0, 0);
                    sc[j] = acc;
                }
                if (t64 * 64 + 63 > qlo) {  // diagonal tile: causal mask
                    const int qcol = qlo + l16;
#pragma unroll
                    for (int j = 0; j < 4; j++) {
                        const int keyb = t64 * 64 + j * 16 + quad * 4;
#pragma unroll
                        for (int r = 0; r < 4; r++)
                            if (keyb + r > qcol) sc[j][r] = -1e30f;
                    }
                }
#pragma unroll
                for (int j = 0; j < 4; j++)
#pragma unroll
                    for (int r = 0; r < 4; r++)
                        sc[j][r] = __builtin_amdgcn_exp2f(sc[j][r]);
                const floatx4 ssum = sc[0] + sc[1] + sc[2] + sc[3];
                accLs[f] += (ssum[0] + ssum[1]) + (ssum[2] + ssum[3]);
                PB p0, p1;
#pragma unroll
                for (int j = 0; j < 2; j++) {
                    p0.u[j * 2 + 0] = cvtpk(sc[j][0], sc[j][1]);
                    p0.u[j * 2 + 1] = cvtpk(sc[j][2], sc[j][3]);
                    p1.u[j * 2 + 0] = cvtpk(sc[j + 2][0], sc[j + 2][1]);
                    p1.u[j * 2 + 1] = cvtpk(sc[j + 2][2], sc[j + 2][3]);
                }
#pragma unroll
                for (int d = 0; d < 4; d++) {
                    accO[f][d] = __builtin_amdgcn_mfma_f32_16x16x32_bf16(p0.s8, vf[d][0], accO[f][d], 0, 0, 0);
                    accO[f][d] = __builtin_amdgcn_mfma_f32_16x16x32_bf16(p1.s8, vf[d][1], accO[f][d], 0, 0, 0);
                }
            }
        }
    };

    const int nt = qt + 1;  // 128-key steps
    stage(0, Ks[0], Vs[0]);
    __syncthreads();        // buf0 staged
    int t = 0;
    while (true) {
        if (t + 1 < nt) stage(t + 1, Ks[1], Vs[1]);  // prefetch under compute
        compute(t, Ks[0], Vs[0]);
        __syncthreads();    // prefetch landed + all waves done with buf0
        if (++t >= nt) break;
        if (t + 1 < nt) stage(t + 1, Ks[0], Vs[0]);
        compute(t, Ks[1], Vs[1]);
        __syncthreads();
        if (++t >= nt) break;
    }

    const int b = bh >> 4, h = bh & 15;
#pragma unroll
    for (int f = 0; f < 2; f++) {
        // accLs[f] = partial row-sum for q = qb+f*16+l16 over this lane's keys.
        float L = accLs[f];
        L += __shfl_xor(L, 16);
        L += __shfl_xor(L, 32);  // now L(q=l16) in all quads
        float inv[4];
#pragma unroll
        for (int r = 0; r < 4; r++) inv[r] = 1.0f / __shfl(L, quad * 4 + r);
#pragma unroll
        for (int d = 0; d < 4; d++)
#pragma unroll
            for (int r = 0; r < 4; r++)
                O[(size_t)(b * 2048 + qb + f * 16 + quad * 4 + r) * 1024 + h * 64 + d * 16 + l16] =
                    f32_to_bf16(accO[f][d][r] * inv[r]);
    }
}

extern "C" void kernel_launch(void* const* d_in, const int* in_sizes, int n_in,
                              void* d_out, int out_size, void* d_ws, size_t ws_size,
                              hipStream_t stream) {
    const float* x    = (const float*)d_in[0];
    const float* Wqkv = (const float*)d_in[1];
    const float* bqkv = (const float*)d_in[2];
    const float* Wout = (const float*)d_in[3];
    const float* bout = (const float*)d_in[4];
    float* out = (float*)d_out;

    char* ws = (char*)d_ws;
    const size_t MB = 1024 * 1024;
    ushort* Q    = (ushort*)(ws + 0 * MB);
    ushort* Kk   = (ushort*)(ws + 8 * MB);
    ushort* Vtb  = (ushort*)(ws + 16 * MB);  // tile-blocked permuted V (direct)
    ushort* O    = (ushort*)(ws + 24 * MB);

    const dim3 blk(256);
    if (ws_size >= 48 * MB) {
        ushort* xb    = (ushort*)(ws + 32 * MB);
        ushort* Wqkvb = (ushort*)(ws + 40 * MB);
        ushort* Woutb = (ushort*)(ws + 46 * MB);
        cvt_bf16_3<<<dim3(4096), blk, 0, stream>>>(x, Wqkv, Wout, xb, Wqkvb, Woutb);
        gemm_bf16<0><<<dim3(32, 24), blk, 0, stream>>>(xb, Wqkvb, bqkv, Q, Kk, Vtb,
                                                       nullptr, 4096, 3072, 1024);
        attn_mfma<<<dim3(512), blk, 0, stream>>>(Q, Kk, Vtb, O);
        gemm_bf16<1><<<dim3(32, 8), blk, 0, stream>>>(O, Woutb, bout, nullptr, nullptr,
                                                      nullptr, out, 4096, 1024, 1024);
    } else {
        gemm_bt<0, 1><<<dim3(32, 24), blk, 0, stream>>>(x, Wqkv, bqkv, Q, Kk, Vtb,
                                                        nullptr, 4096, 3072, 1024);
        attn_mfma<<<dim3(512), blk, 0, stream>>>(Q, Kk, Vtb, O);
        gemm_bt<1, 0><<<dim3(32, 8), blk, 0, stream>>>(O, Wout, bout, nullptr, nullptr,
                                                       nullptr, out, 4096, 1024, 1024);
    }
}

// Round 10
// 170.330 us; speedup vs baseline: 1.7710x; 1.0151x over previous
//
#include <hip/hip_runtime.h>
#include <hip/hip_bf16.h>
#include <cstdint>

// ---------------------------------------------------------------------------
// MultiHeadAttention: B=2, T=2048, D=1024, H=16, hd=64, causal.
// Inputs (fp32): x[B,T,D], W_qkv[3D,D], b_qkv[3D], W_out[D,D], b_out[D]
// out (fp32): [B,T,D]
// ws big path (48MB): Q@0, K@8M, Vtb@16M, O@24M, xb@32M, Wqkvb@40M, Woutb@46M
// GEMMs: one-shot fp32->bf16 cvt (single fused kernel), m97-style staging.
// Softmax: no-max flash (p = exp2(s) directly), in-lane f32 row-sum.
// v10: GEMM K-loop double-buffered (attn-v7 pattern): stage(k+1) issued
//   BEFORE compute(k), ONE barrier/step -> the exposed vmcnt(0) drain
//   (~200-900cyc vs ~240cyc MFMA/step) hides under compute. LDS 32KB,
//   3 blocks/CU. v9's line-pair swizzle kept (conflicts 3.15M -> 0; null at
//   2-phase per regime-gate, but becomes live once the drain is gone).
// History: v6 coalesced LDS staging (attn 68->38us); v7 attn dbuf+fused cvt
// (177.5); v8 fused transpose_v + attn KVBLK=128 (173.1); v9 GEMM swizzle
// (172.9, conflicts->0 but drain-masked).
// LESSONS: launch_bounds 2nd arg acts as min-BLOCKS/CU ((512,4) = 64-VGPR cap
// = spill catastrophe); wave-count/balance give zero overlap gain (v2/v4);
// P-LDS roundtrip was not the wall (v5); K/V txn pattern was (v6); hipcc host
// pass lacks gfx950 builtins -> #if must be inside function bodies (R5);
// bank-conflict fixes are null while a full-drain barrier dominates (v9).
// ---------------------------------------------------------------------------

using short8  = __attribute__((ext_vector_type(8))) short;
using floatx4 = __attribute__((ext_vector_type(4))) float;

#define LDS_STRIDE 40  // legacy gemm tiles: 32+8 pad

__device__ __forceinline__ float bf16_to_f32(unsigned short u) {
    union { unsigned int i; float f; } v; v.i = ((unsigned int)u) << 16; return v.f;
}
__device__ __forceinline__ unsigned short f32_to_bf16(float f) {
    union { float f; unsigned int i; } v; v.f = f;
    unsigned int x = v.i;
    unsigned int r = x + 0x7FFFu + ((x >> 16) & 1u);  // RNE
    return (unsigned short)(r >> 16);
}
__device__ __forceinline__ short8 cvt8(const float* __restrict__ p) {
    const float4 f0 = *(const float4*)p;
    const float4 f1 = *(const float4*)(p + 4);
    short8 r;
    r[0] = (short)f32_to_bf16(f0.x); r[1] = (short)f32_to_bf16(f0.y);
    r[2] = (short)f32_to_bf16(f0.z); r[3] = (short)f32_to_bf16(f0.w);
    r[4] = (short)f32_to_bf16(f1.x); r[5] = (short)f32_to_bf16(f1.y);
    r[6] = (short)f32_to_bf16(f1.z); r[7] = (short)f32_to_bf16(f1.w);
    return r;
}
// pack two f32 -> one dword of 2 bf16 (RNE); no builtin on gfx950, pure-VALU asm
__device__ __forceinline__ unsigned int cvtpk(float a, float b) {
    unsigned int r;
    asm("v_cvt_pk_bf16_f32 %0, %1, %2" : "=v"(r) : "v"(a), "v"(b));
    return r;
}

// 1/sqrt(64) * log2(e)
#define Q_PRESCALE 0.1803368801111204f

#if __has_builtin(__builtin_amdgcn_global_load_lds)
#define ASYNC_STAGE 1
typedef const __attribute__((address_space(1))) void* gas1_t;
typedef __attribute__((address_space(3))) void* las3_t;
#else
#define ASYNC_STAGE 0
#endif

// Defined unconditionally: hipcc's host pass lacks the builtin, so the #if
// must live INSIDE the body (placeholder branch never executes on device).
__device__ __forceinline__ void gload_lds16(const ushort* g, ushort* l) {
#if ASYNC_STAGE
    __builtin_amdgcn_global_load_lds((gas1_t)g, (las3_t)l, 16, 0, 0);
#else
    *(short8*)l = *(const short8*)g;  // host-pass placeholder
#endif
}

// inverse of transpose_v's slot->key map: which Vtb slot holds key k (0..63)
__device__ __forceinline__ int v_slot(int k) {
    const int k5 = k & 31;
    return (k & 32) + ((k5 >> 4) & 1) * 4 + ((k5 >> 2) & 3) * 8 + (k5 & 3);
}

// fused fp32 -> bf16 for x / W_qkv / W_out, 8 elems/thread, one launch.
// Range boundaries are block-aligned: 524288 = 2048*256, 917504 = 3584*256.
__global__ __launch_bounds__(256, 8) void cvt_bf16_3(
    const float* __restrict__ x,  const float* __restrict__ wq,
    const float* __restrict__ wo, ushort* __restrict__ xb,
    ushort* __restrict__ wqb, ushort* __restrict__ wob)
{
    const int i = blockIdx.x * 256 + threadIdx.x;  // 0..1048575
    const float* src; ushort* dst; int off;
    if (i < 524288)      { src = x;  dst = xb;  off = i; }
    else if (i < 917504) { src = wq; dst = wqb; off = i - 524288; }
    else                 { src = wo; dst = wob; off = i - 917504; }
    *(short8*)(dst + (size_t)off * 8) = cvt8(src + (size_t)off * 8);
}

// ===== m97-style bf16 GEMM: C[M,N] = A[M,K] @ W[N,K]^T + bias[N] =====
// MODE 0: scatter Q (scaled), K [bh][t][64]; V directly into tile-blocked
// permuted Vtb[bh][t64][d][slot] (transpose_v fused). MODE 1: fp32 Cout.
// LDS tiles: line-pair swizzle (v9) + K-loop double-buffer (v10).
template <int MODE>
__global__ __launch_bounds__(256, 3) void gemm_bf16(
    const ushort* __restrict__ A, const ushort* __restrict__ W,
    const float* __restrict__ bias,
    ushort* __restrict__ Cq, ushort* __restrict__ Ck, ushort* __restrict__ Cv,
    float* __restrict__ Cout, int M, int N, int K)
{
    __shared__ __align__(16) ushort As[2][128 * 32];
    __shared__ __align__(16) ushort Bs[2][128 * 32];

    const int tid  = threadIdx.x;
    const int lane = tid & 63;
    const int wave = tid >> 6;
    const int wm = (wave >> 1) * 64;
    const int wn = (wave & 1) * 64;
    const int m0 = blockIdx.x * 128;
    const int n0 = blockIdx.y * 128;
    const int quad = lane >> 4;
    const int l16  = lane & 15;

    floatx4 acc[4][4];
#pragma unroll
    for (int i = 0; i < 4; i++)
#pragma unroll
        for (int j = 0; j < 4; j++) acc[i][j] = (floatx4)0.0f;

    // ---- swizzled staging source map (loop-invariant). Thread's linear LDS
    // dest bytes: ob0 = tid*16 (rows 0-63 half), ob1 = ob0+4096 (rows 64-127).
    // Decode physical -> logical: line = ob>>7, slot = (ob>>4)&7,
    // p = slot ^ (line&7), row = line*2 + (p>>2), chunk = p&3.
    const int ob0 = tid * 16, ob1 = ob0 + 4096;
    const int ln0 = ob0 >> 7, p0_ = ((ob0 >> 4) & 7) ^ (ln0 & 7);
    const int ln1 = ob1 >> 7, p1_ = ((ob1 >> 4) & 7) ^ (ln1 & 7);
    const int row0 = ln0 * 2 + (p0_ >> 2), ch0 = p0_ & 3;
    const int row1 = ln1 * 2 + (p1_ >> 2), ch1 = p1_ & 3;
    const ushort* pA0 = A + (size_t)(m0 + row0) * K + ch0 * 8;
    const ushort* pA1 = A + (size_t)(m0 + row1) * K + ch1 * 8;
    const ushort* pB0 = W + (size_t)(n0 + row0) * K + ch0 * 8;
    const ushort* pB1 = W + (size_t)(n0 + row1) * K + ch1 * 8;

    // ---- swizzled fragment read offsets. row = w? + i*16 + l16, chunk=quad.
    // Across i: line += 8 -> (line&7) unchanged, row&1 unchanged => slot
    // constant; ushort idx = line*64 + slot*8 = base + i*512.
    const int Ra = wm + l16;
    const int aoff = (Ra >> 1) * 64 + (((((Ra & 1) << 2) + quad) ^ ((Ra >> 1) & 7)) << 3);
    const int Rb = wn + l16;
    const int boff = (Rb >> 1) * 64 + (((((Rb & 1) << 2) + quad) ^ ((Rb >> 1) & 7)) << 3);

    auto stage = [&](int k0, ushort* AsB, ushort* BsB) {
        gload_lds16(pA0 + k0, AsB + wave * 512);
        gload_lds16(pA1 + k0, AsB + 2048 + wave * 512);
        gload_lds16(pB0 + k0, BsB + wave * 512);
        gload_lds16(pB1 + k0, BsB + 2048 + wave * 512);
    };
    auto compute = [&](const ushort* AsB, const ushort* BsB) {
        short8 af[4], bf[4];
#pragma unroll
        for (int i = 0; i < 4; i++)
            af[i] = *(const short8*)&AsB[aoff + i * 512];
#pragma unroll
        for (int j = 0; j < 4; j++)
            bf[j] = *(const short8*)&BsB[boff + j * 512];
#pragma unroll
        for (int i = 0; i < 4; i++)
#pragma unroll
            for (int j = 0; j < 4; j++)
                acc[i][j] = __builtin_amdgcn_mfma_f32_16x16x32_bf16(af[i], bf[j], acc[i][j], 0, 0, 0);
    };

#if ASYNC_STAGE
    // dbuf pipeline: prefetch(k+32) issued BEFORE compute(k); one barrier per
    // step. stage(k+32) overwrites the buffer fully consumed before the
    // previous barrier -> race-free (attn-v7 argument).
    stage(0, As[0], Bs[0]);
    __syncthreads();
    int k = 0;
    while (true) {
        if (k + 32 < K) stage(k + 32, As[1], Bs[1]);
        compute(As[0], Bs[0]);
        __syncthreads();
        k += 32; if (k >= K) break;
        if (k + 32 < K) stage(k + 32, As[0], Bs[0]);
        compute(As[1], Bs[1]);
        __syncthreads();
        k += 32; if (k >= K) break;
    }
#else
    for (int k0 = 0; k0 < K; k0 += 32) {
        const short8 a0 = *(const short8*)(pA0 + k0);
        const short8 a1 = *(const short8*)(pA1 + k0);
        const short8 b0 = *(const short8*)(pB0 + k0);
        const short8 b1 = *(const short8*)(pB1 + k0);
        __syncthreads();
        *(short8*)((char*)As[0] + ob0) = a0;
        *(short8*)((char*)As[0] + ob1) = a1;
        *(short8*)((char*)Bs[0] + ob0) = b0;
        *(short8*)((char*)Bs[0] + ob1) = b1;
        __syncthreads();
        compute(As[0], Bs[0]);
    }
#endif

#pragma unroll
    for (int i = 0; i < 4; i++) {
#pragma unroll
        for (int j = 0; j < 4; j++) {
#pragma unroll
            for (int r = 0; r < 4; r++) {
                const int row = m0 + wm + i * 16 + quad * 4 + r;
                const int col = n0 + wn + j * 16 + l16;
                float v = acc[i][j][r] + bias[col];
                if (MODE == 0) {
                    const int h  = col / 192;
                    const int rr = col - h * 192;
                    const int sel = rr >> 6;
                    const int d   = rr & 63;
                    const int b = row >> 11;
                    const int t = row & 2047;
                    const int bh = b * 16 + h;
                    if (sel == 0) {
                        Cq[(((size_t)bh) * 2048 + t) * 64 + d] =
                            f32_to_bf16(v * Q_PRESCALE);
                    } else if (sel == 1) {
                        Ck[(((size_t)bh) * 2048 + t) * 64 + d] = f32_to_bf16(v);
                    } else {
                        // fused transpose_v: Vtb[bh][t>>6][d][slot(t&63)]
                        Cv[(((size_t)bh * 32 + (t >> 6)) * 64 + d) * 64 + v_slot(t & 63)] =
                            f32_to_bf16(v);
                    }
                } else {
                    Cout[(size_t)row * N + col] = v;
                }
            }
        }
    }
}

// ===== legacy fused-cvt GEMM (fallback when ws < 48MB) =====
template <int MODE, int AFP32>
__global__ __launch_bounds__(256, 2) void gemm_bt(
    const void* __restrict__ Av, const float* __restrict__ W,
    const float* __restrict__ bias,
    ushort* __restrict__ Cq, ushort* __restrict__ Ck, ushort* __restrict__ Cv,
    float* __restrict__ Cout, int M, int N, int K)
{
    __shared__ __align__(16) ushort As[128 * LDS_STRIDE];
    __shared__ __align__(16) ushort Bs[128 * LDS_STRIDE];

    const int tid  = threadIdx.x;
    const int lane = tid & 63;
    const int wave = tid >> 6;
    const int wm = (wave >> 1) * 64;
    const int wn = (wave & 1) * 64;
    const int m0 = blockIdx.x * 128;
    const int n0 = blockIdx.y * 128;
    const int quad = lane >> 4;
    const int l16  = lane & 15;

    floatx4 acc[4][4];
#pragma unroll
    for (int i = 0; i < 4; i++)
#pragma unroll
        for (int j = 0; j < 4; j++) acc[i][j] = (floatx4)0.0f;

    const int srow = tid >> 2;
    const int scol = (tid & 3) * 8;

    for (int k0 = 0; k0 < K; k0 += 32) {
        short8 a0, a1;
        if (AFP32) {
            const float* A = (const float*)Av;
            a0 = cvt8(A + (size_t)(m0 + srow) * K + k0 + scol);
            a1 = cvt8(A + (size_t)(m0 + srow + 64) * K + k0 + scol);
        } else {
            const ushort* A = (const ushort*)Av;
            a0 = *(const short8*)(A + (size_t)(m0 + srow) * K + k0 + scol);
            a1 = *(const short8*)(A + (size_t)(m0 + srow + 64) * K + k0 + scol);
        }
        const short8 b0 = cvt8(W + (size_t)(n0 + srow) * K + k0 + scol);
        const short8 b1 = cvt8(W + (size_t)(n0 + srow + 64) * K + k0 + scol);
        __syncthreads();
        *(short8*)&As[srow * LDS_STRIDE + scol] = a0;
        *(short8*)&As[(srow + 64) * LDS_STRIDE + scol] = a1;
        *(short8*)&Bs[srow * LDS_STRIDE + scol] = b0;
        *(short8*)&Bs[(srow + 64) * LDS_STRIDE + scol] = b1;
        __syncthreads();

        short8 af[4], bf[4];
#pragma unroll
        for (int i = 0; i < 4; i++)
            af[i] = *(const short8*)&As[(wm + i * 16 + l16) * LDS_STRIDE + quad * 8];
#pragma unroll
        for (int j = 0; j < 4; j++)
            bf[j] = *(const short8*)&Bs[(wn + j * 16 + l16) * LDS_STRIDE + quad * 8];
#pragma unroll
        for (int i = 0; i < 4; i++)
#pragma unroll
            for (int j = 0; j < 4; j++)
                acc[i][j] = __builtin_amdgcn_mfma_f32_16x16x32_bf16(af[i], bf[j], acc[i][j], 0, 0, 0);
    }

#pragma unroll
    for (int i = 0; i < 4; i++) {
#pragma unroll
        for (int j = 0; j < 4; j++) {
#pragma unroll
            for (int r = 0; r < 4; r++) {
                const int row = m0 + wm + i * 16 + quad * 4 + r;
                const int col = n0 + wn + j * 16 + l16;
                float v = acc[i][j][r] + bias[col];
                if (MODE == 0) {
                    const int h  = col / 192;
                    const int rr = col - h * 192;
                    const int sel = rr >> 6;
                    const int d   = rr & 63;
                    const int b = row >> 11;
                    const int t = row & 2047;
                    const int bh = b * 16 + h;
                    if (sel == 0) {
                        Cq[(((size_t)bh) * 2048 + t) * 64 + d] =
                            f32_to_bf16(v * Q_PRESCALE);
                    } else if (sel == 1) {
                        Ck[(((size_t)bh) * 2048 + t) * 64 + d] = f32_to_bf16(v);
                    } else {
                        Cv[(((size_t)bh * 32 + (t >> 6)) * 64 + d) * 64 + v_slot(t & 63)] =
                            f32_to_bf16(v);
                    }
                } else {
                    Cout[(size_t)row * N + col] = v;
                }
            }
        }
    }
}

// ===========================================================================
// MFMA causal flash attention (v8, unchanged): KVBLK=128, dbuf LDS staging,
// swizzled coalesced global_load_lds, register-P (swapped QK^T + cvt_pk),
// in-lane L sum. Grid 512 = 32 bh x 16 qt (big-first), 256 thr, LDS 64KB.
// ===========================================================================
__global__ __launch_bounds__(256, 2) void attn_mfma(
    const ushort* __restrict__ Q, const ushort* __restrict__ K,
    const ushort* __restrict__ Vtb, ushort* __restrict__ O)
{
    const int bid   = blockIdx.x;
    const int bh    = bid & 31;
    const int qtIdx = bid >> 5;
    const int qt    = (qtIdx < 8) ? (15 - qtIdx) : (qtIdx - 8);
    const int tid  = threadIdx.x;
    const int wave = tid >> 6;
    const int lane = tid & 63;
    const int quad = lane >> 4;
    const int l16  = lane & 15;
    const int qb   = qt * 128 + wave * 32;

    __shared__ __align__(16) ushort Ks[2][8192];  // 128 keys x 64 (2x 8KB swz)
    __shared__ __align__(16) ushort Vs[2][8192];

    const size_t kbase = (size_t)bh * 2048 * 64;

    // staging map: per array, thread covers 4x16B at ob = tid*16 + c*4096.
    // Each 8KB sub-tile has its own chunk swizzle: physical (row r, chunk ch)
    // holds logical (r, ch ^ (r&7)).
    int e[4];
#pragma unroll
    for (int c = 0; c < 4; c++) {
        const int ob  = tid * 16 + c * 4096;
        const int sub = ob >> 13;
        const int obs = ob & 8191;
        const int r   = obs >> 7;
        const int ch  = (obs >> 4) & 7;
        e[c] = sub * 4096 + r * 64 + ((ch ^ (r & 7)) << 3);
    }
    const ushort* Kb = K + kbase;                      // + t128*8192 + e
    const ushort* Vb = Vtb + (size_t)bh * 32 * 4096;   // + t128*8192 + e

    auto stage = [&](int t128, ushort* KsB, ushort* VsB) {
        const ushort* Ktile = Kb + t128 * 8192;
        const ushort* Vtile = Vb + t128 * 8192;
#pragma unroll
        for (int c = 0; c < 4; c++)
            gload_lds16(Ktile + e[c], KsB + c * 2048 + wave * 512);
#pragma unroll
        for (int c = 0; c < 4; c++)
            gload_lds16(Vtile + e[c], VsB + c * 2048 + wave * 512);
    };

    // swizzled fragment read offsets within an 8KB sub-tile:
    // logical (row, chunk C) at ushort idx row*64 + ((C ^ (row&7))<<3).
    const int sw0 = ((quad ^ (l16 & 7)) << 3);        // half 0: C = quad
    const int sw1 = (((4 + quad) ^ (l16 & 7)) << 3);  // half 1: C = 4+quad
    const int rbase = l16 * 64;

    short8 qf0[2], qf1[2];
#pragma unroll
    for (int f = 0; f < 2; f++) {
        const ushort* qp = Q + kbase + (size_t)(qb + f * 16 + l16) * 64 + quad * 8;
        qf0[f] = *(const short8*)qp;
        qf1[f] = *(const short8*)(qp + 32);
    }

    floatx4 accO[2][4];
#pragma unroll
    for (int f = 0; f < 2; f++)
#pragma unroll
        for (int d = 0; d < 4; d++) accO[f][d] = (floatx4)0.0f;
    float accLs[2] = {0.0f, 0.0f};

    union PB { unsigned int u[4]; short8 s8; };

    auto compute = [&](int t128, const ushort* KsB, const ushort* VsB) {
#pragma unroll
        for (int s = 0; s < 2; ++s) {
            const int t64 = 2 * t128 + s;
            if (t64 * 64 > qb + 31) continue;  // both fragments masked
            const ushort* Kt = KsB + s * 4096;
            const ushort* Vt = VsB + s * 4096;
            short8 kf[4][2], vf[4][2];
#pragma unroll
            for (int j = 0; j < 4; j++) {
                kf[j][0] = *(const short8*)&Kt[j * 1024 + rbase + sw0];
                kf[j][1] = *(const short8*)&Kt[j * 1024 + rbase + sw1];
            }
#pragma unroll
            for (int d = 0; d < 4; d++) {
                vf[d][0] = *(const short8*)&Vt[d * 1024 + rbase + sw0];
                vf[d][1] = *(const short8*)&Vt[d * 1024 + rbase + sw1];
            }

#pragma unroll
            for (int f = 0; f < 2; f++) {
                const int qlo = qb + f * 16;
                if (t64 * 64 > qlo + 15) continue;  // fully masked fragment
                floatx4 sc[4];
#pragma unroll
                for (int j = 0; j < 4; j++) {
                    floatx4 acc = (floatx4)0.0f;
                    acc = __builtin_amdgcn_mfma_f32_16x16x32_bf16(kf[j][0], qf0[f], acc, 0, 0, 0);
                    acc = __builtin_amdgcn_mfma_f32_16x16x32_bf16(kf[j][1], qf1[f], acc, 0, 0, 0);
                    sc[j] = acc;
                }
                if (t64 * 64 + 63 > qlo) {  // diagonal tile: causal mask
                    const int qcol = qlo + l16;
#pragma unroll
                    for (int j = 0; j < 4; j++) {
                        const int keyb = t64 * 64 + j * 16 + quad * 4;
#pragma unroll
                        for (int r = 0; r < 4; r++)
                            if (keyb + r > qcol) sc[j][r] = -1e30f;
                    }
                }
#pragma unroll
                for (int j = 0; j < 4; j++)
#pragma unroll
                    for (int r = 0; r < 4; r++)
                        sc[j][r] = __builtin_amdgcn_exp2f(sc[j][r]);
                const floatx4 ssum = sc[0] + sc[1] + sc[2] + sc[3];
                accLs[f] += (ssum[0] + ssum[1]) + (ssum[2] + ssum[3]);
                PB p0, p1;
#pragma unroll
                for (int j = 0; j < 2; j++) {
                    p0.u[j * 2 + 0] = cvtpk(sc[j][0], sc[j][1]);
                    p0.u[j * 2 + 1] = cvtpk(sc[j][2], sc[j][3]);
                    p1.u[j * 2 + 0] = cvtpk(sc[j + 2][0], sc[j + 2][1]);
                    p1.u[j * 2 + 1] = cvtpk(sc[j + 2][2], sc[j + 2][3]);
                }
#pragma unroll
                for (int d = 0; d < 4; d++) {
                    accO[f][d] = __builtin_amdgcn_mfma_f32_16x16x32_bf16(p0.s8, vf[d][0], accO[f][d], 0, 0, 0);
                    accO[f][d] = __builtin_amdgcn_mfma_f32_16x16x32_bf16(p1.s8, vf[d][1], accO[f][d], 0, 0, 0);
                }
            }
        }
    };

    const int nt = qt + 1;  // 128-key steps
    stage(0, Ks[0], Vs[0]);
    __syncthreads();        // buf0 staged
    int t = 0;
    while (true) {
        if (t + 1 < nt) stage(t + 1, Ks[1], Vs[1]);  // prefetch under compute
        compute(t, Ks[0], Vs[0]);
        __syncthreads();    // prefetch landed + all waves done with buf0
        if (++t >= nt) break;
        if (t + 1 < nt) stage(t + 1, Ks[0], Vs[0]);
        compute(t, Ks[1], Vs[1]);
        __syncthreads();
        if (++t >= nt) break;
    }

    const int b = bh >> 4, h = bh & 15;
#pragma unroll
    for (int f = 0; f < 2; f++) {
        // accLs[f] = partial row-sum for q = qb+f*16+l16 over this lane's keys.
        float L = accLs[f];
        L += __shfl_xor(L, 16);
        L += __shfl_xor(L, 32);  // now L(q=l16) in all quads
        float inv[4];
#pragma unroll
        for (int r = 0; r < 4; r++) inv[r] = 1.0f / __shfl(L, quad * 4 + r);
#pragma unroll
        for (int d = 0; d < 4; d++)
#pragma unroll
            for (int r = 0; r < 4; r++)
                O[(size_t)(b * 2048 + qb + f * 16 + quad * 4 + r) * 1024 + h * 64 + d * 16 + l16] =
                    f32_to_bf16(accO[f][d][r] * inv[r]);
    }
}

extern "C" void kernel_launch(void* const* d_in, const int* in_sizes, int n_in,
                              void* d_out, int out_size, void* d_ws, size_t ws_size,
                              hipStream_t stream) {
    const float* x    = (const float*)d_in[0];
    const float* Wqkv = (const float*)d_in[1];
    const float* bqkv = (const float*)d_in[2];
    const float* Wout = (const float*)d_in[3];
    const float* bout = (const float*)d_in[4];
    float* out = (float*)d_out;

    char* ws = (char*)d_ws;
    const size_t MB = 1024 * 1024;
    ushort* Q    = (ushort*)(ws + 0 * MB);
    ushort* Kk   = (ushort*)(ws + 8 * MB);
    ushort* Vtb  = (ushort*)(ws + 16 * MB);  // tile-blocked permuted V (direct)
    ushort* O    = (ushort*)(ws + 24 * MB);

    const dim3 blk(256);
    if (ws_size >= 48 * MB) {
        ushort* xb    = (ushort*)(ws + 32 * MB);
        ushort* Wqkvb = (ushort*)(ws + 40 * MB);
        ushort* Woutb = (ushort*)(ws + 46 * MB);
        cvt_bf16_3<<<dim3(4096), blk, 0, stream>>>(x, Wqkv, Wout, xb, Wqkvb, Woutb);
        gemm_bf16<0><<<dim3(32, 24), blk, 0, stream>>>(xb, Wqkvb, bqkv, Q, Kk, Vtb,
                                                       nullptr, 4096, 3072, 1024);
        attn_mfma<<<dim3(512), blk, 0, stream>>>(Q, Kk, Vtb, O);
        gemm_bf16<1><<<dim3(32, 8), blk, 0, stream>>>(O, Woutb, bout, nullptr, nullptr,
                                                      nullptr, out, 4096, 1024, 1024);
    } else {
        gemm_bt<0, 1><<<dim3(32, 24), blk, 0, stream>>>(x, Wqkv, bqkv, Q, Kk, Vtb,
                                                        nullptr, 4096, 3072, 1024);
        attn_mfma<<<dim3(512), blk, 0, stream>>>(Q, Kk, Vtb, O);
        gemm_bt<1, 0><<<dim3(32, 8), blk, 0, stream>>>(O, Wout, bout, nullptr, nullptr,
                                                       nullptr, out, 4096, 1024, 1024);
    }
}

// Round 11
// 169.550 us; speedup vs baseline: 1.7791x; 1.0046x over previous
//
#include <hip/hip_runtime.h>
#include <hip/hip_bf16.h>
#include <cstdint>

// ---------------------------------------------------------------------------
// MultiHeadAttention: B=2, T=2048, D=1024, H=16, hd=64, causal.
// Inputs (fp32): x[B,T,D], W_qkv[3D,D], b_qkv[3D], W_out[D,D], b_out[D]
// out (fp32): [B,T,D]
// ws big path (48MB): Q@0, K@8M, Vtb@16M, O@24M, xb@32M, Wqkvb@40M, Woutb@46M
// GEMMs: one-shot fp32->bf16 cvt (single fused kernel), m97-style staging.
// Softmax: no-max flash (p = exp2(s) directly), in-lane f32 row-sum.
// v11: GEMM counted-vmcnt deep pipeline (T4). v10's dbuf+__syncthreads still
//   drained vmcnt(0) each step (the just-issued prefetch too) -> exposed
//   (latency - compute) every step; only -1.7us. Now: 3 buffers, prefetch
//   distance 2, per step: vmcnt(4) [stage(t) landed, stage(t+1) in flight]
//   -> raw s_barrier -> compute(buf t) -> stage(t+2). WAR safe: buf(t-1)
//   reads completed (all feed MFMAs, lgkmcnt-waited) before the step-t
//   barrier; stage(t+2) issued after it. LDS 48KB -> 3 blocks/CU kept.
//   v9 swizzle (conflicts 0) becomes live now that LDS is critical-path.
// History: v6 coalesced LDS staging (attn 68->38us); v7 attn dbuf+fused cvt
// (177.5); v8 fused transpose_v + attn KVBLK=128 (173.1); v9 GEMM swizzle
// (172.9, conflicts 3.15M->0, drain-masked); v10 GEMM dbuf (170.3).
// LESSONS: launch_bounds 2nd arg acts as min-BLOCKS/CU ((512,4) = 64-VGPR cap
// = spill catastrophe); wave-count/balance give zero overlap gain (v2/v4);
// P-LDS roundtrip was not the wall (v5); K/V txn pattern was (v6); hipcc host
// pass lacks gfx950 builtins -> #if must be inside function bodies (R5);
// bank-conflict fixes are null while a full-drain barrier dominates (v9);
// 1-deep prefetch is null when compute < latency (v10).
// ---------------------------------------------------------------------------

using short8  = __attribute__((ext_vector_type(8))) short;
using floatx4 = __attribute__((ext_vector_type(4))) float;

#define LDS_STRIDE 40  // legacy gemm tiles: 32+8 pad

__device__ __forceinline__ float bf16_to_f32(unsigned short u) {
    union { unsigned int i; float f; } v; v.i = ((unsigned int)u) << 16; return v.f;
}
__device__ __forceinline__ unsigned short f32_to_bf16(float f) {
    union { float f; unsigned int i; } v; v.f = f;
    unsigned int x = v.i;
    unsigned int r = x + 0x7FFFu + ((x >> 16) & 1u);  // RNE
    return (unsigned short)(r >> 16);
}
__device__ __forceinline__ short8 cvt8(const float* __restrict__ p) {
    const float4 f0 = *(const float4*)p;
    const float4 f1 = *(const float4*)(p + 4);
    short8 r;
    r[0] = (short)f32_to_bf16(f0.x); r[1] = (short)f32_to_bf16(f0.y);
    r[2] = (short)f32_to_bf16(f0.z); r[3] = (short)f32_to_bf16(f0.w);
    r[4] = (short)f32_to_bf16(f1.x); r[5] = (short)f32_to_bf16(f1.y);
    r[6] = (short)f32_to_bf16(f1.z); r[7] = (short)f32_to_bf16(f1.w);
    return r;
}
// pack two f32 -> one dword of 2 bf16 (RNE); no builtin on gfx950, pure-VALU asm
__device__ __forceinline__ unsigned int cvtpk(float a, float b) {
    unsigned int r;
    asm("v_cvt_pk_bf16_f32 %0, %1, %2" : "=v"(r) : "v"(a), "v"(b));
    return r;
}

// 1/sqrt(64) * log2(e)
#define Q_PRESCALE 0.1803368801111204f

#if __has_builtin(__builtin_amdgcn_global_load_lds)
#define ASYNC_STAGE 1
typedef const __attribute__((address_space(1))) void* gas1_t;
typedef __attribute__((address_space(3))) void* las3_t;
#else
#define ASYNC_STAGE 0
#endif

// Defined unconditionally: hipcc's host pass lacks the builtin, so the #if
// must live INSIDE the body (placeholder branch never executes on device).
__device__ __forceinline__ void gload_lds16(const ushort* g, ushort* l) {
#if ASYNC_STAGE
    __builtin_amdgcn_global_load_lds((gas1_t)g, (las3_t)l, 16, 0, 0);
#else
    *(short8*)l = *(const short8*)g;  // host-pass placeholder
#endif
}

// inverse of transpose_v's slot->key map: which Vtb slot holds key k (0..63)
__device__ __forceinline__ int v_slot(int k) {
    const int k5 = k & 31;
    return (k & 32) + ((k5 >> 4) & 1) * 4 + ((k5 >> 2) & 3) * 8 + (k5 & 3);
}

// fused fp32 -> bf16 for x / W_qkv / W_out, 8 elems/thread, one launch.
// Range boundaries are block-aligned: 524288 = 2048*256, 917504 = 3584*256.
__global__ __launch_bounds__(256, 8) void cvt_bf16_3(
    const float* __restrict__ x,  const float* __restrict__ wq,
    const float* __restrict__ wo, ushort* __restrict__ xb,
    ushort* __restrict__ wqb, ushort* __restrict__ wob)
{
    const int i = blockIdx.x * 256 + threadIdx.x;  // 0..1048575
    const float* src; ushort* dst; int off;
    if (i < 524288)      { src = x;  dst = xb;  off = i; }
    else if (i < 917504) { src = wq; dst = wqb; off = i - 524288; }
    else                 { src = wo; dst = wob; off = i - 917504; }
    *(short8*)(dst + (size_t)off * 8) = cvt8(src + (size_t)off * 8);
}

// ===== m97-style bf16 GEMM: C[M,N] = A[M,K] @ W[N,K]^T + bias[N] =====
// MODE 0: scatter Q (scaled), K [bh][t][64]; V directly into tile-blocked
// permuted Vtb[bh][t64][d][slot] (transpose_v fused). MODE 1: fp32 Cout.
// LDS tiles: line-pair swizzle (v9) + 3-buffer counted-vmcnt pipeline (v11).
template <int MODE>
__global__ __launch_bounds__(256, 3) void gemm_bf16(
    const ushort* __restrict__ A, const ushort* __restrict__ W,
    const float* __restrict__ bias,
    ushort* __restrict__ Cq, ushort* __restrict__ Ck, ushort* __restrict__ Cv,
    float* __restrict__ Cout, int M, int N, int K)
{
    __shared__ __align__(16) ushort As[3][128 * 32];
    __shared__ __align__(16) ushort Bs[3][128 * 32];

    const int tid  = threadIdx.x;
    const int lane = tid & 63;
    const int wave = tid >> 6;
    const int wm = (wave >> 1) * 64;
    const int wn = (wave & 1) * 64;
    const int m0 = blockIdx.x * 128;
    const int n0 = blockIdx.y * 128;
    const int quad = lane >> 4;
    const int l16  = lane & 15;

    floatx4 acc[4][4];
#pragma unroll
    for (int i = 0; i < 4; i++)
#pragma unroll
        for (int j = 0; j < 4; j++) acc[i][j] = (floatx4)0.0f;

    // ---- swizzled staging source map (loop-invariant). Thread's linear LDS
    // dest bytes: ob0 = tid*16 (rows 0-63 half), ob1 = ob0+4096 (rows 64-127).
    // Decode physical -> logical: line = ob>>7, slot = (ob>>4)&7,
    // p = slot ^ (line&7), row = line*2 + (p>>2), chunk = p&3.
    const int ob0 = tid * 16, ob1 = ob0 + 4096;
    const int ln0 = ob0 >> 7, p0_ = ((ob0 >> 4) & 7) ^ (ln0 & 7);
    const int ln1 = ob1 >> 7, p1_ = ((ob1 >> 4) & 7) ^ (ln1 & 7);
    const int row0 = ln0 * 2 + (p0_ >> 2), ch0 = p0_ & 3;
    const int row1 = ln1 * 2 + (p1_ >> 2), ch1 = p1_ & 3;
    const ushort* pA0 = A + (size_t)(m0 + row0) * K + ch0 * 8;
    const ushort* pA1 = A + (size_t)(m0 + row1) * K + ch1 * 8;
    const ushort* pB0 = W + (size_t)(n0 + row0) * K + ch0 * 8;
    const ushort* pB1 = W + (size_t)(n0 + row1) * K + ch1 * 8;

    // ---- swizzled fragment read offsets. row = w? + i*16 + l16, chunk=quad.
    // Across i: line += 8 -> (line&7) unchanged, row&1 unchanged => slot
    // constant; ushort idx = line*64 + slot*8 = base + i*512.
    const int Ra = wm + l16;
    const int aoff = (Ra >> 1) * 64 + (((((Ra & 1) << 2) + quad) ^ ((Ra >> 1) & 7)) << 3);
    const int Rb = wn + l16;
    const int boff = (Rb >> 1) * 64 + (((((Rb & 1) << 2) + quad) ^ ((Rb >> 1) & 7)) << 3);

    auto stage = [&](int k0, ushort* AsB, ushort* BsB) {
        gload_lds16(pA0 + k0, AsB + wave * 512);
        gload_lds16(pA1 + k0, AsB + 2048 + wave * 512);
        gload_lds16(pB0 + k0, BsB + wave * 512);
        gload_lds16(pB1 + k0, BsB + 2048 + wave * 512);
    };
    auto compute = [&](const ushort* AsB, const ushort* BsB) {
        short8 af[4], bf[4];
#pragma unroll
        for (int i = 0; i < 4; i++)
            af[i] = *(const short8*)&AsB[aoff + i * 512];
#pragma unroll
        for (int j = 0; j < 4; j++)
            bf[j] = *(const short8*)&BsB[boff + j * 512];
#pragma unroll
        for (int i = 0; i < 4; i++)
#pragma unroll
            for (int j = 0; j < 4; j++)
                acc[i][j] = __builtin_amdgcn_mfma_f32_16x16x32_bf16(af[i], bf[j], acc[i][j], 0, 0, 0);
    };

#if ASYNC_STAGE
    // 3-buffer, distance-2 counted-vmcnt pipeline (T4): per step,
    //   vmcnt(4): own stage(t) landed (stage(t+1)'s 4 loads stay in flight)
    //   s_barrier: all waves' stage(t) landed AND all waves finished
    //              compute(t-1) (whose buf stage(t+2) will overwrite)
    //   compute(buf t); then issue stage(t+2).
    // RAW: stage(t) had ~2 steps to land. WAR: buf(t-1) reads all feed MFMAs
    // (lgkmcnt-waited inside compute(t-1)) before that wave passed the step-t
    // barrier; stage(t+2) is issued after it. "memory" clobbers keep the
    // compiler from hoisting ds_reads above the wait/barrier.
    const int NT = K >> 5;  // 32-wide K-steps; NT >= 2 for K >= 64
    ushort *Ac = As[0], *An = As[1], *Af = As[2];
    ushort *Bc = Bs[0], *Bn = Bs[1], *Bf = Bs[2];
    stage(0, Ac, Bc);
    stage(32, An, Bn);
    for (int t = 0; t < NT; ++t) {
        if (t + 1 < NT) {
            asm volatile("s_waitcnt vmcnt(4)" ::: "memory");
        } else {
            asm volatile("s_waitcnt vmcnt(0)" ::: "memory");
        }
        __builtin_amdgcn_s_barrier();
        compute(Ac, Bc);
        if (t + 2 < NT) stage((t + 2) * 32, Af, Bf);
        ushort* ta = Ac; Ac = An; An = Af; Af = ta;
        ushort* tb = Bc; Bc = Bn; Bn = Bf; Bf = tb;
    }
#else
    for (int k0 = 0; k0 < K; k0 += 32) {
        const short8 a0 = *(const short8*)(pA0 + k0);
        const short8 a1 = *(const short8*)(pA1 + k0);
        const short8 b0 = *(const short8*)(pB0 + k0);
        const short8 b1 = *(const short8*)(pB1 + k0);
        __syncthreads();
        *(short8*)((char*)As[0] + ob0) = a0;
        *(short8*)((char*)As[0] + ob1) = a1;
        *(short8*)((char*)Bs[0] + ob0) = b0;
        *(short8*)((char*)Bs[0] + ob1) = b1;
        __syncthreads();
        compute(As[0], Bs[0]);
    }
#endif

#pragma unroll
    for (int i = 0; i < 4; i++) {
#pragma unroll
        for (int j = 0; j < 4; j++) {
#pragma unroll
            for (int r = 0; r < 4; r++) {
                const int row = m0 + wm + i * 16 + quad * 4 + r;
                const int col = n0 + wn + j * 16 + l16;
                float v = acc[i][j][r] + bias[col];
                if (MODE == 0) {
                    const int h  = col / 192;
                    const int rr = col - h * 192;
                    const int sel = rr >> 6;
                    const int d   = rr & 63;
                    const int b = row >> 11;
                    const int t = row & 2047;
                    const int bh = b * 16 + h;
                    if (sel == 0) {
                        Cq[(((size_t)bh) * 2048 + t) * 64 + d] =
                            f32_to_bf16(v * Q_PRESCALE);
                    } else if (sel == 1) {
                        Ck[(((size_t)bh) * 2048 + t) * 64 + d] = f32_to_bf16(v);
                    } else {
                        // fused transpose_v: Vtb[bh][t>>6][d][slot(t&63)]
                        Cv[(((size_t)bh * 32 + (t >> 6)) * 64 + d) * 64 + v_slot(t & 63)] =
                            f32_to_bf16(v);
                    }
                } else {
                    Cout[(size_t)row * N + col] = v;
                }
            }
        }
    }
}

// ===== legacy fused-cvt GEMM (fallback when ws < 48MB) =====
template <int MODE, int AFP32>
__global__ __launch_bounds__(256, 2) void gemm_bt(
    const void* __restrict__ Av, const float* __restrict__ W,
    const float* __restrict__ bias,
    ushort* __restrict__ Cq, ushort* __restrict__ Ck, ushort* __restrict__ Cv,
    float* __restrict__ Cout, int M, int N, int K)
{
    __shared__ __align__(16) ushort As[128 * LDS_STRIDE];
    __shared__ __align__(16) ushort Bs[128 * LDS_STRIDE];

    const int tid  = threadIdx.x;
    const int lane = tid & 63;
    const int wave = tid >> 6;
    const int wm = (wave >> 1) * 64;
    const int wn = (wave & 1) * 64;
    const int m0 = blockIdx.x * 128;
    const int n0 = blockIdx.y * 128;
    const int quad = lane >> 4;
    const int l16  = lane & 15;

    floatx4 acc[4][4];
#pragma unroll
    for (int i = 0; i < 4; i++)
#pragma unroll
        for (int j = 0; j < 4; j++) acc[i][j] = (floatx4)0.0f;

    const int srow = tid >> 2;
    const int scol = (tid & 3) * 8;

    for (int k0 = 0; k0 < K; k0 += 32) {
        short8 a0, a1;
        if (AFP32) {
            const float* A = (const float*)Av;
            a0 = cvt8(A + (size_t)(m0 + srow) * K + k0 + scol);
            a1 = cvt8(A + (size_t)(m0 + srow + 64) * K + k0 + scol);
        } else {
            const ushort* A = (const ushort*)Av;
            a0 = *(const short8*)(A + (size_t)(m0 + srow) * K + k0 + scol);
            a1 = *(const short8*)(A + (size_t)(m0 + srow + 64) * K + k0 + scol);
        }
        const short8 b0 = cvt8(W + (size_t)(n0 + srow) * K + k0 + scol);
        const short8 b1 = cvt8(W + (size_t)(n0 + srow + 64) * K + k0 + scol);
        __syncthreads();
        *(short8*)&As[srow * LDS_STRIDE + scol] = a0;
        *(short8*)&As[(srow + 64) * LDS_STRIDE + scol] = a1;
        *(short8*)&Bs[srow * LDS_STRIDE + scol] = b0;
        *(short8*)&Bs[(srow + 64) * LDS_STRIDE + scol] = b1;
        __syncthreads();

        short8 af[4], bf[4];
#pragma unroll
        for (int i = 0; i < 4; i++)
            af[i] = *(const short8*)&As[(wm + i * 16 + l16) * LDS_STRIDE + quad * 8];
#pragma unroll
        for (int j = 0; j < 4; j++)
            bf[j] = *(const short8*)&Bs[(wn + j * 16 + l16) * LDS_STRIDE + quad * 8];
#pragma unroll
        for (int i = 0; i < 4; i++)
#pragma unroll
            for (int j = 0; j < 4; j++)
                acc[i][j] = __builtin_amdgcn_mfma_f32_16x16x32_bf16(af[i], bf[j], acc[i][j], 0, 0, 0);
    }

#pragma unroll
    for (int i = 0; i < 4; i++) {
#pragma unroll
        for (int j = 0; j < 4; j++) {
#pragma unroll
            for (int r = 0; r < 4; r++) {
                const int row = m0 + wm + i * 16 + quad * 4 + r;
                const int col = n0 + wn + j * 16 + l16;
                float v = acc[i][j][r] + bias[col];
                if (MODE == 0) {
                    const int h  = col / 192;
                    const int rr = col - h * 192;
                    const int sel = rr >> 6;
                    const int d   = rr & 63;
                    const int b = row >> 11;
                    const int t = row & 2047;
                    const int bh = b * 16 + h;
                    if (sel == 0) {
                        Cq[(((size_t)bh) * 2048 + t) * 64 + d] =
                            f32_to_bf16(v * Q_PRESCALE);
                    } else if (sel == 1) {
                        Ck[(((size_t)bh) * 2048 + t) * 64 + d] = f32_to_bf16(v);
                    } else {
                        Cv[(((size_t)bh * 32 + (t >> 6)) * 64 + d) * 64 + v_slot(t & 63)] =
                            f32_to_bf16(v);
                    }
                } else {
                    Cout[(size_t)row * N + col] = v;
                }
            }
        }
    }
}

// ===========================================================================
// MFMA causal flash attention (v8, unchanged): KVBLK=128, dbuf LDS staging,
// swizzled coalesced global_load_lds, register-P (swapped QK^T + cvt_pk),
// in-lane L sum. Grid 512 = 32 bh x 16 qt (big-first), 256 thr, LDS 64KB.
// ===========================================================================
__global__ __launch_bounds__(256, 2) void attn_mfma(
    const ushort* __restrict__ Q, const ushort* __restrict__ K,
    const ushort* __restrict__ Vtb, ushort* __restrict__ O)
{
    const int bid   = blockIdx.x;
    const int bh    = bid & 31;
    const int qtIdx = bid >> 5;
    const int qt    = (qtIdx < 8) ? (15 - qtIdx) : (qtIdx - 8);
    const int tid  = threadIdx.x;
    const int wave = tid >> 6;
    const int lane = tid & 63;
    const int quad = lane >> 4;
    const int l16  = lane & 15;
    const int qb   = qt * 128 + wave * 32;

    __shared__ __align__(16) ushort Ks[2][8192];  // 128 keys x 64 (2x 8KB swz)
    __shared__ __align__(16) ushort Vs[2][8192];

    const size_t kbase = (size_t)bh * 2048 * 64;

    // staging map: per array, thread covers 4x16B at ob = tid*16 + c*4096.
    // Each 8KB sub-tile has its own chunk swizzle: physical (row r, chunk ch)
    // holds logical (r, ch ^ (r&7)).
    int e[4];
#pragma unroll
    for (int c = 0; c < 4; c++) {
        const int ob  = tid * 16 + c * 4096;
        const int sub = ob >> 13;
        const int obs = ob & 8191;
        const int r   = obs >> 7;
        const int ch  = (obs >> 4) & 7;
        e[c] = sub * 4096 + r * 64 + ((ch ^ (r & 7)) << 3);
    }
    const ushort* Kb = K + kbase;                      // + t128*8192 + e
    const ushort* Vb = Vtb + (size_t)bh * 32 * 4096;   // + t128*8192 + e

    auto stage = [&](int t128, ushort* KsB, ushort* VsB) {
        const ushort* Ktile = Kb + t128 * 8192;
        const ushort* Vtile = Vb + t128 * 8192;
#pragma unroll
        for (int c = 0; c < 4; c++)
            gload_lds16(Ktile + e[c], KsB + c * 2048 + wave * 512);
#pragma unroll
        for (int c = 0; c < 4; c++)
            gload_lds16(Vtile + e[c], VsB + c * 2048 + wave * 512);
    };

    // swizzled fragment read offsets within an 8KB sub-tile:
    // logical (row, chunk C) at ushort idx row*64 + ((C ^ (row&7))<<3).
    const int sw0 = ((quad ^ (l16 & 7)) << 3);        // half 0: C = quad
    const int sw1 = (((4 + quad) ^ (l16 & 7)) << 3);  // half 1: C = 4+quad
    const int rbase = l16 * 64;

    short8 qf0[2], qf1[2];
#pragma unroll
    for (int f = 0; f < 2; f++) {
        const ushort* qp = Q + kbase + (size_t)(qb + f * 16 + l16) * 64 + quad * 8;
        qf0[f] = *(const short8*)qp;
        qf1[f] = *(const short8*)(qp + 32);
    }

    floatx4 accO[2][4];
#pragma unroll
    for (int f = 0; f < 2; f++)
#pragma unroll
        for (int d = 0; d < 4; d++) accO[f][d] = (floatx4)0.0f;
    float accLs[2] = {0.0f, 0.0f};

    union PB { unsigned int u[4]; short8 s8; };

    auto compute = [&](int t128, const ushort* KsB, const ushort* VsB) {
#pragma unroll
        for (int s = 0; s < 2; ++s) {
            const int t64 = 2 * t128 + s;
            if (t64 * 64 > qb + 31) continue;  // both fragments masked
            const ushort* Kt = KsB + s * 4096;
            const ushort* Vt = VsB + s * 4096;
            short8 kf[4][2], vf[4][2];
#pragma unroll
            for (int j = 0; j < 4; j++) {
                kf[j][0] = *(const short8*)&Kt[j * 1024 + rbase + sw0];
                kf[j][1] = *(const short8*)&Kt[j * 1024 + rbase + sw1];
            }
#pragma unroll
            for (int d = 0; d < 4; d++) {
                vf[d][0] = *(const short8*)&Vt[d * 1024 + rbase + sw0];
                vf[d][1] = *(const short8*)&Vt[d * 1024 + rbase + sw1];
            }

#pragma unroll
            for (int f = 0; f < 2; f++) {
                const int qlo = qb + f * 16;
                if (t64 * 64 > qlo + 15) continue;  // fully masked fragment
                floatx4 sc[4];
#pragma unroll
                for (int j = 0; j < 4; j++) {
                    floatx4 acc = (floatx4)0.0f;
                    acc = __builtin_amdgcn_mfma_f32_16x16x32_bf16(kf[j][0], qf0[f], acc, 0, 0, 0);
                    acc = __builtin_amdgcn_mfma_f32_16x16x32_bf16(kf[j][1], qf1[f], acc, 0, 0, 0);
                    sc[j] = acc;
                }
                if (t64 * 64 + 63 > qlo) {  // diagonal tile: causal mask
                    const int qcol = qlo + l16;
#pragma unroll
                    for (int j = 0; j < 4; j++) {
                        const int keyb = t64 * 64 + j * 16 + quad * 4;
#pragma unroll
                        for (int r = 0; r < 4; r++)
                            if (keyb + r > qcol) sc[j][r] = -1e30f;
                    }
                }
#pragma unroll
                for (int j = 0; j < 4; j++)
#pragma unroll
                    for (int r = 0; r < 4; r++)
                        sc[j][r] = __builtin_amdgcn_exp2f(sc[j][r]);
                const floatx4 ssum = sc[0] + sc[1] + sc[2] + sc[3];
                accLs[f] += (ssum[0] + ssum[1]) + (ssum[2] + ssum[3]);
                PB p0, p1;
#pragma unroll
                for (int j = 0; j < 2; j++) {
                    p0.u[j * 2 + 0] = cvtpk(sc[j][0], sc[j][1]);
                    p0.u[j * 2 + 1] = cvtpk(sc[j][2], sc[j][3]);
                    p1.u[j * 2 + 0] = cvtpk(sc[j + 2][0], sc[j + 2][1]);
                    p1.u[j * 2 + 1] = cvtpk(sc[j + 2][2], sc[j + 2][3]);
                }
#pragma unroll
                for (int d = 0; d < 4; d++) {
                    accO[f][d] = __builtin_amdgcn_mfma_f32_16x16x32_bf16(p0.s8, vf[d][0], accO[f][d], 0, 0, 0);
                    accO[f][d] = __builtin_amdgcn_mfma_f32_16x16x32_bf16(p1.s8, vf[d][1], accO[f][d], 0, 0, 0);
                }
            }
        }
    };

    const int nt = qt + 1;  // 128-key steps
    stage(0, Ks[0], Vs[0]);
    __syncthreads();        // buf0 staged
    int t = 0;
    while (true) {
        if (t + 1 < nt) stage(t + 1, Ks[1], Vs[1]);  // prefetch under compute
        compute(t, Ks[0], Vs[0]);
        __syncthreads();    // prefetch landed + all waves done with buf0
        if (++t >= nt) break;
        if (t + 1 < nt) stage(t + 1, Ks[0], Vs[0]);
        compute(t, Ks[1], Vs[1]);
        __syncthreads();
        if (++t >= nt) break;
    }

    const int b = bh >> 4, h = bh & 15;
#pragma unroll
    for (int f = 0; f < 2; f++) {
        // accLs[f] = partial row-sum for q = qb+f*16+l16 over this lane's keys.
        float L = accLs[f];
        L += __shfl_xor(L, 16);
        L += __shfl_xor(L, 32);  // now L(q=l16) in all quads
        float inv[4];
#pragma unroll
        for (int r = 0; r < 4; r++) inv[r] = 1.0f / __shfl(L, quad * 4 + r);
#pragma unroll
        for (int d = 0; d < 4; d++)
#pragma unroll
            for (int r = 0; r < 4; r++)
                O[(size_t)(b * 2048 + qb + f * 16 + quad * 4 + r) * 1024 + h * 64 + d * 16 + l16] =
                    f32_to_bf16(accO[f][d][r] * inv[r]);
    }
}

extern "C" void kernel_launch(void* const* d_in, const int* in_sizes, int n_in,
                              void* d_out, int out_size, void* d_ws, size_t ws_size,
                              hipStream_t stream) {
    const float* x    = (const float*)d_in[0];
    const float* Wqkv = (const float*)d_in[1];
    const float* bqkv = (const float*)d_in[2];
    const float* Wout = (const float*)d_in[3];
    const float* bout = (const float*)d_in[4];
    float* out = (float*)d_out;

    char* ws = (char*)d_ws;
    const size_t MB = 1024 * 1024;
    ushort* Q    = (ushort*)(ws + 0 * MB);
    ushort* Kk   = (ushort*)(ws + 8 * MB);
    ushort* Vtb  = (ushort*)(ws + 16 * MB);  // tile-blocked permuted V (direct)
    ushort* O    = (ushort*)(ws + 24 * MB);

    const dim3 blk(256);
    if (ws_size >= 48 * MB) {
        ushort* xb    = (ushort*)(ws + 32 * MB);
        ushort* Wqkvb = (ushort*)(ws + 40 * MB);
        ushort* Woutb = (ushort*)(ws + 46 * MB);
        cvt_bf16_3<<<dim3(4096), blk, 0, stream>>>(x, Wqkv, Wout, xb, Wqkvb, Woutb);
        gemm_bf16<0><<<dim3(32, 24), blk, 0, stream>>>(xb, Wqkvb, bqkv, Q, Kk, Vtb,
                                                       nullptr, 4096, 3072, 1024);
        attn_mfma<<<dim3(512), blk, 0, stream>>>(Q, Kk, Vtb, O);
        gemm_bf16<1><<<dim3(32, 8), blk, 0, stream>>>(O, Woutb, bout, nullptr, nullptr,
                                                      nullptr, out, 4096, 1024, 1024);
    } else {
        gemm_bt<0, 1><<<dim3(32, 24), blk, 0, stream>>>(x, Wqkv, bqkv, Q, Kk, Vtb,
                                                        nullptr, 4096, 3072, 1024);
        attn_mfma<<<dim3(512), blk, 0, stream>>>(Q, Kk, Vtb, O);
        gemm_bt<1, 0><<<dim3(32, 8), blk, 0, stream>>>(O, Wout, bout, nullptr, nullptr,
                                                       nullptr, out, 4096, 1024, 1024);
    }
}